// Round 10
// baseline (3893.207 us; speedup 1.0000x reference)
//
#include <hip/hip_runtime.h>
#include <math.h>

#define B_   16
#define N_   2048
#define S_   1025
#define K_   16
#define EMB_ 64
#define NF_  (B_ * S_ * K_)   // 262400
#define NCH_ (NF_ / 64)       // 4100 column-chunks of 64

typedef float v2f __attribute__((ext_vector_type(2)));

// ======== FUSED: blocks 0-15 = FPS (round-8 validated body, 745us) ; blocks 16+ = pk ========
__global__ __launch_bounds__(256) __attribute__((amdgpu_waves_per_eu(1, 1)))
void fps_pk_kernel(const float* __restrict__ xy, const float* __restrict__ fea,
                   const float* __restrict__ W1,
                   int* __restrict__ fps_idx, float* __restrict__ new_xyz,
                   float* __restrict__ out0, float* __restrict__ P) {
  __shared__ float smem[8192];   // 32 KB union
  if (blockIdx.x < 16) {
    // ---------------- FPS: one wave per batch ----------------
    const int b = blockIdx.x;
    float2* lxy = reinterpret_cast<float2*>(smem);   // 16 KB
    const int lane = threadIdx.x;
    const float* xb = xy + (size_t)b * 2 * N_;
    v2f pxp[16], pyp[16];
    float dist[32];
    if (lane < 64) {
      const float2* xb2 = (const float2*)xb;
      const float2* yb2 = (const float2*)(xb + N_);
#pragma unroll
      for (int q = 0; q < 16; ++q) {
        float2 x01 = xb2[lane * 16 + q];
        float2 y01 = yb2[lane * 16 + q];
        int p = lane * 32 + 2 * q;
        lxy[p] = make_float2(x01.x, y01.x);
        lxy[p + 1] = make_float2(x01.y, y01.y);
        pxp[q][0] = x01.x; pxp[q][1] = x01.y;
        pyp[q][0] = y01.x; pyp[q][1] = y01.y;
        dist[2 * q] = __builtin_inff();
        dist[2 * q + 1] = __builtin_inff();
      }
#pragma unroll
      for (int q = 0; q < 16; ++q) {   // opaque pin: true VGPR residency
        asm volatile("" : "+v"(pxp[q]), "+v"(pyp[q]));
      }
    }
    __syncthreads();
    if (lane < 64) {
      int cur = 0;
      for (int t = 0; t < S_; ++t) {
        float2 c = lxy[cur];          // uniform-address broadcast read
        if (lane == 0) {
          fps_idx[b * S_ + t] = cur;
          new_xyz[(b * S_ + t) * 2 + 0] = c.x;
          new_xyz[(b * S_ + t) * 2 + 1] = c.y;
          out0[b * 2 * S_ + t] = c.x;
          out0[b * 2 * S_ + S_ + t] = c.y;
        }
        const float ncx = -c.x, ncy = -c.y;  // pk_add(x,-c) == rn(x-c)
        v2f ncx2; ncx2[0] = ncx; ncx2[1] = ncx;
        v2f ncy2; ncy2[0] = ncy; ncy2[1] = ncy;
        float lmax0 = -__builtin_inff(), lmax1 = -__builtin_inff();
#pragma unroll
        for (int q = 0; q < 16; ++q) {
          v2f dx, dy, sx, sy, dd;
          asm("v_pk_add_f32 %0, %1, %2" : "=v"(dx) : "v"(pxp[q]), "v"(ncx2));
          asm("v_pk_add_f32 %0, %1, %2" : "=v"(dy) : "v"(pyp[q]), "v"(ncy2));
          asm("v_pk_mul_f32 %0, %1, %1" : "=v"(sx) : "v"(dx));
          asm("v_pk_mul_f32 %0, %1, %1" : "=v"(sy) : "v"(dy));
          asm("v_pk_add_f32 %0, %1, %2" : "=v"(dd) : "v"(sx), "v"(sy));
          float nd0 = fminf(dist[2 * q], dd[0]);
          float nd1 = fminf(dist[2 * q + 1], dd[1]);
          dist[2 * q] = nd0;
          dist[2 * q + 1] = nd1;
          lmax0 = fmaxf(lmax0, nd0);
          lmax1 = fmaxf(lmax1, nd1);
        }
        const float lmax = fmaxf(lmax0, lmax1);
        int xr = __float_as_int(lmax);
#define DPP_MAX_STEP(CTRL)                                                        \
        {                                                                         \
          int tmp_ = __builtin_amdgcn_update_dpp(xr, xr, (CTRL), 0xF, 0xF, false);\
          xr = __float_as_int(fmaxf(__int_as_float(xr), __int_as_float(tmp_)));   \
        }
        DPP_MAX_STEP(0x111)
        DPP_MAX_STEP(0x112)
        DPP_MAX_STEP(0x114)
        DPP_MAX_STEP(0x118)
        DPP_MAX_STEP(0x142)
        DPP_MAX_STEP(0x143)
#undef DPP_MAX_STEP
        const float g = __int_as_float(__builtin_amdgcn_readlane(xr, 63));
        int lf = 0;
#pragma unroll
        for (int j = 31; j >= 0; --j)
          if (dist[j] == g) lf = j;             // descending scan keeps lowest j
        unsigned long long mask = __ballot(lmax == g);
        int first = __ffsll(mask) - 1;          // lowest lane with the max
        cur = __builtin_amdgcn_readlane(lane * 32 + lf, first);
      }
    }
  } else {
    // ---------------- pk: P[b][pt][c] = sum_e W1[c][2+e]*fea[b][e][pt] ----------------
    const int bid = blockIdx.x - 16;
    const int t = threadIdx.x;
    const int b = bid >> 5;
    const int pt0 = (bid & 31) << 6;
    float* W1L = smem;            // [e][c] 16 KB
    float* feaL = smem + 4096;    // [e][pt] 16 KB
#pragma unroll
    for (int p = 0; p < 16; ++p) {
      int idx = t + 256 * p;
      int c = idx >> 6, e = idx & 63;
      W1L[e * 64 + c] = W1[c * 66 + 2 + e];
      int r = (t >> 6) + 4 * p, cc = t & 63;
      feaL[r * 64 + cc] = fea[((size_t)b * 64 + r) * N_ + pt0 + cc];
    }
    __syncthreads();
    const int tpt = t & 15, tcq = t >> 4;
    float acc[4][4];
#pragma unroll
    for (int i = 0; i < 4; ++i)
#pragma unroll
      for (int j = 0; j < 4; ++j) acc[i][j] = 0.f;
    for (int e = 0; e < 64; ++e) {
      float4 a4 = *reinterpret_cast<const float4*>(&W1L[e * 64 + tcq * 4]);
      float4 b4 = *reinterpret_cast<const float4*>(&feaL[e * 64 + tpt * 4]);
      const float av[4] = {a4.x, a4.y, a4.z, a4.w};
      const float bvv[4] = {b4.x, b4.y, b4.z, b4.w};
#pragma unroll
      for (int i = 0; i < 4; ++i)
#pragma unroll
        for (int j = 0; j < 4; ++j) acc[i][j] = fmaf(av[i], bvv[j], acc[i][j]);
    }
#pragma unroll
    for (int j = 0; j < 4; ++j) {
      int pt = tpt * 4 + j;
      float4 v = {acc[0][j], acc[1][j], acc[2][j], acc[3][j]};
      *reinterpret_cast<float4*>(&P[((size_t)(b * N_ + pt0 + pt)) * 64 + tcq * 4]) = v;
    }
  }
}

// ---------------- KNN fp64-exact, 16 lanes per query point (validated) ----------------
__global__ __launch_bounds__(256) void knn_kernel(const float* __restrict__ xy,
                                                  const int* __restrict__ fps_idx,
                                                  int* __restrict__ knn_sel) {
  const int b = blockIdx.y;
  __shared__ float2 lxy[N_];
  __shared__ double lsq[N_];
  const float* xb = xy + (size_t)b * 2 * N_;
  for (int p = threadIdx.x; p < N_; p += 256) {
    float x = xb[p], y = xb[N_ + p];
    lxy[p] = make_float2(x, y);
    lsq[p] = (double)x * (double)x + (double)y * (double)y;
  }
  __syncthreads();
  const int t = threadIdx.x;
  const int s = blockIdx.x * 16 + (t >> 4);
  if (s >= S_) return;
  const int oct = t & 15;
  const int p0 = fps_idx[b * S_ + s];
  float2 q = lxy[p0];
  const double xn = (double)q.x, yn = (double)q.y;
  const double sqn = lsq[p0];
  double d16[16];
  int i16[16];
#pragma unroll
  for (int j = 0; j < 16; ++j) { d16[j] = __builtin_inf(); i16[j] = 0x7fffffff; }
  const int mlo = oct * 128;
  for (int m0 = mlo; m0 < mlo + 128; m0 += 4) {
    double dd[4];
#pragma unroll
    for (int u = 0; u < 4; ++u) {
      float2 p = lxy[m0 + u];
      double dot = (double)p.x * xn + (double)p.y * yn;
      dd[u] = (sqn - 2.0 * dot) + lsq[m0 + u];
    }
#pragma unroll
    for (int u = 0; u < 4; ++u) {
      if (dd[u] < d16[15]) {
        double d = dd[u];
        int mi = m0 + u;
#pragma unroll
        for (int j = 15; j >= 1; --j) {
          bool shift = d < d16[j - 1];
          bool ins = d < d16[j];
          d16[j] = shift ? d16[j - 1] : (ins ? d : d16[j]);
          i16[j] = shift ? i16[j - 1] : (ins ? mi : i16[j]);
        }
        if (d < d16[0]) { d16[0] = d; i16[0] = mi; }
      }
    }
  }
#pragma unroll
  for (int w = 1; w <= 8; w <<= 1) {
    double nd[16]; int ni[16];
#pragma unroll
    for (int i = 0; i < 16; ++i) {
      double rd = __shfl_xor(d16[15 - i], w, 64);
      int ri = __shfl_xor(i16[15 - i], w, 64);
      bool takeR = (rd < d16[i]) || (rd == d16[i] && ri < i16[i]);
      nd[i] = takeR ? rd : d16[i];
      ni[i] = takeR ? ri : i16[i];
    }
#pragma unroll
    for (int i = 0; i < 16; ++i) { d16[i] = nd[i]; i16[i] = ni[i]; }
    if (w < 8) {
#pragma unroll
      for (int dstg = 8; dstg >= 1; dstg >>= 1) {
#pragma unroll
        for (int i = 0; i < 16; ++i) {
          if ((i & dstg) == 0) {
            int a = i, c = i + dstg;
            bool sw = (d16[a] > d16[c]) || (d16[a] == d16[c] && i16[a] > i16[c]);
            double tlo = sw ? d16[c] : d16[a];
            double thi = sw ? d16[a] : d16[c];
            int ulo = sw ? i16[c] : i16[a];
            int uhi = sw ? i16[a] : i16[c];
            d16[a] = tlo; d16[c] = thi; i16[a] = ulo; i16[c] = uhi;
          }
        }
      }
    }
  }
  if (oct == 0) {
    int* dst = knn_sel + ((size_t)b * S_ + s) * K_;
#pragma unroll
    for (int j = 0; j < 16; ++j) dst[j] = i16[j];
  }
}

// ---------------- Y1[64][NF]: gather P + W1a*dxy + b1 ----------------
__global__ __launch_bounds__(256) void yk1_kernel(const float* __restrict__ xy,
                                                  const int* __restrict__ knn_sel,
                                                  const float* __restrict__ new_xyz,
                                                  const float* __restrict__ P,
                                                  const float* __restrict__ W1,
                                                  const float* __restrict__ b1,
                                                  float* __restrict__ Y1) {
  __shared__ float w0s[64], w1s[64], bbs[64];
  const int t = threadIdx.x;
  if (t < 64) { w0s[t] = W1[t * 66 + 0]; w1s[t] = W1[t * 66 + 1]; bbs[t] = b1[t]; }
  __syncthreads();
  const int n = blockIdx.x * 256 + t;
  const int bs = n >> 4;
  const int b = bs / S_;
  const int nbr = knn_sel[n];
  const float dx = xy[(size_t)b * 2 * N_ + nbr] - new_xyz[bs * 2 + 0];
  const float dy = xy[(size_t)b * 2 * N_ + N_ + nbr] - new_xyz[bs * 2 + 1];
  const float* prow = &P[((size_t)(b * N_ + nbr)) * 64];
  for (int c4 = 0; c4 < 64; c4 += 4) {
    float4 p4 = *reinterpret_cast<const float4*>(&prow[c4]);
    float v0 = p4.x + w0s[c4 + 0] * dx + w1s[c4 + 0] * dy + bbs[c4 + 0];
    float v1 = p4.y + w0s[c4 + 1] * dx + w1s[c4 + 1] * dy + bbs[c4 + 1];
    float v2 = p4.z + w0s[c4 + 2] * dx + w1s[c4 + 2] * dy + bbs[c4 + 2];
    float v3 = p4.w + w0s[c4 + 3] * dx + w1s[c4 + 3] * dy + bbs[c4 + 3];
    Y1[(size_t)(c4 + 0) * NF_ + n] = v0;
    Y1[(size_t)(c4 + 1) * NF_ + n] = v1;
    Y1[(size_t)(c4 + 2) * NF_ + n] = v2;
    Y1[(size_t)(c4 + 3) * NF_ + n] = v3;
  }
}

// ---------------- per-row sum + sumsq in one pass (fp64) ----------------
__global__ __launch_bounds__(1024) void rowstats_kernel(const float* __restrict__ Y,
                                                        double* __restrict__ sum_out,
                                                        double* __restrict__ sq_out) {
  const int r = blockIdx.x;
  const float* row = Y + (size_t)r * NF_;
  double s = 0.0, s2 = 0.0;
  for (int i = threadIdx.x * 4; i < NF_; i += 4096) {
    float4 v = *reinterpret_cast<const float4*>(&row[i]);
    double dx = v.x, dy = v.y, dz = v.z, dw = v.w;
    s += (dx + dy) + (dz + dw);
    s2 = fma(dx, dx, s2); s2 = fma(dy, dy, s2);
    s2 = fma(dz, dz, s2); s2 = fma(dw, dw, s2);
  }
  __shared__ double sh[1024], sh2[1024];
  sh[threadIdx.x] = s; sh2[threadIdx.x] = s2;
  __syncthreads();
  for (int o = 512; o > 0; o >>= 1) {
    if (threadIdx.x < o) {
      sh[threadIdx.x] += sh[threadIdx.x + o];
      sh2[threadIdx.x] += sh2[threadIdx.x + o];
    }
    __syncthreads();
  }
  if (threadIdx.x == 0) { sum_out[r] = sh[0]; sq_out[r] = sh2[0]; }
}

// ---------------- layer-1 BN coeffs from sum/sumsq (validated) ----------------
__global__ void absch_kernel(const double* __restrict__ sumv, const double* __restrict__ sqv,
                             const float* __restrict__ g, const float* __restrict__ be,
                             float* __restrict__ A, float* __restrict__ D, int M) {
  int m = threadIdx.x;
  if (m >= M) return;
  double mu = sumv[m] * (1.0 / NF_);
  double var = sqv[m] * (1.0 / NF_) - mu * mu;
  double a = (double)g[m] / sqrt(var + 1e-5);
  A[m] = (float)a;
  D[m] = (float)((double)be[m] - a * mu);
}

// ============ GramA: G1 = sum x1 x1^T (64x64) + rowsums, x1 = relu(A1*Y1+Bc1) ============
__global__ __launch_bounds__(256) void gramA_kernel(const float* __restrict__ Y1,
                                                    const float* __restrict__ A1v,
                                                    const float* __restrict__ Bc1v,
                                                    float* __restrict__ parts) {
  __shared__ float X1s[64 * 68];   // 17.4 KB
  const int t = threadIdx.x;
  const int rI = t >> 4, cJ = t & 15;
  float a1r[4], c1r[4];
#pragma unroll
  for (int u = 0; u < 4; ++u) {
    a1r[u] = A1v[rI + 16 * u];
    c1r[u] = Bc1v[rI + 16 * u];
  }
  float accG[4][4], rs[4];
#pragma unroll
  for (int i = 0; i < 4; ++i) {
    rs[i] = 0.f;
#pragma unroll
    for (int j = 0; j < 4; ++j) accG[i][j] = 0.f;
  }
  for (int ch = blockIdx.x; ch < NCH_; ch += 256) {
    const size_t n0 = (size_t)ch * 64;
#pragma unroll
    for (int u = 0; u < 4; ++u) {
      const int row = rI + 16 * u;
      float4 y4 = *reinterpret_cast<const float4*>(&Y1[(size_t)row * NF_ + n0 + cJ * 4]);
      float4 v;
      v.x = fmaxf(fmaf(y4.x, a1r[u], c1r[u]), 0.f);
      v.y = fmaxf(fmaf(y4.y, a1r[u], c1r[u]), 0.f);
      v.z = fmaxf(fmaf(y4.z, a1r[u], c1r[u]), 0.f);
      v.w = fmaxf(fmaf(y4.w, a1r[u], c1r[u]), 0.f);
      *reinterpret_cast<float4*>(&X1s[row * 68 + cJ * 4]) = v;
    }
    __syncthreads();
#pragma unroll
    for (int c4 = 0; c4 < 16; ++c4) {
      float4 a4[4];
#pragma unroll
      for (int i = 0; i < 4; ++i)
        a4[i] = *reinterpret_cast<const float4*>(&X1s[(rI + 16 * i) * 68 + c4 * 4]);
      if (cJ == 0) {
#pragma unroll
        for (int i = 0; i < 4; ++i) rs[i] += (a4[i].x + a4[i].y) + (a4[i].z + a4[i].w);
      }
#pragma unroll
      for (int j = 0; j < 4; ++j) {
        float4 b4 = *reinterpret_cast<const float4*>(&X1s[(cJ + 16 * j) * 68 + c4 * 4]);
#pragma unroll
        for (int i = 0; i < 4; ++i) {
          accG[i][j] = fmaf(a4[i].x, b4.x, accG[i][j]);
          accG[i][j] = fmaf(a4[i].y, b4.y, accG[i][j]);
          accG[i][j] = fmaf(a4[i].z, b4.z, accG[i][j]);
          accG[i][j] = fmaf(a4[i].w, b4.w, accG[i][j]);
        }
      }
    }
    __syncthreads();
  }
  float* bp = parts + (size_t)blockIdx.x * 4160;
#pragma unroll
  for (int i = 0; i < 4; ++i)
#pragma unroll
    for (int j = 0; j < 4; ++j) bp[(rI + 16 * i) * 64 + (cJ + 16 * j)] = accG[i][j];
  if (cJ == 0) {
#pragma unroll
    for (int i = 0; i < 4; ++i) bp[4096 + rI + 16 * i] = rs[i];
  }
}

// ============ GramB: GEMM2 -> x2, then G2 = sum x2 x2^T (128x128) + rowsums ============
__global__ __launch_bounds__(256) void gramB_kernel(const float* __restrict__ Y1,
                                                    const float* __restrict__ W2,
                                                    const float* __restrict__ A1v,
                                                    const float* __restrict__ Bc1v,
                                                    const float* __restrict__ A2v,
                                                    const float* __restrict__ D2v,
                                                    float* __restrict__ parts) {
  __shared__ float W2L[64 * 128];
  __shared__ float ab[128];
  __shared__ float X2s[128 * 68];
  const int t = threadIdx.x;
#pragma unroll
  for (int p = 0; p < 32; ++p) {
    int idx = t + 256 * p;
    int m = idx >> 6, k = idx & 63;
    W2L[k * 128 + m] = W2[m * 64 + k];
  }
  if (t < 64) { ab[t] = A1v[t]; ab[64 + t] = Bc1v[t]; }
  const int tmA = t >> 4, tcA = t & 15;
  const int rI = tmA, cJ = tcA;
  float a2r[8], d2r[8], rs[8];
  float accG[8][8];
#pragma unroll
  for (int i = 0; i < 8; ++i) {
    a2r[i] = A2v[tmA * 8 + i];
    d2r[i] = D2v[tmA * 8 + i];
    rs[i] = 0.f;
#pragma unroll
    for (int j = 0; j < 8; ++j) accG[i][j] = 0.f;
  }
  __syncthreads();
  for (int ch = blockIdx.x; ch < NCH_; ch += 256) {
    const size_t n0 = (size_t)ch * 64;
    {
      float acc[8][4];
#pragma unroll
      for (int i = 0; i < 8; ++i)
#pragma unroll
        for (int j = 0; j < 4; ++j) acc[i][j] = 0.f;
#pragma unroll 2
      for (int k = 0; k < 64; ++k) {
        float4 y4 = *reinterpret_cast<const float4*>(&Y1[(size_t)k * NF_ + n0 + tcA * 4]);
        float a1 = ab[k], c1 = ab[64 + k];
        float bx[4];
        bx[0] = fmaxf(fmaf(y4.x, a1, c1), 0.f);
        bx[1] = fmaxf(fmaf(y4.y, a1, c1), 0.f);
        bx[2] = fmaxf(fmaf(y4.z, a1, c1), 0.f);
        bx[3] = fmaxf(fmaf(y4.w, a1, c1), 0.f);
        const float4* ap = reinterpret_cast<const float4*>(&W2L[k * 128 + tmA * 8]);
        float4 a0 = ap[0], a4 = ap[1];
        const float av[8] = {a0.x, a0.y, a0.z, a0.w, a4.x, a4.y, a4.z, a4.w};
#pragma unroll
        for (int i = 0; i < 8; ++i)
#pragma unroll
          for (int j = 0; j < 4; ++j) acc[i][j] = fmaf(av[i], bx[j], acc[i][j]);
      }
#pragma unroll
      for (int i = 0; i < 8; ++i) {
        float4 v;
        v.x = fmaxf(fmaf(acc[i][0], a2r[i], d2r[i]), 0.f);
        v.y = fmaxf(fmaf(acc[i][1], a2r[i], d2r[i]), 0.f);
        v.z = fmaxf(fmaf(acc[i][2], a2r[i], d2r[i]), 0.f);
        v.w = fmaxf(fmaf(acc[i][3], a2r[i], d2r[i]), 0.f);
        *reinterpret_cast<float4*>(&X2s[(tmA * 8 + i) * 68 + tcA * 4]) = v;
      }
    }
    __syncthreads();
    // Gram of X2s: rows rI+16i, cols cJ+16j (bank-friendly maps)
#pragma unroll
    for (int c4 = 0; c4 < 16; ++c4) {
      float4 a4[8];
#pragma unroll
      for (int i = 0; i < 8; ++i)
        a4[i] = *reinterpret_cast<const float4*>(&X2s[(rI + 16 * i) * 68 + c4 * 4]);
      if (cJ == 0) {
#pragma unroll
        for (int i = 0; i < 8; ++i) rs[i] += (a4[i].x + a4[i].y) + (a4[i].z + a4[i].w);
      }
#pragma unroll
      for (int j = 0; j < 8; ++j) {
        float4 b4 = *reinterpret_cast<const float4*>(&X2s[(cJ + 16 * j) * 68 + c4 * 4]);
#pragma unroll
        for (int i = 0; i < 8; ++i) {
          accG[i][j] = fmaf(a4[i].x, b4.x, accG[i][j]);
          accG[i][j] = fmaf(a4[i].y, b4.y, accG[i][j]);
          accG[i][j] = fmaf(a4[i].z, b4.z, accG[i][j]);
          accG[i][j] = fmaf(a4[i].w, b4.w, accG[i][j]);
        }
      }
    }
    __syncthreads();
  }
  float* bp = parts + (size_t)blockIdx.x * 16512;
#pragma unroll
  for (int i = 0; i < 8; ++i)
#pragma unroll
    for (int j = 0; j < 8; ++j) bp[(rI + 16 * i) * 128 + (cJ + 16 * j)] = accG[i][j];
  if (cJ == 0) {
#pragma unroll
    for (int i = 0; i < 8; ++i) bp[16384 + rI + 16 * i] = rs[i];
  }
}

// ---------------- reduce Gram partials [NB][stride] -> G fp64 + S fp64 ----------------
__global__ void redG_kernel(const float* __restrict__ parts, double* __restrict__ Gout,
                            double* __restrict__ Sout, int NB, int stride, int GN, int SN) {
  int e = blockIdx.x * 256 + threadIdx.x;
  if (e >= GN + SN) return;
  double a = 0.0;
  for (int p = 0; p < NB; ++p) a += (double)parts[(size_t)p * stride + e];
  if (e < GN) Gout[e] = a;
  else Sout[e - GN] = a;
}

// ---------------- BN coeffs from Gram: var = wGw/NF - mu^2, mu = wS/NF ----------------
__global__ void abschG_kernel(const double* __restrict__ G, const double* __restrict__ S,
                              const float* __restrict__ W, const float* __restrict__ g,
                              const float* __restrict__ be, float* __restrict__ A,
                              float* __restrict__ D) {
  const int Pp = blockDim.x;   // 64 or 128
  const int m = blockIdx.x;
  const int p = threadIdx.x;
  const double* Grow = G + (size_t)p * Pp;
  const float* Wm = W + (size_t)m * Pp;
  double wp = (double)Wm[p];
  double hp = 0.0;
  for (int q = 0; q < Pp; ++q) hp += Grow[q] * (double)Wm[q];
  __shared__ double sv[128], su[128];
  sv[p] = wp * hp;
  su[p] = wp * S[p];
  __syncthreads();
  for (int o = Pp >> 1; o > 0; o >>= 1) {
    if (p < o) { sv[p] += sv[p + o]; su[p] += su[p + o]; }
    __syncthreads();
  }
  if (p == 0) {
    double mu = su[0] * (1.0 / NF_);
    double var = sv[0] * (1.0 / NF_) - mu * mu;
    double a = (double)g[m] / sqrt(var + 1e-5);
    A[m] = (float)a;
    D[m] = (float)((double)be[m] - a * mu);
  }
}

// ============ final pass: GEMM2 -> BN -> relu -> GEMM3 -> BN -> max over k -> relu ============
__global__ __launch_bounds__(256) void final_kernel(const float* __restrict__ Y1,
                                                    const float* __restrict__ W2,
                                                    const float* __restrict__ W3,
                                                    const float* __restrict__ A1v,
                                                    const float* __restrict__ Bc1v,
                                                    const float* __restrict__ A2v,
                                                    const float* __restrict__ D2v,
                                                    const float* __restrict__ A3v,
                                                    const float* __restrict__ D3v,
                                                    float* __restrict__ out1) {
  __shared__ float W2L[64 * 128];   // aliased as W3c in phase B
  __shared__ float ab[128];
  __shared__ float X2s[128 * 68];
  float* W3c = W2L;
  const int t = threadIdx.x;
#pragma unroll
  for (int p = 0; p < 32; ++p) {
    int idx = t + 256 * p;
    int m = idx >> 6, k = idx & 63;
    W2L[k * 128 + m] = W2[m * 64 + k];
  }
  if (t < 64) { ab[t] = A1v[t]; ab[64 + t] = Bc1v[t]; }
  const int tmA = t >> 4, tcA = t & 15;
  const int tm3 = t & 31, tcol = t >> 5;
  float a2r[8], d2r[8], a3r[8], d3r[8];
#pragma unroll
  for (int i = 0; i < 8; ++i) {
    a2r[i] = A2v[tmA * 8 + i];
    d2r[i] = D2v[tmA * 8 + i];
    a3r[i] = A3v[tm3 * 8 + i];
    d3r[i] = D3v[tm3 * 8 + i];
  }
  __syncthreads();
  const int ch = blockIdx.x;
  const size_t n0 = (size_t)ch * 64;
  {
    float acc[8][4];
#pragma unroll
    for (int i = 0; i < 8; ++i)
#pragma unroll
      for (int j = 0; j < 4; ++j) acc[i][j] = 0.f;
#pragma unroll 2
    for (int k = 0; k < 64; ++k) {
      float4 y4 = *reinterpret_cast<const float4*>(&Y1[(size_t)k * NF_ + n0 + tcA * 4]);
      float a1 = ab[k], c1 = ab[64 + k];
      float bx[4];
      bx[0] = fmaxf(fmaf(y4.x, a1, c1), 0.f);
      bx[1] = fmaxf(fmaf(y4.y, a1, c1), 0.f);
      bx[2] = fmaxf(fmaf(y4.z, a1, c1), 0.f);
      bx[3] = fmaxf(fmaf(y4.w, a1, c1), 0.f);
      const float4* ap = reinterpret_cast<const float4*>(&W2L[k * 128 + tmA * 8]);
      float4 a0 = ap[0], a4 = ap[1];
      const float av[8] = {a0.x, a0.y, a0.z, a0.w, a4.x, a4.y, a4.z, a4.w};
#pragma unroll
      for (int i = 0; i < 8; ++i)
#pragma unroll
        for (int j = 0; j < 4; ++j) acc[i][j] = fmaf(av[i], bx[j], acc[i][j]);
    }
#pragma unroll
    for (int i = 0; i < 8; ++i) {
      float4 v;
      v.x = fmaxf(fmaf(acc[i][0], a2r[i], d2r[i]), 0.f);
      v.y = fmaxf(fmaf(acc[i][1], a2r[i], d2r[i]), 0.f);
      v.z = fmaxf(fmaf(acc[i][2], a2r[i], d2r[i]), 0.f);
      v.w = fmaxf(fmaf(acc[i][3], a2r[i], d2r[i]), 0.f);
      *reinterpret_cast<float4*>(&X2s[(tmA * 8 + i) * 68 + tcA * 4]) = v;
    }
  }
  __syncthreads();
  float acc3[8][8];
#pragma unroll
  for (int i = 0; i < 8; ++i)
#pragma unroll
    for (int j = 0; j < 8; ++j) acc3[i][j] = 0.f;
  for (int kc = 0; kc < 8; ++kc) {
#pragma unroll
    for (int q = 0; q < 4; ++q) {
      float4 w = *reinterpret_cast<const float4*>(&W3[(size_t)t * 128 + kc * 16 + q * 4]);
      W3c[(q * 4 + 0) * 256 + t] = w.x;
      W3c[(q * 4 + 1) * 256 + t] = w.y;
      W3c[(q * 4 + 2) * 256 + t] = w.z;
      W3c[(q * 4 + 3) * 256 + t] = w.w;
    }
    __syncthreads();
#pragma unroll
    for (int kk = 0; kk < 16; ++kk) {
      const float4* ap = reinterpret_cast<const float4*>(&W3c[kk * 256 + tm3 * 8]);
      float4 a0 = ap[0], a4 = ap[1];
      const float4* bp = reinterpret_cast<const float4*>(&X2s[(kc * 16 + kk) * 68 + tcol * 8]);
      float4 b0 = bp[0], b4 = bp[1];
      const float av[8] = {a0.x, a0.y, a0.z, a0.w, a4.x, a4.y, a4.z, a4.w};
      const float bw[8] = {b0.x, b0.y, b0.z, b0.w, b4.x, b4.y, b4.z, b4.w};
#pragma unroll
      for (int i = 0; i < 8; ++i)
#pragma unroll
        for (int j = 0; j < 8; ++j) acc3[i][j] = fmaf(av[i], bw[j], acc3[i][j]);
    }
    __syncthreads();
  }
#pragma unroll
  for (int i = 0; i < 8; ++i) {
    float mx = -__builtin_inff();
#pragma unroll
    for (int j = 0; j < 8; ++j) {
      float v = fmaf(acc3[i][j], a3r[i], d3r[i]);
      mx = fmaxf(mx, v);
    }
    float o = __shfl_xor(mx, 32, 64);
    mx = fmaxf(mx, o);
    if ((tcol & 1) == 0) {
      int g = tcol >> 1;
      int bs = ch * 4 + g;
      int b = bs / S_;
      int s = bs - b * S_;
      out1[((size_t)(b * 256 + tm3 * 8 + i)) * S_ + s] = fmaxf(mx, 0.f);
    }
  }
}

__global__ void diag_kernel(float* out, float v) {
  if (threadIdx.x == 0 && blockIdx.x == 0) out[0] = v;
}

extern "C" void kernel_launch(void* const* d_in, const int* in_sizes, int n_in,
                              void* d_out, int out_size, void* d_ws, size_t ws_size,
                              hipStream_t stream) {
  const float* xy  = (const float*)d_in[0];
  const float* fea = (const float*)d_in[1];
  const float* W1  = (const float*)d_in[2];
  const float* b1  = (const float*)d_in[3];
  const float* g1  = (const float*)d_in[4];
  const float* be1 = (const float*)d_in[5];
  const float* W2  = (const float*)d_in[6];
  const float* g2  = (const float*)d_in[8];
  const float* be2 = (const float*)d_in[9];
  const float* W3  = (const float*)d_in[10];
  const float* g3  = (const float*)d_in[12];
  const float* be3 = (const float*)d_in[13];
  float* out = (float*)d_out;
  float* out1 = out + B_ * 2 * S_;

  char* w = (char*)d_ws;
  size_t off = 0;
  auto take = [&](size_t bytes) -> void* {
    void* p = w + off;
    off += (bytes + 255) & ~(size_t)255;
    return p;
  };
  int*    fps_idx = (int*)take((size_t)B_ * S_ * 4);
  float*  new_xyz = (float*)take((size_t)B_ * S_ * 2 * 4);
  int*    knn_sel = (int*)take((size_t)NF_ * 4);
  float*  P       = (float*)take((size_t)B_ * N_ * 64 * 4);   // 8.4 MB
  float*  Y1      = (float*)take((size_t)64 * NF_ * 4);       // 67.2 MB
  double* Sy1     = (double*)take(64 * 8);
  double* Sq1     = (double*)take(64 * 8);
  float*  A1      = (float*)take(64 * 4);
  float*  Bc1     = (float*)take(64 * 4);
  float*  partsGA = (float*)take((size_t)256 * 4160 * 4);     // 4.3 MB
  double* G1d     = (double*)take((size_t)4096 * 8);
  double* S1d     = (double*)take(64 * 8);
  float*  A2      = (float*)take(128 * 4);
  float*  D2      = (float*)take(128 * 4);
  float*  partsGB = (float*)take((size_t)256 * 16512 * 4);    // 16.9 MB
  double* G2d     = (double*)take((size_t)16384 * 8);         // 128 KB
  double* S2d     = (double*)take(128 * 8);
  float*  A3      = (float*)take(256 * 4);
  float*  D3      = (float*)take(256 * 4);

  if (off > ws_size) {
    diag_kernel<<<1, 64, 0, stream>>>(out, (float)(ws_size >> 20));
    return;
  }

  fps_pk_kernel<<<16 + 512, 256, 0, stream>>>(xy, fea, W1, fps_idx, new_xyz, out, P);
  knn_kernel<<<dim3((S_ + 15) / 16, B_), 256, 0, stream>>>(xy, fps_idx, knn_sel);
  yk1_kernel<<<NF_ / 256, 256, 0, stream>>>(xy, knn_sel, new_xyz, P, W1, b1, Y1);

  rowstats_kernel<<<64, 1024, 0, stream>>>(Y1, Sy1, Sq1);
  absch_kernel<<<1, 64, 0, stream>>>(Sy1, Sq1, g1, be1, A1, Bc1, 64);

  gramA_kernel<<<256, 256, 0, stream>>>(Y1, A1, Bc1, partsGA);
  redG_kernel<<<17, 256, 0, stream>>>(partsGA, G1d, S1d, 256, 4160, 4096, 64);
  abschG_kernel<<<128, 64, 0, stream>>>(G1d, S1d, W2, g2, be2, A2, D2);

  gramB_kernel<<<256, 256, 0, stream>>>(Y1, W2, A1, Bc1, A2, D2, partsGB);
  redG_kernel<<<65, 256, 0, stream>>>(partsGB, G2d, S2d, 256, 16512, 16384, 128);
  abschG_kernel<<<256, 128, 0, stream>>>(G2d, S2d, W3, g3, be3, A3, D3);

  final_kernel<<<NCH_, 256, 0, stream>>>(Y1, W2, W3, A1, Bc1, A2, D2, A3, D3, out1);
}

// Round 11
// 2546.866 us; speedup vs baseline: 1.5286x; 1.5286x over previous
//
#include <hip/hip_runtime.h>
#include <math.h>

#define B_   16
#define N_   2048
#define S_   1025
#define K_   16
#define EMB_ 64
#define NF_  (B_ * S_ * K_)   // 262400
#define NCH_ (NF_ / 64)       // 4100 column-chunks of 64

typedef float v2f __attribute__((ext_vector_type(2)));

// ======== FUSED: blocks 0-15 = FPS (round-8 validated body) ; blocks 16+ = pk ========
__global__ __launch_bounds__(256) __attribute__((amdgpu_waves_per_eu(1, 1)))
void fps_pk_kernel(const float* __restrict__ xy, const float* __restrict__ fea,
                   const float* __restrict__ W1,
                   int* __restrict__ fps_idx, float* __restrict__ new_xyz,
                   float* __restrict__ out0, float* __restrict__ P) {
  __shared__ float smem[8192];   // 32 KB union
  if (blockIdx.x < 16) {
    const int b = blockIdx.x;
    float2* lxy = reinterpret_cast<float2*>(smem);   // 16 KB
    const int lane = threadIdx.x;
    const float* xb = xy + (size_t)b * 2 * N_;
    v2f pxp[16], pyp[16];
    float dist[32];
    if (lane < 64) {
      const float2* xb2 = (const float2*)xb;
      const float2* yb2 = (const float2*)(xb + N_);
#pragma unroll
      for (int q = 0; q < 16; ++q) {
        float2 x01 = xb2[lane * 16 + q];
        float2 y01 = yb2[lane * 16 + q];
        int p = lane * 32 + 2 * q;
        lxy[p] = make_float2(x01.x, y01.x);
        lxy[p + 1] = make_float2(x01.y, y01.y);
        pxp[q][0] = x01.x; pxp[q][1] = x01.y;
        pyp[q][0] = y01.x; pyp[q][1] = y01.y;
        dist[2 * q] = __builtin_inff();
        dist[2 * q + 1] = __builtin_inff();
      }
#pragma unroll
      for (int q = 0; q < 16; ++q) {   // opaque pin: true VGPR residency
        asm volatile("" : "+v"(pxp[q]), "+v"(pyp[q]));
      }
    }
    __syncthreads();
    if (lane < 64) {
      int cur = 0;
      for (int t = 0; t < S_; ++t) {
        float2 c = lxy[cur];          // uniform-address broadcast read
        if (lane == 0) {
          fps_idx[b * S_ + t] = cur;
          new_xyz[(b * S_ + t) * 2 + 0] = c.x;
          new_xyz[(b * S_ + t) * 2 + 1] = c.y;
          out0[b * 2 * S_ + t] = c.x;
          out0[b * 2 * S_ + S_ + t] = c.y;
        }
        const float ncx = -c.x, ncy = -c.y;  // pk_add(x,-c) == rn(x-c)
        v2f ncx2; ncx2[0] = ncx; ncx2[1] = ncx;
        v2f ncy2; ncy2[0] = ncy; ncy2[1] = ncy;
        float lmax0 = -__builtin_inff(), lmax1 = -__builtin_inff();
#pragma unroll
        for (int q = 0; q < 16; ++q) {
          v2f dx, dy, sx, sy, dd;
          asm("v_pk_add_f32 %0, %1, %2" : "=v"(dx) : "v"(pxp[q]), "v"(ncx2));
          asm("v_pk_add_f32 %0, %1, %2" : "=v"(dy) : "v"(pyp[q]), "v"(ncy2));
          asm("v_pk_mul_f32 %0, %1, %1" : "=v"(sx) : "v"(dx));
          asm("v_pk_mul_f32 %0, %1, %1" : "=v"(sy) : "v"(dy));
          asm("v_pk_add_f32 %0, %1, %2" : "=v"(dd) : "v"(sx), "v"(sy));
          float nd0 = fminf(dist[2 * q], dd[0]);
          float nd1 = fminf(dist[2 * q + 1], dd[1]);
          dist[2 * q] = nd0;
          dist[2 * q + 1] = nd1;
          lmax0 = fmaxf(lmax0, nd0);
          lmax1 = fmaxf(lmax1, nd1);
        }
        const float lmax = fmaxf(lmax0, lmax1);
        int xr = __float_as_int(lmax);
#define DPP_MAX_STEP(CTRL)                                                        \
        {                                                                         \
          int tmp_ = __builtin_amdgcn_update_dpp(xr, xr, (CTRL), 0xF, 0xF, false);\
          xr = __float_as_int(fmaxf(__int_as_float(xr), __int_as_float(tmp_)));   \
        }
        DPP_MAX_STEP(0x111)
        DPP_MAX_STEP(0x112)
        DPP_MAX_STEP(0x114)
        DPP_MAX_STEP(0x118)
        DPP_MAX_STEP(0x142)
        DPP_MAX_STEP(0x143)
#undef DPP_MAX_STEP
        const float g = __int_as_float(__builtin_amdgcn_readlane(xr, 63));
        int lf = 0;
#pragma unroll
        for (int j = 31; j >= 0; --j)
          if (dist[j] == g) lf = j;             // descending scan keeps lowest j
        unsigned long long mask = __ballot(lmax == g);
        int first = __ffsll(mask) - 1;          // lowest lane with the max
        cur = __builtin_amdgcn_readlane(lane * 32 + lf, first);
      }
    }
  } else {
    // ---------------- pk: P[b][pt][c] = sum_e W1[c][2+e]*fea[b][e][pt] ----------------
    const int bid = blockIdx.x - 16;
    const int t = threadIdx.x;
    const int b = bid >> 5;
    const int pt0 = (bid & 31) << 6;
    float* W1L = smem;            // [e][c] 16 KB
    float* feaL = smem + 4096;    // [e][pt] 16 KB
#pragma unroll
    for (int p = 0; p < 16; ++p) {
      int idx = t + 256 * p;
      int c = idx >> 6, e = idx & 63;
      W1L[e * 64 + c] = W1[c * 66 + 2 + e];
      int r = (t >> 6) + 4 * p, cc = t & 63;
      feaL[r * 64 + cc] = fea[((size_t)b * 64 + r) * N_ + pt0 + cc];
    }
    __syncthreads();
    const int tpt = t & 15, tcq = t >> 4;
    float acc[4][4];
#pragma unroll
    for (int i = 0; i < 4; ++i)
#pragma unroll
      for (int j = 0; j < 4; ++j) acc[i][j] = 0.f;
    for (int e = 0; e < 64; ++e) {
      float4 a4 = *reinterpret_cast<const float4*>(&W1L[e * 64 + tcq * 4]);
      float4 b4 = *reinterpret_cast<const float4*>(&feaL[e * 64 + tpt * 4]);
      const float av[4] = {a4.x, a4.y, a4.z, a4.w};
      const float bvv[4] = {b4.x, b4.y, b4.z, b4.w};
#pragma unroll
      for (int i = 0; i < 4; ++i)
#pragma unroll
        for (int j = 0; j < 4; ++j) acc[i][j] = fmaf(av[i], bvv[j], acc[i][j]);
    }
#pragma unroll
    for (int j = 0; j < 4; ++j) {
      int pt = tpt * 4 + j;
      float4 v = {acc[0][j], acc[1][j], acc[2][j], acc[3][j]};
      *reinterpret_cast<float4*>(&P[((size_t)(b * N_ + pt0 + pt)) * 64 + tcq * 4]) = v;
    }
  }
}

// ---------------- KNN fp64-exact, 16 lanes per query point (validated) ----------------
__global__ __launch_bounds__(256) void knn_kernel(const float* __restrict__ xy,
                                                  const int* __restrict__ fps_idx,
                                                  int* __restrict__ knn_sel) {
  const int b = blockIdx.y;
  __shared__ float2 lxy[N_];
  __shared__ double lsq[N_];
  const float* xb = xy + (size_t)b * 2 * N_;
  for (int p = threadIdx.x; p < N_; p += 256) {
    float x = xb[p], y = xb[N_ + p];
    lxy[p] = make_float2(x, y);
    lsq[p] = (double)x * (double)x + (double)y * (double)y;
  }
  __syncthreads();
  const int t = threadIdx.x;
  const int s = blockIdx.x * 16 + (t >> 4);
  if (s >= S_) return;
  const int oct = t & 15;
  const int p0 = fps_idx[b * S_ + s];
  float2 q = lxy[p0];
  const double xn = (double)q.x, yn = (double)q.y;
  const double sqn = lsq[p0];
  double d16[16];
  int i16[16];
#pragma unroll
  for (int j = 0; j < 16; ++j) { d16[j] = __builtin_inf(); i16[j] = 0x7fffffff; }
  const int mlo = oct * 128;
  for (int m0 = mlo; m0 < mlo + 128; m0 += 4) {
    double dd[4];
#pragma unroll
    for (int u = 0; u < 4; ++u) {
      float2 p = lxy[m0 + u];
      double dot = (double)p.x * xn + (double)p.y * yn;
      dd[u] = (sqn - 2.0 * dot) + lsq[m0 + u];
    }
#pragma unroll
    for (int u = 0; u < 4; ++u) {
      if (dd[u] < d16[15]) {
        double d = dd[u];
        int mi = m0 + u;
#pragma unroll
        for (int j = 15; j >= 1; --j) {
          bool shift = d < d16[j - 1];
          bool ins = d < d16[j];
          d16[j] = shift ? d16[j - 1] : (ins ? d : d16[j]);
          i16[j] = shift ? i16[j - 1] : (ins ? mi : i16[j]);
        }
        if (d < d16[0]) { d16[0] = d; i16[0] = mi; }
      }
    }
  }
#pragma unroll
  for (int w = 1; w <= 8; w <<= 1) {
    double nd[16]; int ni[16];
#pragma unroll
    for (int i = 0; i < 16; ++i) {
      double rd = __shfl_xor(d16[15 - i], w, 64);
      int ri = __shfl_xor(i16[15 - i], w, 64);
      bool takeR = (rd < d16[i]) || (rd == d16[i] && ri < i16[i]);
      nd[i] = takeR ? rd : d16[i];
      ni[i] = takeR ? ri : i16[i];
    }
#pragma unroll
    for (int i = 0; i < 16; ++i) { d16[i] = nd[i]; i16[i] = ni[i]; }
    if (w < 8) {
#pragma unroll
      for (int dstg = 8; dstg >= 1; dstg >>= 1) {
#pragma unroll
        for (int i = 0; i < 16; ++i) {
          if ((i & dstg) == 0) {
            int a = i, c = i + dstg;
            bool sw = (d16[a] > d16[c]) || (d16[a] == d16[c] && i16[a] > i16[c]);
            double tlo = sw ? d16[c] : d16[a];
            double thi = sw ? d16[a] : d16[c];
            int ulo = sw ? i16[c] : i16[a];
            int uhi = sw ? i16[a] : i16[c];
            d16[a] = tlo; d16[c] = thi; i16[a] = ulo; i16[c] = uhi;
          }
        }
      }
    }
  }
  if (oct == 0) {
    int* dst = knn_sel + ((size_t)b * S_ + s) * K_;
#pragma unroll
    for (int j = 0; j < 16; ++j) dst[j] = i16[j];
  }
}

// ---------------- Y1[64][NF]: gather P + W1a*dxy + b1 ----------------
__global__ __launch_bounds__(256) void yk1_kernel(const float* __restrict__ xy,
                                                  const int* __restrict__ knn_sel,
                                                  const float* __restrict__ new_xyz,
                                                  const float* __restrict__ P,
                                                  const float* __restrict__ W1,
                                                  const float* __restrict__ b1,
                                                  float* __restrict__ Y1) {
  __shared__ float w0s[64], w1s[64], bbs[64];
  const int t = threadIdx.x;
  if (t < 64) { w0s[t] = W1[t * 66 + 0]; w1s[t] = W1[t * 66 + 1]; bbs[t] = b1[t]; }
  __syncthreads();
  const int n = blockIdx.x * 256 + t;
  const int bs = n >> 4;
  const int b = bs / S_;
  const int nbr = knn_sel[n];
  const float dx = xy[(size_t)b * 2 * N_ + nbr] - new_xyz[bs * 2 + 0];
  const float dy = xy[(size_t)b * 2 * N_ + N_ + nbr] - new_xyz[bs * 2 + 1];
  const float* prow = &P[((size_t)(b * N_ + nbr)) * 64];
  for (int c4 = 0; c4 < 64; c4 += 4) {
    float4 p4 = *reinterpret_cast<const float4*>(&prow[c4]);
    float v0 = p4.x + w0s[c4 + 0] * dx + w1s[c4 + 0] * dy + bbs[c4 + 0];
    float v1 = p4.y + w0s[c4 + 1] * dx + w1s[c4 + 1] * dy + bbs[c4 + 1];
    float v2 = p4.z + w0s[c4 + 2] * dx + w1s[c4 + 2] * dy + bbs[c4 + 2];
    float v3 = p4.w + w0s[c4 + 3] * dx + w1s[c4 + 3] * dy + bbs[c4 + 3];
    Y1[(size_t)(c4 + 0) * NF_ + n] = v0;
    Y1[(size_t)(c4 + 1) * NF_ + n] = v1;
    Y1[(size_t)(c4 + 2) * NF_ + n] = v2;
    Y1[(size_t)(c4 + 3) * NF_ + n] = v3;
  }
}

// ---------------- per-row sum + sumsq in one pass (fp64) ----------------
__global__ __launch_bounds__(1024) void rowstats_kernel(const float* __restrict__ Y,
                                                        double* __restrict__ sum_out,
                                                        double* __restrict__ sq_out) {
  const int r = blockIdx.x;
  const float* row = Y + (size_t)r * NF_;
  double s = 0.0, s2 = 0.0;
  for (int i = threadIdx.x * 4; i < NF_; i += 4096) {
    float4 v = *reinterpret_cast<const float4*>(&row[i]);
    double dx = v.x, dy = v.y, dz = v.z, dw = v.w;
    s += (dx + dy) + (dz + dw);
    s2 = fma(dx, dx, s2); s2 = fma(dy, dy, s2);
    s2 = fma(dz, dz, s2); s2 = fma(dw, dw, s2);
  }
  __shared__ double sh[1024], sh2[1024];
  sh[threadIdx.x] = s; sh2[threadIdx.x] = s2;
  __syncthreads();
  for (int o = 512; o > 0; o >>= 1) {
    if (threadIdx.x < o) {
      sh[threadIdx.x] += sh[threadIdx.x + o];
      sh2[threadIdx.x] += sh2[threadIdx.x + o];
    }
    __syncthreads();
  }
  if (threadIdx.x == 0) { sum_out[r] = sh[0]; sq_out[r] = sh2[0]; }
}

// ---------------- BN coeffs from sum/sumsq (validated) ----------------
__global__ void absch_kernel(const double* __restrict__ sumv, const double* __restrict__ sqv,
                             const float* __restrict__ g, const float* __restrict__ be,
                             float* __restrict__ A, float* __restrict__ D, int M) {
  int m = threadIdx.x;
  if (m >= M) return;
  double mu = sumv[m] * (1.0 / NF_);
  double var = sqv[m] * (1.0 / NF_) - mu * mu;
  double a = (double)g[m] / sqrt(var + 1e-5);
  A[m] = (float)a;
  D[m] = (float)((double)be[m] - a * mu);
}

// ---------------- reduce partials [P][2M] -> sum[M], sq[M] (fp64) ----------------
__global__ void redab_kernel(const float* __restrict__ parts, double* __restrict__ sum_out,
                             double* __restrict__ sq_out, int P, int M) {
  int m = threadIdx.x;
  if (m >= M) return;
  double a = 0.0, b = 0.0;
  for (int p = 0; p < P; ++p) {
    a += (double)parts[(size_t)p * 2 * M + m];
    b += (double)parts[(size_t)p * 2 * M + M + m];
  }
  sum_out[m] = a;
  sq_out[m] = b;
}

// ============ passA: GEMM2 per chunk, accumulate sum(y2), sum(y2^2) ============
__global__ __launch_bounds__(256) void passA_kernel(const float* __restrict__ Y1,
                                                    const float* __restrict__ W2,
                                                    const float* __restrict__ A1v,
                                                    const float* __restrict__ Bc1v,
                                                    float* __restrict__ parts) {
  __shared__ float W2L[64 * 128];
  __shared__ float ab[128];
  __shared__ float vpart[16][128];
  const int t = threadIdx.x;
#pragma unroll
  for (int p = 0; p < 32; ++p) {
    int idx = t + 256 * p;
    int m = idx >> 6, k = idx & 63;
    W2L[k * 128 + m] = W2[m * 64 + k];
  }
  if (t < 64) { ab[t] = A1v[t]; ab[64 + t] = Bc1v[t]; }
  const int tmA = t >> 4, tcA = t & 15;
  float vs[8], vq[8];
#pragma unroll
  for (int i = 0; i < 8; ++i) { vs[i] = 0.f; vq[i] = 0.f; }
  __syncthreads();
  for (int ch = blockIdx.x; ch < NCH_; ch += 512) {
    const size_t n0 = (size_t)ch * 64;
    float acc[8][4];
#pragma unroll
    for (int i = 0; i < 8; ++i)
#pragma unroll
      for (int j = 0; j < 4; ++j) acc[i][j] = 0.f;
#pragma unroll 2
    for (int k = 0; k < 64; ++k) {
      float4 y4 = *reinterpret_cast<const float4*>(&Y1[(size_t)k * NF_ + n0 + tcA * 4]);
      float a1 = ab[k], c1 = ab[64 + k];
      float bx[4];
      bx[0] = fmaxf(fmaf(y4.x, a1, c1), 0.f);
      bx[1] = fmaxf(fmaf(y4.y, a1, c1), 0.f);
      bx[2] = fmaxf(fmaf(y4.z, a1, c1), 0.f);
      bx[3] = fmaxf(fmaf(y4.w, a1, c1), 0.f);
      const float4* ap = reinterpret_cast<const float4*>(&W2L[k * 128 + tmA * 8]);
      float4 a0 = ap[0], a4 = ap[1];
      const float av[8] = {a0.x, a0.y, a0.z, a0.w, a4.x, a4.y, a4.z, a4.w};
#pragma unroll
      for (int i = 0; i < 8; ++i)
#pragma unroll
        for (int j = 0; j < 4; ++j) acc[i][j] = fmaf(av[i], bx[j], acc[i][j]);
    }
#pragma unroll
    for (int i = 0; i < 8; ++i)
#pragma unroll
      for (int j = 0; j < 4; ++j) {
        float y = acc[i][j];
        vs[i] += y;
        vq[i] = fmaf(y, y, vq[i]);
      }
  }
#pragma unroll
  for (int i = 0; i < 8; ++i) vpart[tcA][tmA * 8 + i] = vs[i];
  __syncthreads();
  if (t < 128) {
    float s = 0.f;
    for (int q = 0; q < 16; ++q) s += vpart[q][t];
    parts[(size_t)blockIdx.x * 256 + t] = s;
  }
  __syncthreads();
#pragma unroll
  for (int i = 0; i < 8; ++i) vpart[tcA][tmA * 8 + i] = vq[i];
  __syncthreads();
  if (t < 128) {
    float s = 0.f;
    for (int q = 0; q < 16; ++q) s += vpart[q][t];
    parts[(size_t)blockIdx.x * 256 + 128 + t] = s;
  }
}

// ============ passB: GEMM2 -> x2 -> GEMM3 per chunk, accumulate sum(y3), sum(y3^2) ============
__global__ __launch_bounds__(256) void passB_kernel(const float* __restrict__ Y1,
                                                    const float* __restrict__ W2,
                                                    const float* __restrict__ W3,
                                                    const float* __restrict__ A1v,
                                                    const float* __restrict__ Bc1v,
                                                    const float* __restrict__ A2v,
                                                    const float* __restrict__ D2v,
                                                    float* __restrict__ parts) {
  __shared__ float W2L[64 * 128];
  __shared__ float ab[128];
  __shared__ float X2s[128 * 68];
  __shared__ float W3c[16 * 256];
  __shared__ float vpart3[8][256];
  const int t = threadIdx.x;
#pragma unroll
  for (int p = 0; p < 32; ++p) {
    int idx = t + 256 * p;
    int m = idx >> 6, k = idx & 63;
    W2L[k * 128 + m] = W2[m * 64 + k];
  }
  if (t < 64) { ab[t] = A1v[t]; ab[64 + t] = Bc1v[t]; }
  const int tmA = t >> 4, tcA = t & 15;
  const int tm3 = t & 31, tcol = t >> 5;
  float a2r[8], d2r[8], vs[8], vq[8];
#pragma unroll
  for (int i = 0; i < 8; ++i) {
    a2r[i] = A2v[tmA * 8 + i];
    d2r[i] = D2v[tmA * 8 + i];
    vs[i] = 0.f; vq[i] = 0.f;
  }
  __syncthreads();
  for (int ch = blockIdx.x; ch < NCH_; ch += 256) {
    const size_t n0 = (size_t)ch * 64;
    {
      float acc[8][4];
#pragma unroll
      for (int i = 0; i < 8; ++i)
#pragma unroll
        for (int j = 0; j < 4; ++j) acc[i][j] = 0.f;
#pragma unroll 2
      for (int k = 0; k < 64; ++k) {
        float4 y4 = *reinterpret_cast<const float4*>(&Y1[(size_t)k * NF_ + n0 + tcA * 4]);
        float a1 = ab[k], c1 = ab[64 + k];
        float bx[4];
        bx[0] = fmaxf(fmaf(y4.x, a1, c1), 0.f);
        bx[1] = fmaxf(fmaf(y4.y, a1, c1), 0.f);
        bx[2] = fmaxf(fmaf(y4.z, a1, c1), 0.f);
        bx[3] = fmaxf(fmaf(y4.w, a1, c1), 0.f);
        const float4* ap = reinterpret_cast<const float4*>(&W2L[k * 128 + tmA * 8]);
        float4 a0 = ap[0], a4 = ap[1];
        const float av[8] = {a0.x, a0.y, a0.z, a0.w, a4.x, a4.y, a4.z, a4.w};
#pragma unroll
        for (int i = 0; i < 8; ++i)
#pragma unroll
          for (int j = 0; j < 4; ++j) acc[i][j] = fmaf(av[i], bx[j], acc[i][j]);
      }
#pragma unroll
      for (int i = 0; i < 8; ++i) {
        float4 v;
        v.x = fmaxf(fmaf(acc[i][0], a2r[i], d2r[i]), 0.f);
        v.y = fmaxf(fmaf(acc[i][1], a2r[i], d2r[i]), 0.f);
        v.z = fmaxf(fmaf(acc[i][2], a2r[i], d2r[i]), 0.f);
        v.w = fmaxf(fmaf(acc[i][3], a2r[i], d2r[i]), 0.f);
        *reinterpret_cast<float4*>(&X2s[(tmA * 8 + i) * 68 + tcA * 4]) = v;
      }
    }
    __syncthreads();
    float acc3[8][8];
#pragma unroll
    for (int i = 0; i < 8; ++i)
#pragma unroll
      for (int j = 0; j < 8; ++j) acc3[i][j] = 0.f;
    for (int kc = 0; kc < 8; ++kc) {
#pragma unroll
      for (int q = 0; q < 4; ++q) {
        float4 w = *reinterpret_cast<const float4*>(&W3[(size_t)t * 128 + kc * 16 + q * 4]);
        W3c[(q * 4 + 0) * 256 + t] = w.x;
        W3c[(q * 4 + 1) * 256 + t] = w.y;
        W3c[(q * 4 + 2) * 256 + t] = w.z;
        W3c[(q * 4 + 3) * 256 + t] = w.w;
      }
      __syncthreads();
#pragma unroll
      for (int kk = 0; kk < 16; ++kk) {
        const float4* ap = reinterpret_cast<const float4*>(&W3c[kk * 256 + tm3 * 8]);
        float4 a0 = ap[0], a4 = ap[1];
        const float4* bp = reinterpret_cast<const float4*>(&X2s[(kc * 16 + kk) * 68 + tcol * 8]);
        float4 b0 = bp[0], b4 = bp[1];
        const float av[8] = {a0.x, a0.y, a0.z, a0.w, a4.x, a4.y, a4.z, a4.w};
        const float bw[8] = {b0.x, b0.y, b0.z, b0.w, b4.x, b4.y, b4.z, b4.w};
#pragma unroll
        for (int i = 0; i < 8; ++i)
#pragma unroll
          for (int j = 0; j < 8; ++j) acc3[i][j] = fmaf(av[i], bw[j], acc3[i][j]);
      }
      __syncthreads();
    }
#pragma unroll
    for (int i = 0; i < 8; ++i)
#pragma unroll
      for (int j = 0; j < 8; ++j) {
        float y = acc3[i][j];
        vs[i] += y;
        vq[i] = fmaf(y, y, vq[i]);
      }
    __syncthreads();
  }
#pragma unroll
  for (int i = 0; i < 8; ++i) vpart3[tcol][tm3 * 8 + i] = vs[i];
  __syncthreads();
  {
    float s = 0.f;
    for (int q = 0; q < 8; ++q) s += vpart3[q][t];
    parts[(size_t)blockIdx.x * 512 + t] = s;
  }
  __syncthreads();
#pragma unroll
  for (int i = 0; i < 8; ++i) vpart3[tcol][tm3 * 8 + i] = vq[i];
  __syncthreads();
  {
    float s = 0.f;
    for (int q = 0; q < 8; ++q) s += vpart3[q][t];
    parts[(size_t)blockIdx.x * 512 + 256 + t] = s;
  }
}

// ============ final pass: GEMM2 -> BN -> relu -> GEMM3 -> BN -> max over k -> relu ============
__global__ __launch_bounds__(256) void final_kernel(const float* __restrict__ Y1,
                                                    const float* __restrict__ W2,
                                                    const float* __restrict__ W3,
                                                    const float* __restrict__ A1v,
                                                    const float* __restrict__ Bc1v,
                                                    const float* __restrict__ A2v,
                                                    const float* __restrict__ D2v,
                                                    const float* __restrict__ A3v,
                                                    const float* __restrict__ D3v,
                                                    float* __restrict__ out1) {
  __shared__ float W2L[64 * 128];   // aliased as W3c in phase B
  __shared__ float ab[128];
  __shared__ float X2s[128 * 68];
  float* W3c = W2L;
  const int t = threadIdx.x;
#pragma unroll
  for (int p = 0; p < 32; ++p) {
    int idx = t + 256 * p;
    int m = idx >> 6, k = idx & 63;
    W2L[k * 128 + m] = W2[m * 64 + k];
  }
  if (t < 64) { ab[t] = A1v[t]; ab[64 + t] = Bc1v[t]; }
  const int tmA = t >> 4, tcA = t & 15;
  const int tm3 = t & 31, tcol = t >> 5;
  float a2r[8], d2r[8], a3r[8], d3r[8];
#pragma unroll
  for (int i = 0; i < 8; ++i) {
    a2r[i] = A2v[tmA * 8 + i];
    d2r[i] = D2v[tmA * 8 + i];
    a3r[i] = A3v[tm3 * 8 + i];
    d3r[i] = D3v[tm3 * 8 + i];
  }
  __syncthreads();
  const int ch = blockIdx.x;
  const size_t n0 = (size_t)ch * 64;
  {
    float acc[8][4];
#pragma unroll
    for (int i = 0; i < 8; ++i)
#pragma unroll
      for (int j = 0; j < 4; ++j) acc[i][j] = 0.f;
#pragma unroll 2
    for (int k = 0; k < 64; ++k) {
      float4 y4 = *reinterpret_cast<const float4*>(&Y1[(size_t)k * NF_ + n0 + tcA * 4]);
      float a1 = ab[k], c1 = ab[64 + k];
      float bx[4];
      bx[0] = fmaxf(fmaf(y4.x, a1, c1), 0.f);
      bx[1] = fmaxf(fmaf(y4.y, a1, c1), 0.f);
      bx[2] = fmaxf(fmaf(y4.z, a1, c1), 0.f);
      bx[3] = fmaxf(fmaf(y4.w, a1, c1), 0.f);
      const float4* ap = reinterpret_cast<const float4*>(&W2L[k * 128 + tmA * 8]);
      float4 a0 = ap[0], a4 = ap[1];
      const float av[8] = {a0.x, a0.y, a0.z, a0.w, a4.x, a4.y, a4.z, a4.w};
#pragma unroll
      for (int i = 0; i < 8; ++i)
#pragma unroll
        for (int j = 0; j < 4; ++j) acc[i][j] = fmaf(av[i], bx[j], acc[i][j]);
    }
#pragma unroll
    for (int i = 0; i < 8; ++i) {
      float4 v;
      v.x = fmaxf(fmaf(acc[i][0], a2r[i], d2r[i]), 0.f);
      v.y = fmaxf(fmaf(acc[i][1], a2r[i], d2r[i]), 0.f);
      v.z = fmaxf(fmaf(acc[i][2], a2r[i], d2r[i]), 0.f);
      v.w = fmaxf(fmaf(acc[i][3], a2r[i], d2r[i]), 0.f);
      *reinterpret_cast<float4*>(&X2s[(tmA * 8 + i) * 68 + tcA * 4]) = v;
    }
  }
  __syncthreads();
  float acc3[8][8];
#pragma unroll
  for (int i = 0; i < 8; ++i)
#pragma unroll
    for (int j = 0; j < 8; ++j) acc3[i][j] = 0.f;
  for (int kc = 0; kc < 8; ++kc) {
#pragma unroll
    for (int q = 0; q < 4; ++q) {
      float4 w = *reinterpret_cast<const float4*>(&W3[(size_t)t * 128 + kc * 16 + q * 4]);
      W3c[(q * 4 + 0) * 256 + t] = w.x;
      W3c[(q * 4 + 1) * 256 + t] = w.y;
      W3c[(q * 4 + 2) * 256 + t] = w.z;
      W3c[(q * 4 + 3) * 256 + t] = w.w;
    }
    __syncthreads();
#pragma unroll
    for (int kk = 0; kk < 16; ++kk) {
      const float4* ap = reinterpret_cast<const float4*>(&W3c[kk * 256 + tm3 * 8]);
      float4 a0 = ap[0], a4 = ap[1];
      const float4* bp = reinterpret_cast<const float4*>(&X2s[(kc * 16 + kk) * 68 + tcol * 8]);
      float4 b0 = bp[0], b4 = bp[1];
      const float av[8] = {a0.x, a0.y, a0.z, a0.w, a4.x, a4.y, a4.z, a4.w};
      const float bw[8] = {b0.x, b0.y, b0.z, b0.w, b4.x, b4.y, b4.z, b4.w};
#pragma unroll
      for (int i = 0; i < 8; ++i)
#pragma unroll
        for (int j = 0; j < 8; ++j) acc3[i][j] = fmaf(av[i], bw[j], acc3[i][j]);
    }
    __syncthreads();
  }
#pragma unroll
  for (int i = 0; i < 8; ++i) {
    float mx = -__builtin_inff();
#pragma unroll
    for (int j = 0; j < 8; ++j) {
      float v = fmaf(acc3[i][j], a3r[i], d3r[i]);
      mx = fmaxf(mx, v);
    }
    float o = __shfl_xor(mx, 32, 64);
    mx = fmaxf(mx, o);
    if ((tcol & 1) == 0) {
      int g = tcol >> 1;
      int bs = ch * 4 + g;
      int b = bs / S_;
      int s = bs - b * S_;
      out1[((size_t)(b * 256 + tm3 * 8 + i)) * S_ + s] = fmaxf(mx, 0.f);
    }
  }
}

__global__ void diag_kernel(float* out, float v) {
  if (threadIdx.x == 0 && blockIdx.x == 0) out[0] = v;
}

extern "C" void kernel_launch(void* const* d_in, const int* in_sizes, int n_in,
                              void* d_out, int out_size, void* d_ws, size_t ws_size,
                              hipStream_t stream) {
  const float* xy  = (const float*)d_in[0];
  const float* fea = (const float*)d_in[1];
  const float* W1  = (const float*)d_in[2];
  const float* b1  = (const float*)d_in[3];
  const float* g1  = (const float*)d_in[4];
  const float* be1 = (const float*)d_in[5];
  const float* W2  = (const float*)d_in[6];
  const float* g2  = (const float*)d_in[8];
  const float* be2 = (const float*)d_in[9];
  const float* W3  = (const float*)d_in[10];
  const float* g3  = (const float*)d_in[12];
  const float* be3 = (const float*)d_in[13];
  float* out = (float*)d_out;
  float* out1 = out + B_ * 2 * S_;

  char* w = (char*)d_ws;
  size_t off = 0;
  auto take = [&](size_t bytes) -> void* {
    void* p = w + off;
    off += (bytes + 255) & ~(size_t)255;
    return p;
  };
  int*    fps_idx = (int*)take((size_t)B_ * S_ * 4);
  float*  new_xyz = (float*)take((size_t)B_ * S_ * 2 * 4);
  int*    knn_sel = (int*)take((size_t)NF_ * 4);
  float*  P       = (float*)take((size_t)B_ * N_ * 64 * 4);   // 8.4 MB
  float*  Y1      = (float*)take((size_t)64 * NF_ * 4);       // 67.2 MB
  double* Sy1     = (double*)take(64 * 8);
  double* Sq1     = (double*)take(64 * 8);
  float*  A1      = (float*)take(64 * 4);
  float*  Bc1     = (float*)take(64 * 4);
  float*  partsA  = (float*)take((size_t)512 * 256 * 4);
  double* Sy2     = (double*)take(128 * 8);
  double* Sq2     = (double*)take(128 * 8);
  float*  A2      = (float*)take(128 * 4);
  float*  D2      = (float*)take(128 * 4);
  float*  partsB  = (float*)take((size_t)256 * 512 * 4);
  double* Sy3     = (double*)take(256 * 8);
  double* Sq3     = (double*)take(256 * 8);
  float*  A3      = (float*)take(256 * 4);
  float*  D3      = (float*)take(256 * 4);

  if (off > ws_size) {
    diag_kernel<<<1, 64, 0, stream>>>(out, (float)(ws_size >> 20));
    return;
  }

  fps_pk_kernel<<<16 + 512, 256, 0, stream>>>(xy, fea, W1, fps_idx, new_xyz, out, P);
  knn_kernel<<<dim3((S_ + 15) / 16, B_), 256, 0, stream>>>(xy, fps_idx, knn_sel);
  yk1_kernel<<<NF_ / 256, 256, 0, stream>>>(xy, knn_sel, new_xyz, P, W1, b1, Y1);

  rowstats_kernel<<<64, 1024, 0, stream>>>(Y1, Sy1, Sq1);
  absch_kernel<<<1, 64, 0, stream>>>(Sy1, Sq1, g1, be1, A1, Bc1, 64);

  passA_kernel<<<512, 256, 0, stream>>>(Y1, W2, A1, Bc1, partsA);
  redab_kernel<<<1, 128, 0, stream>>>(partsA, Sy2, Sq2, 512, 128);
  absch_kernel<<<1, 128, 0, stream>>>(Sy2, Sq2, g2, be2, A2, D2, 128);

  passB_kernel<<<256, 256, 0, stream>>>(Y1, W2, W3, A1, Bc1, A2, D2, partsB);
  redab_kernel<<<1, 256, 0, stream>>>(partsB, Sy3, Sq3, 256, 256);
  absch_kernel<<<1, 256, 0, stream>>>(Sy3, Sq3, g3, be3, A3, D3, 256);

  final_kernel<<<NCH_, 256, 0, stream>>>(Y1, W2, W3, A1, Bc1, A2, D2, A3, D3, out1);
}

// Round 12
// 2052.873 us; speedup vs baseline: 1.8965x; 1.2406x over previous
//
#include <hip/hip_runtime.h>
#include <math.h>

#define B_   16
#define N_   2048
#define S_   1025
#define K_   16
#define EMB_ 64
#define NF_  (B_ * S_ * K_)   // 262400
#define NCH_ (NF_ / 64)       // 4100 column-chunks of 64

typedef float v2f __attribute__((ext_vector_type(2)));
typedef short bf16x8 __attribute__((ext_vector_type(8)));
typedef float f32x4 __attribute__((ext_vector_type(4)));

__device__ __forceinline__ unsigned short f2bf(float f) {  // RNE fp32->bf16
  unsigned u = __float_as_uint(f);
  u += 0x7fffu + ((u >> 16) & 1u);
  return (unsigned short)(u >> 16);
}

// ======== FUSED: blocks 0-15 = FPS (validated) ; blocks 16+ = pk ========
__global__ __launch_bounds__(256) __attribute__((amdgpu_waves_per_eu(1, 1)))
void fps_pk_kernel(const float* __restrict__ xy, const float* __restrict__ fea,
                   const float* __restrict__ W1,
                   int* __restrict__ fps_idx, float* __restrict__ new_xyz,
                   float* __restrict__ out0, float* __restrict__ P) {
  __shared__ float smem[8192];   // 32 KB union
  if (blockIdx.x < 16) {
    const int b = blockIdx.x;
    float2* lxy = reinterpret_cast<float2*>(smem);
    const int lane = threadIdx.x;
    const float* xb = xy + (size_t)b * 2 * N_;
    v2f pxp[16], pyp[16];
    float dist[32];
    if (lane < 64) {
      const float2* xb2 = (const float2*)xb;
      const float2* yb2 = (const float2*)(xb + N_);
#pragma unroll
      for (int q = 0; q < 16; ++q) {
        float2 x01 = xb2[lane * 16 + q];
        float2 y01 = yb2[lane * 16 + q];
        int p = lane * 32 + 2 * q;
        lxy[p] = make_float2(x01.x, y01.x);
        lxy[p + 1] = make_float2(x01.y, y01.y);
        pxp[q][0] = x01.x; pxp[q][1] = x01.y;
        pyp[q][0] = y01.x; pyp[q][1] = y01.y;
        dist[2 * q] = __builtin_inff();
        dist[2 * q + 1] = __builtin_inff();
      }
#pragma unroll
      for (int q = 0; q < 16; ++q) {
        asm volatile("" : "+v"(pxp[q]), "+v"(pyp[q]));
      }
    }
    __syncthreads();
    if (lane < 64) {
      int cur = 0;
      for (int t = 0; t < S_; ++t) {
        float2 c = lxy[cur];
        if (lane == 0) {
          fps_idx[b * S_ + t] = cur;
          new_xyz[(b * S_ + t) * 2 + 0] = c.x;
          new_xyz[(b * S_ + t) * 2 + 1] = c.y;
          out0[b * 2 * S_ + t] = c.x;
          out0[b * 2 * S_ + S_ + t] = c.y;
        }
        const float ncx = -c.x, ncy = -c.y;
        v2f ncx2; ncx2[0] = ncx; ncx2[1] = ncx;
        v2f ncy2; ncy2[0] = ncy; ncy2[1] = ncy;
        float lmax0 = -__builtin_inff(), lmax1 = -__builtin_inff();
#pragma unroll
        for (int q = 0; q < 16; ++q) {
          v2f dx, dy, sx, sy, dd;
          asm("v_pk_add_f32 %0, %1, %2" : "=v"(dx) : "v"(pxp[q]), "v"(ncx2));
          asm("v_pk_add_f32 %0, %1, %2" : "=v"(dy) : "v"(pyp[q]), "v"(ncy2));
          asm("v_pk_mul_f32 %0, %1, %1" : "=v"(sx) : "v"(dx));
          asm("v_pk_mul_f32 %0, %1, %1" : "=v"(sy) : "v"(dy));
          asm("v_pk_add_f32 %0, %1, %2" : "=v"(dd) : "v"(sx), "v"(sy));
          float nd0 = fminf(dist[2 * q], dd[0]);
          float nd1 = fminf(dist[2 * q + 1], dd[1]);
          dist[2 * q] = nd0;
          dist[2 * q + 1] = nd1;
          lmax0 = fmaxf(lmax0, nd0);
          lmax1 = fmaxf(lmax1, nd1);
        }
        const float lmax = fmaxf(lmax0, lmax1);
        int xr = __float_as_int(lmax);
#define DPP_MAX_STEP(CTRL)                                                        \
        {                                                                         \
          int tmp_ = __builtin_amdgcn_update_dpp(xr, xr, (CTRL), 0xF, 0xF, false);\
          xr = __float_as_int(fmaxf(__int_as_float(xr), __int_as_float(tmp_)));   \
        }
        DPP_MAX_STEP(0x111)
        DPP_MAX_STEP(0x112)
        DPP_MAX_STEP(0x114)
        DPP_MAX_STEP(0x118)
        DPP_MAX_STEP(0x142)
        DPP_MAX_STEP(0x143)
#undef DPP_MAX_STEP
        const float g = __int_as_float(__builtin_amdgcn_readlane(xr, 63));
        int lf = 0;
#pragma unroll
        for (int j = 31; j >= 0; --j)
          if (dist[j] == g) lf = j;
        unsigned long long mask = __ballot(lmax == g);
        int first = __ffsll(mask) - 1;
        cur = __builtin_amdgcn_readlane(lane * 32 + lf, first);
      }
    }
  } else {
    const int bid = blockIdx.x - 16;
    const int t = threadIdx.x;
    const int b = bid >> 5;
    const int pt0 = (bid & 31) << 6;
    float* W1L = smem;
    float* feaL = smem + 4096;
#pragma unroll
    for (int p = 0; p < 16; ++p) {
      int idx = t + 256 * p;
      int c = idx >> 6, e = idx & 63;
      W1L[e * 64 + c] = W1[c * 66 + 2 + e];
      int r = (t >> 6) + 4 * p, cc = t & 63;
      feaL[r * 64 + cc] = fea[((size_t)b * 64 + r) * N_ + pt0 + cc];
    }
    __syncthreads();
    const int tpt = t & 15, tcq = t >> 4;
    float acc[4][4];
#pragma unroll
    for (int i = 0; i < 4; ++i)
#pragma unroll
      for (int j = 0; j < 4; ++j) acc[i][j] = 0.f;
    for (int e = 0; e < 64; ++e) {
      float4 a4 = *reinterpret_cast<const float4*>(&W1L[e * 64 + tcq * 4]);
      float4 b4 = *reinterpret_cast<const float4*>(&feaL[e * 64 + tpt * 4]);
      const float av[4] = {a4.x, a4.y, a4.z, a4.w};
      const float bvv[4] = {b4.x, b4.y, b4.z, b4.w};
#pragma unroll
      for (int i = 0; i < 4; ++i)
#pragma unroll
        for (int j = 0; j < 4; ++j) acc[i][j] = fmaf(av[i], bvv[j], acc[i][j]);
    }
#pragma unroll
    for (int j = 0; j < 4; ++j) {
      int pt = tpt * 4 + j;
      float4 v = {acc[0][j], acc[1][j], acc[2][j], acc[3][j]};
      *reinterpret_cast<float4*>(&P[((size_t)(b * N_ + pt0 + pt)) * 64 + tcq * 4]) = v;
    }
  }
}

// ---------------- W2/W3 -> bf16 (RNE), row-major ----------------
__global__ void wconv_kernel(const float* __restrict__ W2, const float* __restrict__ W3,
                             unsigned short* __restrict__ W2b, unsigned short* __restrict__ W3b) {
  int i = blockIdx.x * 256 + threadIdx.x;
  if (i < 128 * 64) W2b[i] = f2bf(W2[i]);
  if (i < 256 * 128) W3b[i] = f2bf(W3[i]);
}

// ---------------- KNN fp64-exact (validated) ----------------
__global__ __launch_bounds__(256) void knn_kernel(const float* __restrict__ xy,
                                                  const int* __restrict__ fps_idx,
                                                  int* __restrict__ knn_sel) {
  const int b = blockIdx.y;
  __shared__ float2 lxy[N_];
  __shared__ double lsq[N_];
  const float* xb = xy + (size_t)b * 2 * N_;
  for (int p = threadIdx.x; p < N_; p += 256) {
    float x = xb[p], y = xb[N_ + p];
    lxy[p] = make_float2(x, y);
    lsq[p] = (double)x * (double)x + (double)y * (double)y;
  }
  __syncthreads();
  const int t = threadIdx.x;
  const int s = blockIdx.x * 16 + (t >> 4);
  if (s >= S_) return;
  const int oct = t & 15;
  const int p0 = fps_idx[b * S_ + s];
  float2 q = lxy[p0];
  const double xn = (double)q.x, yn = (double)q.y;
  const double sqn = lsq[p0];
  double d16[16];
  int i16[16];
#pragma unroll
  for (int j = 0; j < 16; ++j) { d16[j] = __builtin_inf(); i16[j] = 0x7fffffff; }
  const int mlo = oct * 128;
  for (int m0 = mlo; m0 < mlo + 128; m0 += 4) {
    double dd[4];
#pragma unroll
    for (int u = 0; u < 4; ++u) {
      float2 p = lxy[m0 + u];
      double dot = (double)p.x * xn + (double)p.y * yn;
      dd[u] = (sqn - 2.0 * dot) + lsq[m0 + u];
    }
#pragma unroll
    for (int u = 0; u < 4; ++u) {
      if (dd[u] < d16[15]) {
        double d = dd[u];
        int mi = m0 + u;
#pragma unroll
        for (int j = 15; j >= 1; --j) {
          bool shift = d < d16[j - 1];
          bool ins = d < d16[j];
          d16[j] = shift ? d16[j - 1] : (ins ? d : d16[j]);
          i16[j] = shift ? i16[j - 1] : (ins ? mi : i16[j]);
        }
        if (d < d16[0]) { d16[0] = d; i16[0] = mi; }
      }
    }
  }
#pragma unroll
  for (int w = 1; w <= 8; w <<= 1) {
    double nd[16]; int ni[16];
#pragma unroll
    for (int i = 0; i < 16; ++i) {
      double rd = __shfl_xor(d16[15 - i], w, 64);
      int ri = __shfl_xor(i16[15 - i], w, 64);
      bool takeR = (rd < d16[i]) || (rd == d16[i] && ri < i16[i]);
      nd[i] = takeR ? rd : d16[i];
      ni[i] = takeR ? ri : i16[i];
    }
#pragma unroll
    for (int i = 0; i < 16; ++i) { d16[i] = nd[i]; i16[i] = ni[i]; }
    if (w < 8) {
#pragma unroll
      for (int dstg = 8; dstg >= 1; dstg >>= 1) {
#pragma unroll
        for (int i = 0; i < 16; ++i) {
          if ((i & dstg) == 0) {
            int a = i, c = i + dstg;
            bool sw = (d16[a] > d16[c]) || (d16[a] == d16[c] && i16[a] > i16[c]);
            double tlo = sw ? d16[c] : d16[a];
            double thi = sw ? d16[a] : d16[c];
            int ulo = sw ? i16[c] : i16[a];
            int uhi = sw ? i16[a] : i16[c];
            d16[a] = tlo; d16[c] = thi; i16[a] = ulo; i16[c] = uhi;
          }
        }
      }
    }
  }
  if (oct == 0) {
    int* dst = knn_sel + ((size_t)b * S_ + s) * K_;
#pragma unroll
    for (int j = 0; j < 16; ++j) dst[j] = i16[j];
  }
}

// ---------------- Y1[64][NF]: gather P + W1a*dxy + b1 ----------------
__global__ __launch_bounds__(256) void yk1_kernel(const float* __restrict__ xy,
                                                  const int* __restrict__ knn_sel,
                                                  const float* __restrict__ new_xyz,
                                                  const float* __restrict__ P,
                                                  const float* __restrict__ W1,
                                                  const float* __restrict__ b1,
                                                  float* __restrict__ Y1) {
  __shared__ float w0s[64], w1s[64], bbs[64];
  const int t = threadIdx.x;
  if (t < 64) { w0s[t] = W1[t * 66 + 0]; w1s[t] = W1[t * 66 + 1]; bbs[t] = b1[t]; }
  __syncthreads();
  const int n = blockIdx.x * 256 + t;
  const int bs = n >> 4;
  const int b = bs / S_;
  const int nbr = knn_sel[n];
  const float dx = xy[(size_t)b * 2 * N_ + nbr] - new_xyz[bs * 2 + 0];
  const float dy = xy[(size_t)b * 2 * N_ + N_ + nbr] - new_xyz[bs * 2 + 1];
  const float* prow = &P[((size_t)(b * N_ + nbr)) * 64];
  for (int c4 = 0; c4 < 64; c4 += 4) {
    float4 p4 = *reinterpret_cast<const float4*>(&prow[c4]);
    float v0 = p4.x + w0s[c4 + 0] * dx + w1s[c4 + 0] * dy + bbs[c4 + 0];
    float v1 = p4.y + w0s[c4 + 1] * dx + w1s[c4 + 1] * dy + bbs[c4 + 1];
    float v2 = p4.z + w0s[c4 + 2] * dx + w1s[c4 + 2] * dy + bbs[c4 + 2];
    float v3 = p4.w + w0s[c4 + 3] * dx + w1s[c4 + 3] * dy + bbs[c4 + 3];
    Y1[(size_t)(c4 + 0) * NF_ + n] = v0;
    Y1[(size_t)(c4 + 1) * NF_ + n] = v1;
    Y1[(size_t)(c4 + 2) * NF_ + n] = v2;
    Y1[(size_t)(c4 + 3) * NF_ + n] = v3;
  }
}

// ---------------- per-row sum + sumsq (fp64) ----------------
__global__ __launch_bounds__(1024) void rowstats_kernel(const float* __restrict__ Y,
                                                        double* __restrict__ sum_out,
                                                        double* __restrict__ sq_out) {
  const int r = blockIdx.x;
  const float* row = Y + (size_t)r * NF_;
  double s = 0.0, s2 = 0.0;
  for (int i = threadIdx.x * 4; i < NF_; i += 4096) {
    float4 v = *reinterpret_cast<const float4*>(&row[i]);
    double dx = v.x, dy = v.y, dz = v.z, dw = v.w;
    s += (dx + dy) + (dz + dw);
    s2 = fma(dx, dx, s2); s2 = fma(dy, dy, s2);
    s2 = fma(dz, dz, s2); s2 = fma(dw, dw, s2);
  }
  __shared__ double sh[1024], sh2[1024];
  sh[threadIdx.x] = s; sh2[threadIdx.x] = s2;
  __syncthreads();
  for (int o = 512; o > 0; o >>= 1) {
    if (threadIdx.x < o) {
      sh[threadIdx.x] += sh[threadIdx.x + o];
      sh2[threadIdx.x] += sh2[threadIdx.x + o];
    }
    __syncthreads();
  }
  if (threadIdx.x == 0) { sum_out[r] = sh[0]; sq_out[r] = sh2[0]; }
}

// ---------------- BN coeffs from sum/sumsq (validated) ----------------
__global__ void absch_kernel(const double* __restrict__ sumv, const double* __restrict__ sqv,
                             const float* __restrict__ g, const float* __restrict__ be,
                             float* __restrict__ A, float* __restrict__ D, int M) {
  int m = threadIdx.x;
  if (m >= M) return;
  double mu = sumv[m] * (1.0 / NF_);
  double var = sqv[m] * (1.0 / NF_) - mu * mu;
  double a = (double)g[m] / sqrt(var + 1e-5);
  A[m] = (float)a;
  D[m] = (float)((double)be[m] - a * mu);
}

// ---------------- reduce partials [P][2M] -> sum[M], sq[M] ----------------
__global__ void redab_kernel(const float* __restrict__ parts, double* __restrict__ sum_out,
                             double* __restrict__ sq_out, int P, int M) {
  int m = threadIdx.x;
  if (m >= M) return;
  double a = 0.0, b = 0.0;
  for (int p = 0; p < P; ++p) {
    a += (double)parts[(size_t)p * 2 * M + m];
    b += (double)parts[(size_t)p * 2 * M + M + m];
  }
  sum_out[m] = a;
  sq_out[m] = b;
}

// ============ passA: GEMM2 per chunk, accumulate sum(y2), sum(y2^2) [fp32, validated] ======
__global__ __launch_bounds__(256) void passA_kernel(const float* __restrict__ Y1,
                                                    const float* __restrict__ W2,
                                                    const float* __restrict__ A1v,
                                                    const float* __restrict__ Bc1v,
                                                    float* __restrict__ parts) {
  __shared__ float W2L[64 * 128];
  __shared__ float ab[128];
  __shared__ float vpart[16][128];
  const int t = threadIdx.x;
#pragma unroll
  for (int p = 0; p < 32; ++p) {
    int idx = t + 256 * p;
    int m = idx >> 6, k = idx & 63;
    W2L[k * 128 + m] = W2[m * 64 + k];
  }
  if (t < 64) { ab[t] = A1v[t]; ab[64 + t] = Bc1v[t]; }
  const int tmA = t >> 4, tcA = t & 15;
  float vs[8], vq[8];
#pragma unroll
  for (int i = 0; i < 8; ++i) { vs[i] = 0.f; vq[i] = 0.f; }
  __syncthreads();
  for (int ch = blockIdx.x; ch < NCH_; ch += 512) {
    const size_t n0 = (size_t)ch * 64;
    float acc[8][4];
#pragma unroll
    for (int i = 0; i < 8; ++i)
#pragma unroll
      for (int j = 0; j < 4; ++j) acc[i][j] = 0.f;
#pragma unroll 2
    for (int k = 0; k < 64; ++k) {
      float4 y4 = *reinterpret_cast<const float4*>(&Y1[(size_t)k * NF_ + n0 + tcA * 4]);
      float a1 = ab[k], c1 = ab[64 + k];
      float bx[4];
      bx[0] = fmaxf(fmaf(y4.x, a1, c1), 0.f);
      bx[1] = fmaxf(fmaf(y4.y, a1, c1), 0.f);
      bx[2] = fmaxf(fmaf(y4.z, a1, c1), 0.f);
      bx[3] = fmaxf(fmaf(y4.w, a1, c1), 0.f);
      const float4* ap = reinterpret_cast<const float4*>(&W2L[k * 128 + tmA * 8]);
      float4 a0 = ap[0], a4 = ap[1];
      const float av[8] = {a0.x, a0.y, a0.z, a0.w, a4.x, a4.y, a4.z, a4.w};
#pragma unroll
      for (int i = 0; i < 8; ++i)
#pragma unroll
        for (int j = 0; j < 4; ++j) acc[i][j] = fmaf(av[i], bx[j], acc[i][j]);
    }
#pragma unroll
    for (int i = 0; i < 8; ++i)
#pragma unroll
      for (int j = 0; j < 4; ++j) {
        float y = acc[i][j];
        vs[i] += y;
        vq[i] = fmaf(y, y, vq[i]);
      }
  }
#pragma unroll
  for (int i = 0; i < 8; ++i) vpart[tcA][tmA * 8 + i] = vs[i];
  __syncthreads();
  if (t < 128) {
    float s = 0.f;
    for (int q = 0; q < 16; ++q) s += vpart[q][t];
    parts[(size_t)blockIdx.x * 256 + t] = s;
  }
  __syncthreads();
#pragma unroll
  for (int i = 0; i < 8; ++i) vpart[tcA][tmA * 8 + i] = vq[i];
  __syncthreads();
  if (t < 128) {
    float s = 0.f;
    for (int q = 0; q < 16; ++q) s += vpart[q][t];
    parts[(size_t)blockIdx.x * 256 + 128 + t] = s;
  }
}

// ============ passB: GEMM2 -> x2 -> GEMM3, sum(y3), sum(y3^2) [fp32, validated] ============
__global__ __launch_bounds__(256) void passB_kernel(const float* __restrict__ Y1,
                                                    const float* __restrict__ W2,
                                                    const float* __restrict__ W3,
                                                    const float* __restrict__ A1v,
                                                    const float* __restrict__ Bc1v,
                                                    const float* __restrict__ A2v,
                                                    const float* __restrict__ D2v,
                                                    float* __restrict__ parts) {
  __shared__ float W2L[64 * 128];
  __shared__ float ab[128];
  __shared__ float X2s[128 * 68];
  __shared__ float W3c[16 * 256];
  __shared__ float vpart3[8][256];
  const int t = threadIdx.x;
#pragma unroll
  for (int p = 0; p < 32; ++p) {
    int idx = t + 256 * p;
    int m = idx >> 6, k = idx & 63;
    W2L[k * 128 + m] = W2[m * 64 + k];
  }
  if (t < 64) { ab[t] = A1v[t]; ab[64 + t] = Bc1v[t]; }
  const int tmA = t >> 4, tcA = t & 15;
  const int tm3 = t & 31, tcol = t >> 5;
  float a2r[8], d2r[8], vs[8], vq[8];
#pragma unroll
  for (int i = 0; i < 8; ++i) {
    a2r[i] = A2v[tmA * 8 + i];
    d2r[i] = D2v[tmA * 8 + i];
    vs[i] = 0.f; vq[i] = 0.f;
  }
  __syncthreads();
  for (int ch = blockIdx.x; ch < NCH_; ch += 256) {
    const size_t n0 = (size_t)ch * 64;
    {
      float acc[8][4];
#pragma unroll
      for (int i = 0; i < 8; ++i)
#pragma unroll
        for (int j = 0; j < 4; ++j) acc[i][j] = 0.f;
#pragma unroll 2
      for (int k = 0; k < 64; ++k) {
        float4 y4 = *reinterpret_cast<const float4*>(&Y1[(size_t)k * NF_ + n0 + tcA * 4]);
        float a1 = ab[k], c1 = ab[64 + k];
        float bx[4];
        bx[0] = fmaxf(fmaf(y4.x, a1, c1), 0.f);
        bx[1] = fmaxf(fmaf(y4.y, a1, c1), 0.f);
        bx[2] = fmaxf(fmaf(y4.z, a1, c1), 0.f);
        bx[3] = fmaxf(fmaf(y4.w, a1, c1), 0.f);
        const float4* ap = reinterpret_cast<const float4*>(&W2L[k * 128 + tmA * 8]);
        float4 a0 = ap[0], a4 = ap[1];
        const float av[8] = {a0.x, a0.y, a0.z, a0.w, a4.x, a4.y, a4.z, a4.w};
#pragma unroll
        for (int i = 0; i < 8; ++i)
#pragma unroll
          for (int j = 0; j < 4; ++j) acc[i][j] = fmaf(av[i], bx[j], acc[i][j]);
      }
#pragma unroll
      for (int i = 0; i < 8; ++i) {
        float4 v;
        v.x = fmaxf(fmaf(acc[i][0], a2r[i], d2r[i]), 0.f);
        v.y = fmaxf(fmaf(acc[i][1], a2r[i], d2r[i]), 0.f);
        v.z = fmaxf(fmaf(acc[i][2], a2r[i], d2r[i]), 0.f);
        v.w = fmaxf(fmaf(acc[i][3], a2r[i], d2r[i]), 0.f);
        *reinterpret_cast<float4*>(&X2s[(tmA * 8 + i) * 68 + tcA * 4]) = v;
      }
    }
    __syncthreads();
    float acc3[8][8];
#pragma unroll
    for (int i = 0; i < 8; ++i)
#pragma unroll
      for (int j = 0; j < 8; ++j) acc3[i][j] = 0.f;
    for (int kc = 0; kc < 8; ++kc) {
#pragma unroll
      for (int q = 0; q < 4; ++q) {
        float4 w = *reinterpret_cast<const float4*>(&W3[(size_t)t * 128 + kc * 16 + q * 4]);
        W3c[(q * 4 + 0) * 256 + t] = w.x;
        W3c[(q * 4 + 1) * 256 + t] = w.y;
        W3c[(q * 4 + 2) * 256 + t] = w.z;
        W3c[(q * 4 + 3) * 256 + t] = w.w;
      }
      __syncthreads();
#pragma unroll
      for (int kk = 0; kk < 16; ++kk) {
        const float4* ap = reinterpret_cast<const float4*>(&W3c[kk * 256 + tm3 * 8]);
        float4 a0 = ap[0], a4 = ap[1];
        const float4* bp = reinterpret_cast<const float4*>(&X2s[(kc * 16 + kk) * 68 + tcol * 8]);
        float4 b0 = bp[0], b4 = bp[1];
        const float av[8] = {a0.x, a0.y, a0.z, a0.w, a4.x, a4.y, a4.z, a4.w};
        const float bw[8] = {b0.x, b0.y, b0.z, b0.w, b4.x, b4.y, b4.z, b4.w};
#pragma unroll
        for (int i = 0; i < 8; ++i)
#pragma unroll
          for (int j = 0; j < 8; ++j) acc3[i][j] = fmaf(av[i], bw[j], acc3[i][j]);
      }
      __syncthreads();
    }
#pragma unroll
    for (int i = 0; i < 8; ++i)
#pragma unroll
      for (int j = 0; j < 8; ++j) {
        float y = acc3[i][j];
        vs[i] += y;
        vq[i] = fmaf(y, y, vq[i]);
      }
    __syncthreads();
  }
#pragma unroll
  for (int i = 0; i < 8; ++i) vpart3[tcol][tm3 * 8 + i] = vs[i];
  __syncthreads();
  {
    float s = 0.f;
    for (int q = 0; q < 8; ++q) s += vpart3[q][t];
    parts[(size_t)blockIdx.x * 512 + t] = s;
  }
  __syncthreads();
#pragma unroll
  for (int i = 0; i < 8; ++i) vpart3[tcol][tm3 * 8 + i] = vq[i];
  __syncthreads();
  {
    float s = 0.f;
    for (int q = 0; q < 8; ++q) s += vpart3[q][t];
    parts[(size_t)blockIdx.x * 512 + 256 + t] = s;
  }
}

// ============ final (MFMA bf16): GEMM2 -> BN2/relu -> GEMM3 -> BN3 -> k-max -> out1 ========
// Fragments (m89-verified family): A[L&15][8*(L>>4)+j], B[8*(L>>4)+j][L&15],
// D: col=L&15, row=4*(L>>4)+r. LDS x1b/x2b: [n][k] bf16, byte addr n*KB + (2k ^ ((n&7)<<4)).
__global__ __launch_bounds__(256) void final_mfma_kernel(
    const float* __restrict__ Y1,
    const unsigned short* __restrict__ W2b,   // [128][64] bf16
    const unsigned short* __restrict__ W3b,   // [256][128] bf16
    const float* __restrict__ A1v, const float* __restrict__ Bc1v,
    const float* __restrict__ A2v, const float* __restrict__ D2v,
    const float* __restrict__ A3v, const float* __restrict__ D3v,
    float* __restrict__ out1) {
  __shared__ float ab1[128];
  __shared__ __align__(16) unsigned short x1b[64 * 64];    // 8 KB
  __shared__ __align__(16) unsigned short x2b[64 * 128];   // 16 KB
  const int t = threadIdx.x;
  const int w = t >> 6, L = t & 63;
  if (t < 128) ab1[t] = (t < 64) ? A1v[t] : Bc1v[t - 64];
  // W3 A-frags: wave w owns output rows 64w..64w+63 (rb=0..3)
  bf16x8 w3f[4][4];
#pragma unroll
  for (int rb = 0; rb < 4; ++rb)
#pragma unroll
    for (int ks = 0; ks < 4; ++ks) {
      int row = (4 * w + rb) * 16 + (L & 15);
      int koff = ks * 32 + (L >> 4) * 8;
      w3f[rb][ks] = *reinterpret_cast<const bf16x8*>(&W3b[row * 128 + koff]);
    }
  // W2 A-frags: wave w owns y2 rows 32w..32w+31 (rb=0..1)
  bf16x8 w2f[2][2];
#pragma unroll
  for (int rb = 0; rb < 2; ++rb)
#pragma unroll
    for (int ks = 0; ks < 2; ++ks) {
      int row = (2 * w + rb) * 16 + (L & 15);
      int koff = ks * 32 + (L >> 4) * 8;
      w2f[rb][ks] = *reinterpret_cast<const bf16x8*>(&W2b[row * 64 + koff]);
    }
  char* x1c = reinterpret_cast<char*>(x1b);
  char* x2c = reinterpret_cast<char*>(x2b);
  for (int ch = blockIdx.x; ch < NCH_; ch += 512) {
    const size_t n0 = (size_t)ch * 64;
    __syncthreads();   // protect x1b/x2b from previous-iteration readers (+ab1 on iter 0)
    // stage x1 = relu(A1*Y1+Bc1) as bf16, layout [n][k] swizzled
#pragma unroll
    for (int e = 0; e < 8; ++e) {
      int k0 = 2 * (w + 4 * e);
      float y0 = Y1[(size_t)k0 * NF_ + n0 + L];
      float y1 = Y1[(size_t)(k0 + 1) * NF_ + n0 + L];
      float v0 = fmaxf(fmaf(y0, ab1[k0], ab1[64 + k0]), 0.f);
      float v1 = fmaxf(fmaf(y1, ab1[k0 + 1], ab1[64 + k0 + 1]), 0.f);
      unsigned pk = (unsigned)f2bf(v0) | ((unsigned)f2bf(v1) << 16);
      *reinterpret_cast<unsigned*>(&x1c[L * 128 + ((2 * k0) ^ ((L & 7) << 4))]) = pk;
    }
    __syncthreads();
    // GEMM2: y2[32w..32w+31][64] -> BN2/relu -> x2b bf16
#pragma unroll
    for (int rb = 0; rb < 2; ++rb) {
      f32x4 acc2[4];
#pragma unroll
      for (int cb = 0; cb < 4; ++cb) acc2[cb][0] = acc2[cb][1] = acc2[cb][2] = acc2[cb][3] = 0.f;
#pragma unroll
      for (int ks = 0; ks < 2; ++ks) {
#pragma unroll
        for (int cb = 0; cb < 4; ++cb) {
          int n = cb * 16 + (L & 15);
          int koff = ks * 32 + (L >> 4) * 8;
          bf16x8 bfr = *reinterpret_cast<const bf16x8*>(&x1c[n * 128 + ((2 * koff) ^ ((n & 7) << 4))]);
          acc2[cb] = __builtin_amdgcn_mfma_f32_16x16x32_bf16(w2f[rb][ks], bfr, acc2[cb], 0, 0, 0);
        }
      }
#pragma unroll
      for (int cb = 0; cb < 4; ++cb) {
        int n = cb * 16 + (L & 15);
        int kbase = (2 * w + rb) * 16 + (L >> 4) * 4;
#pragma unroll
        for (int rp = 0; rp < 2; ++rp) {
          int r0 = 2 * rp;
          float a0 = A2v[kbase + r0], d0 = D2v[kbase + r0];
          float a1 = A2v[kbase + r0 + 1], d1 = D2v[kbase + r0 + 1];
          float v0 = fmaxf(fmaf(acc2[cb][r0], a0, d0), 0.f);
          float v1 = fmaxf(fmaf(acc2[cb][r0 + 1], a1, d1), 0.f);
          unsigned pk = (unsigned)f2bf(v0) | ((unsigned)f2bf(v1) << 16);
          int k0 = kbase + r0;
          *reinterpret_cast<unsigned*>(&x2c[n * 256 + ((2 * k0) ^ ((n & 7) << 4))]) = pk;
        }
      }
    }
    __syncthreads();
    // B3 frags (shared across rb)
    bf16x8 b3[4][4];
#pragma unroll
    for (int cb = 0; cb < 4; ++cb)
#pragma unroll
      for (int ks = 0; ks < 4; ++ks) {
        int n = cb * 16 + (L & 15);
        int koff = ks * 32 + (L >> 4) * 8;
        b3[cb][ks] = *reinterpret_cast<const bf16x8*>(&x2c[n * 256 + ((2 * koff) ^ ((n & 7) << 4))]);
      }
    // GEMM3 + BN3 + max over 16 neighbor-cols + relu + store
#pragma unroll
    for (int rb = 0; rb < 4; ++rb) {
      f32x4 acc3[4];
#pragma unroll
      for (int cb = 0; cb < 4; ++cb) acc3[cb][0] = acc3[cb][1] = acc3[cb][2] = acc3[cb][3] = 0.f;
#pragma unroll
      for (int ks = 0; ks < 4; ++ks)
#pragma unroll
        for (int cb = 0; cb < 4; ++cb)
          acc3[cb] = __builtin_amdgcn_mfma_f32_16x16x32_bf16(w3f[rb][ks], b3[cb][ks], acc3[cb], 0, 0, 0);
      int rowbase = (4 * w + rb) * 16 + (L >> 4) * 4;
#pragma unroll
      for (int cb = 0; cb < 4; ++cb) {
#pragma unroll
        for (int r = 0; r < 4; ++r) {
          float v = fmaf(acc3[cb][r], A3v[rowbase + r], D3v[rowbase + r]);
          int xi = __float_as_int(v);
#define RMAX(CTRL) { int tm_ = __builtin_amdgcn_update_dpp(xi, xi, (CTRL), 0xF, 0xF, false); \
                     xi = __float_as_int(fmaxf(__int_as_float(xi), __int_as_float(tm_))); }
          RMAX(0x111) RMAX(0x112) RMAX(0x114) RMAX(0x118)
#undef RMAX
          if ((L & 15) == 15) {
            int row = rowbase + r;
            int bs = ch * 4 + cb;
            int b = bs / S_;
            int s = bs - b * S_;
            out1[((size_t)(b * 256 + row)) * S_ + s] = fmaxf(__int_as_float(xi), 0.f);
          }
        }
      }
    }
  }
}

__global__ void diag_kernel(float* out, float v) {
  if (threadIdx.x == 0 && blockIdx.x == 0) out[0] = v;
}

extern "C" void kernel_launch(void* const* d_in, const int* in_sizes, int n_in,
                              void* d_out, int out_size, void* d_ws, size_t ws_size,
                              hipStream_t stream) {
  const float* xy  = (const float*)d_in[0];
  const float* fea = (const float*)d_in[1];
  const float* W1  = (const float*)d_in[2];
  const float* b1  = (const float*)d_in[3];
  const float* g1  = (const float*)d_in[4];
  const float* be1 = (const float*)d_in[5];
  const float* W2  = (const float*)d_in[6];
  const float* g2  = (const float*)d_in[8];
  const float* be2 = (const float*)d_in[9];
  const float* W3  = (const float*)d_in[10];
  const float* g3  = (const float*)d_in[12];
  const float* be3 = (const float*)d_in[13];
  float* out = (float*)d_out;
  float* out1 = out + B_ * 2 * S_;

  char* w = (char*)d_ws;
  size_t off = 0;
  auto take = [&](size_t bytes) -> void* {
    void* p = w + off;
    off += (bytes + 255) & ~(size_t)255;
    return p;
  };
  int*    fps_idx = (int*)take((size_t)B_ * S_ * 4);
  float*  new_xyz = (float*)take((size_t)B_ * S_ * 2 * 4);
  int*    knn_sel = (int*)take((size_t)NF_ * 4);
  float*  P       = (float*)take((size_t)B_ * N_ * 64 * 4);   // 8.4 MB
  float*  Y1      = (float*)take((size_t)64 * NF_ * 4);       // 67.2 MB
  double* Sy1     = (double*)take(64 * 8);
  double* Sq1     = (double*)take(64 * 8);
  float*  A1      = (float*)take(64 * 4);
  float*  Bc1     = (float*)take(64 * 4);
  float*  partsA  = (float*)take((size_t)512 * 256 * 4);
  double* Sy2     = (double*)take(128 * 8);
  double* Sq2     = (double*)take(128 * 8);
  float*  A2      = (float*)take(128 * 4);
  float*  D2      = (float*)take(128 * 4);
  float*  partsB  = (float*)take((size_t)256 * 512 * 4);
  double* Sy3     = (double*)take(256 * 8);
  double* Sq3     = (double*)take(256 * 8);
  float*  A3      = (float*)take(256 * 4);
  float*  D3      = (float*)take(256 * 4);
  unsigned short* W2b = (unsigned short*)take((size_t)128 * 64 * 2);
  unsigned short* W3b = (unsigned short*)take((size_t)256 * 128 * 2);

  if (off > ws_size) {
    diag_kernel<<<1, 64, 0, stream>>>(out, (float)(ws_size >> 20));
    return;
  }

  fps_pk_kernel<<<16 + 512, 256, 0, stream>>>(xy, fea, W1, fps_idx, new_xyz, out, P);
  wconv_kernel<<<128, 256, 0, stream>>>(W2, W3, W2b, W3b);
  knn_kernel<<<dim3((S_ + 15) / 16, B_), 256, 0, stream>>>(xy, fps_idx, knn_sel);
  yk1_kernel<<<NF_ / 256, 256, 0, stream>>>(xy, knn_sel, new_xyz, P, W1, b1, Y1);

  rowstats_kernel<<<64, 1024, 0, stream>>>(Y1, Sy1, Sq1);
  absch_kernel<<<1, 64, 0, stream>>>(Sy1, Sq1, g1, be1, A1, Bc1, 64);

  passA_kernel<<<512, 256, 0, stream>>>(Y1, W2, A1, Bc1, partsA);
  redab_kernel<<<1, 128, 0, stream>>>(partsA, Sy2, Sq2, 512, 128);
  absch_kernel<<<1, 128, 0, stream>>>(Sy2, Sq2, g2, be2, A2, D2, 128);

  passB_kernel<<<256, 256, 0, stream>>>(Y1, W2, W3, A1, Bc1, A2, D2, partsB);
  redab_kernel<<<1, 256, 0, stream>>>(partsB, Sy3, Sq3, 256, 256);
  absch_kernel<<<1, 256, 0, stream>>>(Sy3, Sq3, g3, be3, A3, D3, 256);

  final_mfma_kernel<<<512, 256, 0, stream>>>(Y1, W2b, W3b, A1, Bc1, A2, D2, A3, D3, out1);
}

// Round 13
// 1448.655 us; speedup vs baseline: 2.6875x; 1.4171x over previous
//
#include <hip/hip_runtime.h>
#include <math.h>

#define B_   16
#define N_   2048
#define S_   1025
#define K_   16
#define EMB_ 64
#define NF_  (B_ * S_ * K_)   // 262400
#define NCH_ (NF_ / 64)       // 4100 column-chunks of 64

typedef float v2f __attribute__((ext_vector_type(2)));
typedef short bf16x8 __attribute__((ext_vector_type(8)));
typedef float f32x4 __attribute__((ext_vector_type(4)));

__device__ __forceinline__ unsigned short f2bf(float f) {  // RNE fp32->bf16
  unsigned u = __float_as_uint(f);
  u += 0x7fffu + ((u >> 16) & 1u);
  return (unsigned short)(u >> 16);
}

// ======== FUSED: blocks 0-15 = FPS (validated) ; blocks 16+ = pk ========
__global__ __launch_bounds__(256) __attribute__((amdgpu_waves_per_eu(1, 1)))
void fps_pk_kernel(const float* __restrict__ xy, const float* __restrict__ fea,
                   const float* __restrict__ W1,
                   int* __restrict__ fps_idx, float* __restrict__ new_xyz,
                   float* __restrict__ out0, float* __restrict__ P) {
  __shared__ float smem[8192];   // 32 KB union
  if (blockIdx.x < 16) {
    const int b = blockIdx.x;
    float2* lxy = reinterpret_cast<float2*>(smem);
    const int lane = threadIdx.x;
    const float* xb = xy + (size_t)b * 2 * N_;
    v2f pxp[16], pyp[16];
    float dist[32];
    if (lane < 64) {
      const float2* xb2 = (const float2*)xb;
      const float2* yb2 = (const float2*)(xb + N_);
#pragma unroll
      for (int q = 0; q < 16; ++q) {
        float2 x01 = xb2[lane * 16 + q];
        float2 y01 = yb2[lane * 16 + q];
        int p = lane * 32 + 2 * q;
        lxy[p] = make_float2(x01.x, y01.x);
        lxy[p + 1] = make_float2(x01.y, y01.y);
        pxp[q][0] = x01.x; pxp[q][1] = x01.y;
        pyp[q][0] = y01.x; pyp[q][1] = y01.y;
        dist[2 * q] = __builtin_inff();
        dist[2 * q + 1] = __builtin_inff();
      }
#pragma unroll
      for (int q = 0; q < 16; ++q) {
        asm volatile("" : "+v"(pxp[q]), "+v"(pyp[q]));
      }
    }
    __syncthreads();
    if (lane < 64) {
      int cur = 0;
      for (int t = 0; t < S_; ++t) {
        float2 c = lxy[cur];
        if (lane == 0) {
          fps_idx[b * S_ + t] = cur;
          new_xyz[(b * S_ + t) * 2 + 0] = c.x;
          new_xyz[(b * S_ + t) * 2 + 1] = c.y;
          out0[b * 2 * S_ + t] = c.x;
          out0[b * 2 * S_ + S_ + t] = c.y;
        }
        const float ncx = -c.x, ncy = -c.y;
        v2f ncx2; ncx2[0] = ncx; ncx2[1] = ncx;
        v2f ncy2; ncy2[0] = ncy; ncy2[1] = ncy;
        float lmax0 = -__builtin_inff(), lmax1 = -__builtin_inff();
#pragma unroll
        for (int q = 0; q < 16; ++q) {
          v2f dx, dy, sx, sy, dd;
          asm("v_pk_add_f32 %0, %1, %2" : "=v"(dx) : "v"(pxp[q]), "v"(ncx2));
          asm("v_pk_add_f32 %0, %1, %2" : "=v"(dy) : "v"(pyp[q]), "v"(ncy2));
          asm("v_pk_mul_f32 %0, %1, %1" : "=v"(sx) : "v"(dx));
          asm("v_pk_mul_f32 %0, %1, %1" : "=v"(sy) : "v"(dy));
          asm("v_pk_add_f32 %0, %1, %2" : "=v"(dd) : "v"(sx), "v"(sy));
          float nd0 = fminf(dist[2 * q], dd[0]);
          float nd1 = fminf(dist[2 * q + 1], dd[1]);
          dist[2 * q] = nd0;
          dist[2 * q + 1] = nd1;
          lmax0 = fmaxf(lmax0, nd0);
          lmax1 = fmaxf(lmax1, nd1);
        }
        const float lmax = fmaxf(lmax0, lmax1);
        int xr = __float_as_int(lmax);
#define DPP_MAX_STEP(CTRL)                                                        \
        {                                                                         \
          int tmp_ = __builtin_amdgcn_update_dpp(xr, xr, (CTRL), 0xF, 0xF, false);\
          xr = __float_as_int(fmaxf(__int_as_float(xr), __int_as_float(tmp_)));   \
        }
        DPP_MAX_STEP(0x111)
        DPP_MAX_STEP(0x112)
        DPP_MAX_STEP(0x114)
        DPP_MAX_STEP(0x118)
        DPP_MAX_STEP(0x142)
        DPP_MAX_STEP(0x143)
#undef DPP_MAX_STEP
        const float g = __int_as_float(__builtin_amdgcn_readlane(xr, 63));
        int lf = 0;
#pragma unroll
        for (int j = 31; j >= 0; --j)
          if (dist[j] == g) lf = j;
        unsigned long long mask = __ballot(lmax == g);
        int first = __ffsll(mask) - 1;
        cur = __builtin_amdgcn_readlane(lane * 32 + lf, first);
      }
    }
  } else {
    const int bid = blockIdx.x - 16;
    const int t = threadIdx.x;
    const int b = bid >> 5;
    const int pt0 = (bid & 31) << 6;
    float* W1L = smem;
    float* feaL = smem + 4096;
#pragma unroll
    for (int p = 0; p < 16; ++p) {
      int idx = t + 256 * p;
      int c = idx >> 6, e = idx & 63;
      W1L[e * 64 + c] = W1[c * 66 + 2 + e];
      int r = (t >> 6) + 4 * p, cc = t & 63;
      feaL[r * 64 + cc] = fea[((size_t)b * 64 + r) * N_ + pt0 + cc];
    }
    __syncthreads();
    const int tpt = t & 15, tcq = t >> 4;
    float acc[4][4];
#pragma unroll
    for (int i = 0; i < 4; ++i)
#pragma unroll
      for (int j = 0; j < 4; ++j) acc[i][j] = 0.f;
    for (int e = 0; e < 64; ++e) {
      float4 a4 = *reinterpret_cast<const float4*>(&W1L[e * 64 + tcq * 4]);
      float4 b4 = *reinterpret_cast<const float4*>(&feaL[e * 64 + tpt * 4]);
      const float av[4] = {a4.x, a4.y, a4.z, a4.w};
      const float bvv[4] = {b4.x, b4.y, b4.z, b4.w};
#pragma unroll
      for (int i = 0; i < 4; ++i)
#pragma unroll
        for (int j = 0; j < 4; ++j) acc[i][j] = fmaf(av[i], bvv[j], acc[i][j]);
    }
#pragma unroll
    for (int j = 0; j < 4; ++j) {
      int pt = tpt * 4 + j;
      float4 v = {acc[0][j], acc[1][j], acc[2][j], acc[3][j]};
      *reinterpret_cast<float4*>(&P[((size_t)(b * N_ + pt0 + pt)) * 64 + tcq * 4]) = v;
    }
  }
}

// ---------------- W2/W3 -> bf16 (RNE), row-major ----------------
__global__ void wconv_kernel(const float* __restrict__ W2, const float* __restrict__ W3,
                             unsigned short* __restrict__ W2b, unsigned short* __restrict__ W3b) {
  int i = blockIdx.x * 256 + threadIdx.x;
  if (i < 128 * 64) W2b[i] = f2bf(W2[i]);
  if (i < 256 * 128) W3b[i] = f2bf(W3[i]);
}

// ---------------- KNN fp64-exact (validated) ----------------
__global__ __launch_bounds__(256) void knn_kernel(const float* __restrict__ xy,
                                                  const int* __restrict__ fps_idx,
                                                  int* __restrict__ knn_sel) {
  const int b = blockIdx.y;
  __shared__ float2 lxy[N_];
  __shared__ double lsq[N_];
  const float* xb = xy + (size_t)b * 2 * N_;
  for (int p = threadIdx.x; p < N_; p += 256) {
    float x = xb[p], y = xb[N_ + p];
    lxy[p] = make_float2(x, y);
    lsq[p] = (double)x * (double)x + (double)y * (double)y;
  }
  __syncthreads();
  const int t = threadIdx.x;
  const int s = blockIdx.x * 16 + (t >> 4);
  if (s >= S_) return;
  const int oct = t & 15;
  const int p0 = fps_idx[b * S_ + s];
  float2 q = lxy[p0];
  const double xn = (double)q.x, yn = (double)q.y;
  const double sqn = lsq[p0];
  double d16[16];
  int i16[16];
#pragma unroll
  for (int j = 0; j < 16; ++j) { d16[j] = __builtin_inf(); i16[j] = 0x7fffffff; }
  const int mlo = oct * 128;
  for (int m0 = mlo; m0 < mlo + 128; m0 += 4) {
    double dd[4];
#pragma unroll
    for (int u = 0; u < 4; ++u) {
      float2 p = lxy[m0 + u];
      double dot = (double)p.x * xn + (double)p.y * yn;
      dd[u] = (sqn - 2.0 * dot) + lsq[m0 + u];
    }
#pragma unroll
    for (int u = 0; u < 4; ++u) {
      if (dd[u] < d16[15]) {
        double d = dd[u];
        int mi = m0 + u;
#pragma unroll
        for (int j = 15; j >= 1; --j) {
          bool shift = d < d16[j - 1];
          bool ins = d < d16[j];
          d16[j] = shift ? d16[j - 1] : (ins ? d : d16[j]);
          i16[j] = shift ? i16[j - 1] : (ins ? mi : i16[j]);
        }
        if (d < d16[0]) { d16[0] = d; i16[0] = mi; }
      }
    }
  }
#pragma unroll
  for (int w = 1; w <= 8; w <<= 1) {
    double nd[16]; int ni[16];
#pragma unroll
    for (int i = 0; i < 16; ++i) {
      double rd = __shfl_xor(d16[15 - i], w, 64);
      int ri = __shfl_xor(i16[15 - i], w, 64);
      bool takeR = (rd < d16[i]) || (rd == d16[i] && ri < i16[i]);
      nd[i] = takeR ? rd : d16[i];
      ni[i] = takeR ? ri : i16[i];
    }
#pragma unroll
    for (int i = 0; i < 16; ++i) { d16[i] = nd[i]; i16[i] = ni[i]; }
    if (w < 8) {
#pragma unroll
      for (int dstg = 8; dstg >= 1; dstg >>= 1) {
#pragma unroll
        for (int i = 0; i < 16; ++i) {
          if ((i & dstg) == 0) {
            int a = i, c = i + dstg;
            bool sw = (d16[a] > d16[c]) || (d16[a] == d16[c] && i16[a] > i16[c]);
            double tlo = sw ? d16[c] : d16[a];
            double thi = sw ? d16[a] : d16[c];
            int ulo = sw ? i16[c] : i16[a];
            int uhi = sw ? i16[a] : i16[c];
            d16[a] = tlo; d16[c] = thi; i16[a] = ulo; i16[c] = uhi;
          }
        }
      }
    }
  }
  if (oct == 0) {
    int* dst = knn_sel + ((size_t)b * S_ + s) * K_;
#pragma unroll
    for (int j = 0; j < 16; ++j) dst[j] = i16[j];
  }
}

// ---------------- Y1[64][NF]: gather P + W1a*dxy + b1 ----------------
__global__ __launch_bounds__(256) void yk1_kernel(const float* __restrict__ xy,
                                                  const int* __restrict__ knn_sel,
                                                  const float* __restrict__ new_xyz,
                                                  const float* __restrict__ P,
                                                  const float* __restrict__ W1,
                                                  const float* __restrict__ b1,
                                                  float* __restrict__ Y1) {
  __shared__ float w0s[64], w1s[64], bbs[64];
  const int t = threadIdx.x;
  if (t < 64) { w0s[t] = W1[t * 66 + 0]; w1s[t] = W1[t * 66 + 1]; bbs[t] = b1[t]; }
  __syncthreads();
  const int n = blockIdx.x * 256 + t;
  const int bs = n >> 4;
  const int b = bs / S_;
  const int nbr = knn_sel[n];
  const float dx = xy[(size_t)b * 2 * N_ + nbr] - new_xyz[bs * 2 + 0];
  const float dy = xy[(size_t)b * 2 * N_ + N_ + nbr] - new_xyz[bs * 2 + 1];
  const float* prow = &P[((size_t)(b * N_ + nbr)) * 64];
  for (int c4 = 0; c4 < 64; c4 += 4) {
    float4 p4 = *reinterpret_cast<const float4*>(&prow[c4]);
    float v0 = p4.x + w0s[c4 + 0] * dx + w1s[c4 + 0] * dy + bbs[c4 + 0];
    float v1 = p4.y + w0s[c4 + 1] * dx + w1s[c4 + 1] * dy + bbs[c4 + 1];
    float v2 = p4.z + w0s[c4 + 2] * dx + w1s[c4 + 2] * dy + bbs[c4 + 2];
    float v3 = p4.w + w0s[c4 + 3] * dx + w1s[c4 + 3] * dy + bbs[c4 + 3];
    Y1[(size_t)(c4 + 0) * NF_ + n] = v0;
    Y1[(size_t)(c4 + 1) * NF_ + n] = v1;
    Y1[(size_t)(c4 + 2) * NF_ + n] = v2;
    Y1[(size_t)(c4 + 3) * NF_ + n] = v3;
  }
}

// ---------------- per-row sum + sumsq (fp64) ----------------
__global__ __launch_bounds__(1024) void rowstats_kernel(const float* __restrict__ Y,
                                                        double* __restrict__ sum_out,
                                                        double* __restrict__ sq_out) {
  const int r = blockIdx.x;
  const float* row = Y + (size_t)r * NF_;
  double s = 0.0, s2 = 0.0;
  for (int i = threadIdx.x * 4; i < NF_; i += 4096) {
    float4 v = *reinterpret_cast<const float4*>(&row[i]);
    double dx = v.x, dy = v.y, dz = v.z, dw = v.w;
    s += (dx + dy) + (dz + dw);
    s2 = fma(dx, dx, s2); s2 = fma(dy, dy, s2);
    s2 = fma(dz, dz, s2); s2 = fma(dw, dw, s2);
  }
  __shared__ double sh[1024], sh2[1024];
  sh[threadIdx.x] = s; sh2[threadIdx.x] = s2;
  __syncthreads();
  for (int o = 512; o > 0; o >>= 1) {
    if (threadIdx.x < o) {
      sh[threadIdx.x] += sh[threadIdx.x + o];
      sh2[threadIdx.x] += sh2[threadIdx.x + o];
    }
    __syncthreads();
  }
  if (threadIdx.x == 0) { sum_out[r] = sh[0]; sq_out[r] = sh2[0]; }
}

// ---------------- BN coeffs from sum/sumsq (validated) ----------------
__global__ void absch_kernel(const double* __restrict__ sumv, const double* __restrict__ sqv,
                             const float* __restrict__ g, const float* __restrict__ be,
                             float* __restrict__ A, float* __restrict__ D, int M) {
  int m = threadIdx.x;
  if (m >= M) return;
  double mu = sumv[m] * (1.0 / NF_);
  double var = sqv[m] * (1.0 / NF_) - mu * mu;
  double a = (double)g[m] / sqrt(var + 1e-5);
  A[m] = (float)a;
  D[m] = (float)((double)be[m] - a * mu);
}

// ---------------- reduce partials [P][2M] -> sum[M], sq[M] ----------------
__global__ void redab_kernel(const float* __restrict__ parts, double* __restrict__ sum_out,
                             double* __restrict__ sq_out, int P, int M) {
  int m = threadIdx.x;
  if (m >= M) return;
  double a = 0.0, b = 0.0;
  for (int p = 0; p < P; ++p) {
    a += (double)parts[(size_t)p * 2 * M + m];
    b += (double)parts[(size_t)p * 2 * M + M + m];
  }
  sum_out[m] = a;
  sq_out[m] = b;
}

// DPP prefix-add across each 16-lane row group; lane (L&15)==15 holds the group total.
// bound_ctrl=true so out-of-range lanes contribute 0 (NOT the max-reduce's false!).
__device__ __forceinline__ float rowsum16(float v) {
#define RADD(CTRL) { int tm_ = __builtin_amdgcn_update_dpp(0, __float_as_int(v), (CTRL), 0xF, 0xF, true); \
                     v += __int_as_float(tm_); }
  RADD(0x111) RADD(0x112) RADD(0x114) RADD(0x118)
#undef RADD
  return v;
}

// ============ passA (MFMA): y2 = W2b * x1b, accumulate sum(y2), sum(y2^2) ============
__global__ __launch_bounds__(256) void passA_mfma_kernel(
    const float* __restrict__ Y1, const unsigned short* __restrict__ W2b,
    const float* __restrict__ A1v, const float* __restrict__ Bc1v,
    float* __restrict__ parts) {
  __shared__ float ab1[128];
  __shared__ __align__(16) unsigned short x1b[64 * 64];    // 8 KB
  const int t = threadIdx.x;
  const int w = t >> 6, L = t & 63;
  if (t < 128) ab1[t] = (t < 64) ? A1v[t] : Bc1v[t - 64];
  bf16x8 w2f[2][2];
#pragma unroll
  for (int rb = 0; rb < 2; ++rb)
#pragma unroll
    for (int ks = 0; ks < 2; ++ks) {
      int row = (2 * w + rb) * 16 + (L & 15);
      int koff = ks * 32 + (L >> 4) * 8;
      w2f[rb][ks] = *reinterpret_cast<const bf16x8*>(&W2b[row * 64 + koff]);
    }
  float vs[2][4], vq[2][4];
#pragma unroll
  for (int rb = 0; rb < 2; ++rb)
#pragma unroll
    for (int r = 0; r < 4; ++r) { vs[rb][r] = 0.f; vq[rb][r] = 0.f; }
  char* x1c = reinterpret_cast<char*>(x1b);
  for (int ch = blockIdx.x; ch < NCH_; ch += 512) {
    const size_t n0 = (size_t)ch * 64;
    __syncthreads();
#pragma unroll
    for (int e = 0; e < 8; ++e) {
      int k0 = 2 * (w + 4 * e);
      float y0 = Y1[(size_t)k0 * NF_ + n0 + L];
      float y1 = Y1[(size_t)(k0 + 1) * NF_ + n0 + L];
      float v0 = fmaxf(fmaf(y0, ab1[k0], ab1[64 + k0]), 0.f);
      float v1 = fmaxf(fmaf(y1, ab1[k0 + 1], ab1[64 + k0 + 1]), 0.f);
      unsigned pk = (unsigned)f2bf(v0) | ((unsigned)f2bf(v1) << 16);
      *reinterpret_cast<unsigned*>(&x1c[L * 128 + ((2 * k0) ^ ((L & 7) << 4))]) = pk;
    }
    __syncthreads();
#pragma unroll
    for (int rb = 0; rb < 2; ++rb) {
      f32x4 acc2[4];
#pragma unroll
      for (int cb = 0; cb < 4; ++cb) acc2[cb][0] = acc2[cb][1] = acc2[cb][2] = acc2[cb][3] = 0.f;
#pragma unroll
      for (int ks = 0; ks < 2; ++ks)
#pragma unroll
        for (int cb = 0; cb < 4; ++cb) {
          int n = cb * 16 + (L & 15);
          int koff = ks * 32 + (L >> 4) * 8;
          bf16x8 bfr = *reinterpret_cast<const bf16x8*>(&x1c[n * 128 + ((2 * koff) ^ ((n & 7) << 4))]);
          acc2[cb] = __builtin_amdgcn_mfma_f32_16x16x32_bf16(w2f[rb][ks], bfr, acc2[cb], 0, 0, 0);
        }
#pragma unroll
      for (int cb = 0; cb < 4; ++cb)
#pragma unroll
        for (int r = 0; r < 4; ++r) {
          float y = acc2[cb][r];
          vs[rb][r] += y;
          vq[rb][r] = fmaf(y, y, vq[rb][r]);
        }
    }
  }
#pragma unroll
  for (int rb = 0; rb < 2; ++rb)
#pragma unroll
    for (int r = 0; r < 4; ++r) {
      float s = rowsum16(vs[rb][r]);
      float q = rowsum16(vq[rb][r]);
      if ((L & 15) == 15) {
        int row = (2 * w + rb) * 16 + (L >> 4) * 4 + r;
        parts[(size_t)blockIdx.x * 256 + row] = s;
        parts[(size_t)blockIdx.x * 256 + 128 + row] = q;
      }
    }
}

// ============ passB (MFMA): GEMM2 -> BN2/relu -> GEMM3, sum(y3), sum(y3^2) ============
__global__ __launch_bounds__(256) void passB_mfma_kernel(
    const float* __restrict__ Y1,
    const unsigned short* __restrict__ W2b, const unsigned short* __restrict__ W3b,
    const float* __restrict__ A1v, const float* __restrict__ Bc1v,
    const float* __restrict__ A2v, const float* __restrict__ D2v,
    float* __restrict__ parts) {
  __shared__ float ab1[128];
  __shared__ __align__(16) unsigned short x1b[64 * 64];    // 8 KB
  __shared__ __align__(16) unsigned short x2b[64 * 128];   // 16 KB
  const int t = threadIdx.x;
  const int w = t >> 6, L = t & 63;
  if (t < 128) ab1[t] = (t < 64) ? A1v[t] : Bc1v[t - 64];
  bf16x8 w3f[4][4];
#pragma unroll
  for (int rb = 0; rb < 4; ++rb)
#pragma unroll
    for (int ks = 0; ks < 4; ++ks) {
      int row = (4 * w + rb) * 16 + (L & 15);
      int koff = ks * 32 + (L >> 4) * 8;
      w3f[rb][ks] = *reinterpret_cast<const bf16x8*>(&W3b[row * 128 + koff]);
    }
  bf16x8 w2f[2][2];
#pragma unroll
  for (int rb = 0; rb < 2; ++rb)
#pragma unroll
    for (int ks = 0; ks < 2; ++ks) {
      int row = (2 * w + rb) * 16 + (L & 15);
      int koff = ks * 32 + (L >> 4) * 8;
      w2f[rb][ks] = *reinterpret_cast<const bf16x8*>(&W2b[row * 64 + koff]);
    }
  float vs[4][4], vq[4][4];
#pragma unroll
  for (int rb = 0; rb < 4; ++rb)
#pragma unroll
    for (int r = 0; r < 4; ++r) { vs[rb][r] = 0.f; vq[rb][r] = 0.f; }
  char* x1c = reinterpret_cast<char*>(x1b);
  char* x2c = reinterpret_cast<char*>(x2b);
  for (int ch = blockIdx.x; ch < NCH_; ch += 256) {
    const size_t n0 = (size_t)ch * 64;
    __syncthreads();
#pragma unroll
    for (int e = 0; e < 8; ++e) {
      int k0 = 2 * (w + 4 * e);
      float y0 = Y1[(size_t)k0 * NF_ + n0 + L];
      float y1 = Y1[(size_t)(k0 + 1) * NF_ + n0 + L];
      float v0 = fmaxf(fmaf(y0, ab1[k0], ab1[64 + k0]), 0.f);
      float v1 = fmaxf(fmaf(y1, ab1[k0 + 1], ab1[64 + k0 + 1]), 0.f);
      unsigned pk = (unsigned)f2bf(v0) | ((unsigned)f2bf(v1) << 16);
      *reinterpret_cast<unsigned*>(&x1c[L * 128 + ((2 * k0) ^ ((L & 7) << 4))]) = pk;
    }
    __syncthreads();
#pragma unroll
    for (int rb = 0; rb < 2; ++rb) {
      f32x4 acc2[4];
#pragma unroll
      for (int cb = 0; cb < 4; ++cb) acc2[cb][0] = acc2[cb][1] = acc2[cb][2] = acc2[cb][3] = 0.f;
#pragma unroll
      for (int ks = 0; ks < 2; ++ks)
#pragma unroll
        for (int cb = 0; cb < 4; ++cb) {
          int n = cb * 16 + (L & 15);
          int koff = ks * 32 + (L >> 4) * 8;
          bf16x8 bfr = *reinterpret_cast<const bf16x8*>(&x1c[n * 128 + ((2 * koff) ^ ((n & 7) << 4))]);
          acc2[cb] = __builtin_amdgcn_mfma_f32_16x16x32_bf16(w2f[rb][ks], bfr, acc2[cb], 0, 0, 0);
        }
#pragma unroll
      for (int cb = 0; cb < 4; ++cb) {
        int n = cb * 16 + (L & 15);
        int kbase = (2 * w + rb) * 16 + (L >> 4) * 4;
#pragma unroll
        for (int rp = 0; rp < 2; ++rp) {
          int r0 = 2 * rp;
          float a0 = A2v[kbase + r0], d0 = D2v[kbase + r0];
          float a1 = A2v[kbase + r0 + 1], d1 = D2v[kbase + r0 + 1];
          float v0 = fmaxf(fmaf(acc2[cb][r0], a0, d0), 0.f);
          float v1 = fmaxf(fmaf(acc2[cb][r0 + 1], a1, d1), 0.f);
          unsigned pk = (unsigned)f2bf(v0) | ((unsigned)f2bf(v1) << 16);
          int k0 = kbase + r0;
          *reinterpret_cast<unsigned*>(&x2c[n * 256 + ((2 * k0) ^ ((n & 7) << 4))]) = pk;
        }
      }
    }
    __syncthreads();
    bf16x8 b3[4][4];
#pragma unroll
    for (int cb = 0; cb < 4; ++cb)
#pragma unroll
      for (int ks = 0; ks < 4; ++ks) {
        int n = cb * 16 + (L & 15);
        int koff = ks * 32 + (L >> 4) * 8;
        b3[cb][ks] = *reinterpret_cast<const bf16x8*>(&x2c[n * 256 + ((2 * koff) ^ ((n & 7) << 4))]);
      }
#pragma unroll
    for (int rb = 0; rb < 4; ++rb) {
      f32x4 acc3[4];
#pragma unroll
      for (int cb = 0; cb < 4; ++cb) acc3[cb][0] = acc3[cb][1] = acc3[cb][2] = acc3[cb][3] = 0.f;
#pragma unroll
      for (int ks = 0; ks < 4; ++ks)
#pragma unroll
        for (int cb = 0; cb < 4; ++cb)
          acc3[cb] = __builtin_amdgcn_mfma_f32_16x16x32_bf16(w3f[rb][ks], b3[cb][ks], acc3[cb], 0, 0, 0);
#pragma unroll
      for (int cb = 0; cb < 4; ++cb)
#pragma unroll
        for (int r = 0; r < 4; ++r) {
          float y = acc3[cb][r];
          vs[rb][r] += y;
          vq[rb][r] = fmaf(y, y, vq[rb][r]);
        }
    }
  }
#pragma unroll
  for (int rb = 0; rb < 4; ++rb)
#pragma unroll
    for (int r = 0; r < 4; ++r) {
      float s = rowsum16(vs[rb][r]);
      float q = rowsum16(vq[rb][r]);
      if ((L & 15) == 15) {
        int row = (4 * w + rb) * 16 + (L >> 4) * 4 + r;
        parts[(size_t)blockIdx.x * 512 + row] = s;
        parts[(size_t)blockIdx.x * 512 + 256 + row] = q;
      }
    }
}

// ============ final (MFMA, validated r12): GEMM2 -> BN2 -> GEMM3 -> BN3 -> k-max ============
__global__ __launch_bounds__(256) void final_mfma_kernel(
    const float* __restrict__ Y1,
    const unsigned short* __restrict__ W2b,
    const unsigned short* __restrict__ W3b,
    const float* __restrict__ A1v, const float* __restrict__ Bc1v,
    const float* __restrict__ A2v, const float* __restrict__ D2v,
    const float* __restrict__ A3v, const float* __restrict__ D3v,
    float* __restrict__ out1) {
  __shared__ float ab1[128];
  __shared__ __align__(16) unsigned short x1b[64 * 64];
  __shared__ __align__(16) unsigned short x2b[64 * 128];
  const int t = threadIdx.x;
  const int w = t >> 6, L = t & 63;
  if (t < 128) ab1[t] = (t < 64) ? A1v[t] : Bc1v[t - 64];
  bf16x8 w3f[4][4];
#pragma unroll
  for (int rb = 0; rb < 4; ++rb)
#pragma unroll
    for (int ks = 0; ks < 4; ++ks) {
      int row = (4 * w + rb) * 16 + (L & 15);
      int koff = ks * 32 + (L >> 4) * 8;
      w3f[rb][ks] = *reinterpret_cast<const bf16x8*>(&W3b[row * 128 + koff]);
    }
  bf16x8 w2f[2][2];
#pragma unroll
  for (int rb = 0; rb < 2; ++rb)
#pragma unroll
    for (int ks = 0; ks < 2; ++ks) {
      int row = (2 * w + rb) * 16 + (L & 15);
      int koff = ks * 32 + (L >> 4) * 8;
      w2f[rb][ks] = *reinterpret_cast<const bf16x8*>(&W2b[row * 64 + koff]);
    }
  char* x1c = reinterpret_cast<char*>(x1b);
  char* x2c = reinterpret_cast<char*>(x2b);
  for (int ch = blockIdx.x; ch < NCH_; ch += 512) {
    const size_t n0 = (size_t)ch * 64;
    __syncthreads();
#pragma unroll
    for (int e = 0; e < 8; ++e) {
      int k0 = 2 * (w + 4 * e);
      float y0 = Y1[(size_t)k0 * NF_ + n0 + L];
      float y1 = Y1[(size_t)(k0 + 1) * NF_ + n0 + L];
      float v0 = fmaxf(fmaf(y0, ab1[k0], ab1[64 + k0]), 0.f);
      float v1 = fmaxf(fmaf(y1, ab1[k0 + 1], ab1[64 + k0 + 1]), 0.f);
      unsigned pk = (unsigned)f2bf(v0) | ((unsigned)f2bf(v1) << 16);
      *reinterpret_cast<unsigned*>(&x1c[L * 128 + ((2 * k0) ^ ((L & 7) << 4))]) = pk;
    }
    __syncthreads();
#pragma unroll
    for (int rb = 0; rb < 2; ++rb) {
      f32x4 acc2[4];
#pragma unroll
      for (int cb = 0; cb < 4; ++cb) acc2[cb][0] = acc2[cb][1] = acc2[cb][2] = acc2[cb][3] = 0.f;
#pragma unroll
      for (int ks = 0; ks < 2; ++ks)
#pragma unroll
        for (int cb = 0; cb < 4; ++cb) {
          int n = cb * 16 + (L & 15);
          int koff = ks * 32 + (L >> 4) * 8;
          bf16x8 bfr = *reinterpret_cast<const bf16x8*>(&x1c[n * 128 + ((2 * koff) ^ ((n & 7) << 4))]);
          acc2[cb] = __builtin_amdgcn_mfma_f32_16x16x32_bf16(w2f[rb][ks], bfr, acc2[cb], 0, 0, 0);
        }
#pragma unroll
      for (int cb = 0; cb < 4; ++cb) {
        int n = cb * 16 + (L & 15);
        int kbase = (2 * w + rb) * 16 + (L >> 4) * 4;
#pragma unroll
        for (int rp = 0; rp < 2; ++rp) {
          int r0 = 2 * rp;
          float a0 = A2v[kbase + r0], d0 = D2v[kbase + r0];
          float a1 = A2v[kbase + r0 + 1], d1 = D2v[kbase + r0 + 1];
          float v0 = fmaxf(fmaf(acc2[cb][r0], a0, d0), 0.f);
          float v1 = fmaxf(fmaf(acc2[cb][r0 + 1], a1, d1), 0.f);
          unsigned pk = (unsigned)f2bf(v0) | ((unsigned)f2bf(v1) << 16);
          int k0 = kbase + r0;
          *reinterpret_cast<unsigned*>(&x2c[n * 256 + ((2 * k0) ^ ((n & 7) << 4))]) = pk;
        }
      }
    }
    __syncthreads();
    bf16x8 b3[4][4];
#pragma unroll
    for (int cb = 0; cb < 4; ++cb)
#pragma unroll
      for (int ks = 0; ks < 4; ++ks) {
        int n = cb * 16 + (L & 15);
        int koff = ks * 32 + (L >> 4) * 8;
        b3[cb][ks] = *reinterpret_cast<const bf16x8*>(&x2c[n * 256 + ((2 * koff) ^ ((n & 7) << 4))]);
      }
#pragma unroll
    for (int rb = 0; rb < 4; ++rb) {
      f32x4 acc3[4];
#pragma unroll
      for (int cb = 0; cb < 4; ++cb) acc3[cb][0] = acc3[cb][1] = acc3[cb][2] = acc3[cb][3] = 0.f;
#pragma unroll
      for (int ks = 0; ks < 4; ++ks)
#pragma unroll
        for (int cb = 0; cb < 4; ++cb)
          acc3[cb] = __builtin_amdgcn_mfma_f32_16x16x32_bf16(w3f[rb][ks], b3[cb][ks], acc3[cb], 0, 0, 0);
      int rowbase = (4 * w + rb) * 16 + (L >> 4) * 4;
#pragma unroll
      for (int cb = 0; cb < 4; ++cb) {
#pragma unroll
        for (int r = 0; r < 4; ++r) {
          float v = fmaf(acc3[cb][r], A3v[rowbase + r], D3v[rowbase + r]);
          int xi = __float_as_int(v);
#define RMAX(CTRL) { int tm_ = __builtin_amdgcn_update_dpp(xi, xi, (CTRL), 0xF, 0xF, false); \
                     xi = __float_as_int(fmaxf(__int_as_float(xi), __int_as_float(tm_))); }
          RMAX(0x111) RMAX(0x112) RMAX(0x114) RMAX(0x118)
#undef RMAX
          if ((L & 15) == 15) {
            int row = rowbase + r;
            int bs = ch * 4 + cb;
            int b = bs / S_;
            int s = bs - b * S_;
            out1[((size_t)(b * 256 + row)) * S_ + s] = fmaxf(__int_as_float(xi), 0.f);
          }
        }
      }
    }
  }
}

__global__ void diag_kernel(float* out, float v) {
  if (threadIdx.x == 0 && blockIdx.x == 0) out[0] = v;
}

extern "C" void kernel_launch(void* const* d_in, const int* in_sizes, int n_in,
                              void* d_out, int out_size, void* d_ws, size_t ws_size,
                              hipStream_t stream) {
  const float* xy  = (const float*)d_in[0];
  const float* fea = (const float*)d_in[1];
  const float* W1  = (const float*)d_in[2];
  const float* b1  = (const float*)d_in[3];
  const float* g1  = (const float*)d_in[4];
  const float* be1 = (const float*)d_in[5];
  const float* W2  = (const float*)d_in[6];
  const float* g2  = (const float*)d_in[8];
  const float* be2 = (const float*)d_in[9];
  const float* W3  = (const float*)d_in[10];
  const float* g3  = (const float*)d_in[12];
  const float* be3 = (const float*)d_in[13];
  float* out = (float*)d_out;
  float* out1 = out + B_ * 2 * S_;

  char* w = (char*)d_ws;
  size_t off = 0;
  auto take = [&](size_t bytes) -> void* {
    void* p = w + off;
    off += (bytes + 255) & ~(size_t)255;
    return p;
  };
  int*    fps_idx = (int*)take((size_t)B_ * S_ * 4);
  float*  new_xyz = (float*)take((size_t)B_ * S_ * 2 * 4);
  int*    knn_sel = (int*)take((size_t)NF_ * 4);
  float*  P       = (float*)take((size_t)B_ * N_ * 64 * 4);   // 8.4 MB
  float*  Y1      = (float*)take((size_t)64 * NF_ * 4);       // 67.2 MB
  double* Sy1     = (double*)take(64 * 8);
  double* Sq1     = (double*)take(64 * 8);
  float*  A1      = (float*)take(64 * 4);
  float*  Bc1     = (float*)take(64 * 4);
  float*  partsA  = (float*)take((size_t)512 * 256 * 4);
  double* Sy2     = (double*)take(128 * 8);
  double* Sq2     = (double*)take(128 * 8);
  float*  A2      = (float*)take(128 * 4);
  float*  D2      = (float*)take(128 * 4);
  float*  partsB  = (float*)take((size_t)256 * 512 * 4);
  double* Sy3     = (double*)take(256 * 8);
  double* Sq3     = (double*)take(256 * 8);
  float*  A3      = (float*)take(256 * 4);
  float*  D3      = (float*)take(256 * 4);
  unsigned short* W2b = (unsigned short*)take((size_t)128 * 64 * 2);
  unsigned short* W3b = (unsigned short*)take((size_t)256 * 128 * 2);

  if (off > ws_size) {
    diag_kernel<<<1, 64, 0, stream>>>(out, (float)(ws_size >> 20));
    return;
  }

  fps_pk_kernel<<<16 + 512, 256, 0, stream>>>(xy, fea, W1, fps_idx, new_xyz, out, P);
  wconv_kernel<<<128, 256, 0, stream>>>(W2, W3, W2b, W3b);
  knn_kernel<<<dim3((S_ + 15) / 16, B_), 256, 0, stream>>>(xy, fps_idx, knn_sel);
  yk1_kernel<<<NF_ / 256, 256, 0, stream>>>(xy, knn_sel, new_xyz, P, W1, b1, Y1);

  rowstats_kernel<<<64, 1024, 0, stream>>>(Y1, Sy1, Sq1);
  absch_kernel<<<1, 64, 0, stream>>>(Sy1, Sq1, g1, be1, A1, Bc1, 64);

  passA_mfma_kernel<<<512, 256, 0, stream>>>(Y1, W2b, A1, Bc1, partsA);
  redab_kernel<<<1, 128, 0, stream>>>(partsA, Sy2, Sq2, 512, 128);
  absch_kernel<<<1, 128, 0, stream>>>(Sy2, Sq2, g2, be2, A2, D2, 128);

  passB_mfma_kernel<<<256, 256, 0, stream>>>(Y1, W2b, W3b, A1, Bc1, A2, D2, partsB);
  redab_kernel<<<1, 256, 0, stream>>>(partsB, Sy3, Sq3, 256, 256);
  absch_kernel<<<1, 256, 0, stream>>>(Sy3, Sq3, g3, be3, A3, D3, 256);

  final_mfma_kernel<<<512, 256, 0, stream>>>(Y1, W2b, W3b, A1, Bc1, A2, D2, A3, D3, out1);
}

// Round 14
// 1347.269 us; speedup vs baseline: 2.8897x; 1.0753x over previous
//
#include <hip/hip_runtime.h>
#include <math.h>

#define B_   16
#define N_   2048
#define S_   1025
#define K_   16
#define EMB_ 64
#define NF_  (B_ * S_ * K_)   // 262400
#define NCH_ (NF_ / 64)       // 4100 column-chunks of 64

typedef float v2f __attribute__((ext_vector_type(2)));
typedef short bf16x8 __attribute__((ext_vector_type(8)));
typedef float f32x4 __attribute__((ext_vector_type(4)));

__device__ __forceinline__ unsigned short f2bf(float f) {  // RNE fp32->bf16
  unsigned u = __float_as_uint(f);
  u += 0x7fffu + ((u >> 16) & 1u);
  return (unsigned short)(u >> 16);
}

// ======== FUSED: blocks 0-15 = FPS ; blocks 16+ = pk ========
// FPS distance math: validated pk-asm (bit-exact ref rounding). NEW: argmax via pairwise
// max TREE (depth 5, parallel) + tree DESCENT with compile-time-indexed muxes; left-
// preference at each level == lowest-j tie-break (identical semantics to eq-scan).
__global__ __launch_bounds__(256) __attribute__((amdgpu_waves_per_eu(1, 1)))
void fps_pk_kernel(const float* __restrict__ xy, const float* __restrict__ fea,
                   const float* __restrict__ W1,
                   int* __restrict__ fps_idx, float* __restrict__ new_xyz,
                   float* __restrict__ out0, float* __restrict__ P) {
  __shared__ float smem[8192];   // 32 KB union
  if (blockIdx.x < 16) {
    const int b = blockIdx.x;
    float2* lxy = reinterpret_cast<float2*>(smem);
    const int lane = threadIdx.x;
    const float* xb = xy + (size_t)b * 2 * N_;
    v2f pxp[16], pyp[16];
    float dist[32];
    if (lane < 64) {
      const float2* xb2 = (const float2*)xb;
      const float2* yb2 = (const float2*)(xb + N_);
#pragma unroll
      for (int q = 0; q < 16; ++q) {
        float2 x01 = xb2[lane * 16 + q];
        float2 y01 = yb2[lane * 16 + q];
        int p = lane * 32 + 2 * q;
        lxy[p] = make_float2(x01.x, y01.x);
        lxy[p + 1] = make_float2(x01.y, y01.y);
        pxp[q][0] = x01.x; pxp[q][1] = x01.y;
        pyp[q][0] = y01.x; pyp[q][1] = y01.y;
        dist[2 * q] = __builtin_inff();
        dist[2 * q + 1] = __builtin_inff();
      }
#pragma unroll
      for (int q = 0; q < 16; ++q) {
        asm volatile("" : "+v"(pxp[q]), "+v"(pyp[q]));
      }
    }
    __syncthreads();
    if (lane < 64) {
      int cur = 0;
      for (int t = 0; t < S_; ++t) {
        float2 c = lxy[cur];          // uniform-address broadcast read
        if (lane == 0) {
          fps_idx[b * S_ + t] = cur;
          new_xyz[(b * S_ + t) * 2 + 0] = c.x;
          new_xyz[(b * S_ + t) * 2 + 1] = c.y;
          out0[b * 2 * S_ + t] = c.x;
          out0[b * 2 * S_ + S_ + t] = c.y;
        }
        const float ncx = -c.x, ncy = -c.y;  // pk_add(x,-c) == rn(x-c)
        v2f ncx2; ncx2[0] = ncx; ncx2[1] = ncx;
        v2f ncy2; ncy2[0] = ncy; ncy2[1] = ncy;
#pragma unroll
        for (int q = 0; q < 16; ++q) {
          v2f dx, dy, sx, sy, dd;
          asm("v_pk_add_f32 %0, %1, %2" : "=v"(dx) : "v"(pxp[q]), "v"(ncx2));
          asm("v_pk_add_f32 %0, %1, %2" : "=v"(dy) : "v"(pyp[q]), "v"(ncy2));
          asm("v_pk_mul_f32 %0, %1, %1" : "=v"(sx) : "v"(dx));
          asm("v_pk_mul_f32 %0, %1, %1" : "=v"(sy) : "v"(dy));
          asm("v_pk_add_f32 %0, %1, %2" : "=v"(dd) : "v"(sx), "v"(sy));
          dist[2 * q] = fminf(dist[2 * q], dd[0]);
          dist[2 * q + 1] = fminf(dist[2 * q + 1], dd[1]);
        }
        // pairwise max tree (parallel, depth 5)
        float m1[16], m2[8], m3[4], m4[2];
#pragma unroll
        for (int j = 0; j < 16; ++j) m1[j] = fmaxf(dist[2 * j], dist[2 * j + 1]);
#pragma unroll
        for (int j = 0; j < 8; ++j) m2[j] = fmaxf(m1[2 * j], m1[2 * j + 1]);
#pragma unroll
        for (int j = 0; j < 4; ++j) m3[j] = fmaxf(m2[2 * j], m2[2 * j + 1]);
        m4[0] = fmaxf(m3[0], m3[1]);
        m4[1] = fmaxf(m3[2], m3[3]);
        const float lmax = fmaxf(m4[0], m4[1]);
        int xr = __float_as_int(lmax);
#define DPP_MAX_STEP(CTRL)                                                        \
        {                                                                         \
          int tmp_ = __builtin_amdgcn_update_dpp(xr, xr, (CTRL), 0xF, 0xF, false);\
          xr = __float_as_int(fmaxf(__int_as_float(xr), __int_as_float(tmp_)));   \
        }
        DPP_MAX_STEP(0x111)
        DPP_MAX_STEP(0x112)
        DPP_MAX_STEP(0x114)
        DPP_MAX_STEP(0x118)
        DPP_MAX_STEP(0x142)
        DPP_MAX_STEP(0x143)
#undef DPP_MAX_STEP
        const float g = __int_as_float(__builtin_amdgcn_readlane(xr, 63));
        // tree descent: left if left-subtree max == g (==exact) -> lowest j
        int n = (m4[0] == g) ? 0 : 1;
        float c3 = (n & 1) ? m3[2] : m3[0];
        n = 2 * n + ((c3 == g) ? 0 : 1);
        float lo2 = (n & 1) ? m2[2] : m2[0];
        float hi2 = (n & 1) ? m2[6] : m2[4];
        float c2 = (n & 2) ? hi2 : lo2;
        n = 2 * n + ((c2 == g) ? 0 : 1);
        float a0 = (n & 1) ? m1[2] : m1[0];
        float a1 = (n & 1) ? m1[6] : m1[4];
        float a2 = (n & 1) ? m1[10] : m1[8];
        float a3 = (n & 1) ? m1[14] : m1[12];
        float b0 = (n & 2) ? a1 : a0;
        float b1 = (n & 2) ? a3 : a2;
        float c1 = (n & 4) ? b1 : b0;
        n = 2 * n + ((c1 == g) ? 0 : 1);
        float e0 = (n & 1) ? dist[2] : dist[0];
        float e1 = (n & 1) ? dist[6] : dist[4];
        float e2 = (n & 1) ? dist[10] : dist[8];
        float e3 = (n & 1) ? dist[14] : dist[12];
        float e4 = (n & 1) ? dist[18] : dist[16];
        float e5 = (n & 1) ? dist[22] : dist[20];
        float e6 = (n & 1) ? dist[26] : dist[24];
        float e7 = (n & 1) ? dist[30] : dist[28];
        float f0 = (n & 2) ? e1 : e0;
        float f1 = (n & 2) ? e3 : e2;
        float f2 = (n & 2) ? e5 : e4;
        float f3 = (n & 2) ? e7 : e6;
        float g0 = (n & 4) ? f1 : f0;
        float g1 = (n & 4) ? f3 : f2;
        float c0 = (n & 8) ? g1 : g0;
        const int lf = 2 * n + ((c0 == g) ? 0 : 1);
        unsigned long long mask = __ballot(lmax == g);
        int first = __ffsll(mask) - 1;          // lowest lane with the max
        cur = __builtin_amdgcn_readlane(lane * 32 + lf, first);
      }
    }
  } else {
    const int bid = blockIdx.x - 16;
    const int t = threadIdx.x;
    const int b = bid >> 5;
    const int pt0 = (bid & 31) << 6;
    float* W1L = smem;
    float* feaL = smem + 4096;
#pragma unroll
    for (int p = 0; p < 16; ++p) {
      int idx = t + 256 * p;
      int c = idx >> 6, e = idx & 63;
      W1L[e * 64 + c] = W1[c * 66 + 2 + e];
      int r = (t >> 6) + 4 * p, cc = t & 63;
      feaL[r * 64 + cc] = fea[((size_t)b * 64 + r) * N_ + pt0 + cc];
    }
    __syncthreads();
    const int tpt = t & 15, tcq = t >> 4;
    float acc[4][4];
#pragma unroll
    for (int i = 0; i < 4; ++i)
#pragma unroll
      for (int j = 0; j < 4; ++j) acc[i][j] = 0.f;
    for (int e = 0; e < 64; ++e) {
      float4 a4 = *reinterpret_cast<const float4*>(&W1L[e * 64 + tcq * 4]);
      float4 b4 = *reinterpret_cast<const float4*>(&feaL[e * 64 + tpt * 4]);
      const float av[4] = {a4.x, a4.y, a4.z, a4.w};
      const float bvv[4] = {b4.x, b4.y, b4.z, b4.w};
#pragma unroll
      for (int i = 0; i < 4; ++i)
#pragma unroll
        for (int j = 0; j < 4; ++j) acc[i][j] = fmaf(av[i], bvv[j], acc[i][j]);
    }
#pragma unroll
    for (int j = 0; j < 4; ++j) {
      int pt = tpt * 4 + j;
      float4 v = {acc[0][j], acc[1][j], acc[2][j], acc[3][j]};
      *reinterpret_cast<float4*>(&P[((size_t)(b * N_ + pt0 + pt)) * 64 + tcq * 4]) = v;
    }
  }
}

// ---------------- W2/W3 -> bf16 (RNE), row-major ----------------
__global__ void wconv_kernel(const float* __restrict__ W2, const float* __restrict__ W3,
                             unsigned short* __restrict__ W2b, unsigned short* __restrict__ W3b) {
  int i = blockIdx.x * 256 + threadIdx.x;
  if (i < 128 * 64) W2b[i] = f2bf(W2[i]);
  if (i < 256 * 128) W3b[i] = f2bf(W3[i]);
}

// ---------------- KNN fp64-exact, 32 lanes per query point ----------------
__global__ __launch_bounds__(256) void knn_kernel(const float* __restrict__ xy,
                                                  const int* __restrict__ fps_idx,
                                                  int* __restrict__ knn_sel) {
  const int b = blockIdx.y;
  __shared__ float2 lxy[N_];
  __shared__ double lsq[N_];
  const float* xb = xy + (size_t)b * 2 * N_;
  for (int p = threadIdx.x; p < N_; p += 256) {
    float x = xb[p], y = xb[N_ + p];
    lxy[p] = make_float2(x, y);
    lsq[p] = (double)x * (double)x + (double)y * (double)y;
  }
  __syncthreads();
  const int t = threadIdx.x;
  const int s = blockIdx.x * 8 + (t >> 5);
  if (s >= S_) return;          // uniform per 32-lane group
  const int oct = t & 31;
  const int p0 = fps_idx[b * S_ + s];
  float2 q = lxy[p0];
  const double xn = (double)q.x, yn = (double)q.y;
  const double sqn = lsq[p0];
  double d16[16];
  int i16[16];
#pragma unroll
  for (int j = 0; j < 16; ++j) { d16[j] = __builtin_inf(); i16[j] = 0x7fffffff; }
  const int mlo = oct * 64;
  for (int m0 = mlo; m0 < mlo + 64; m0 += 4) {
    double dd[4];
#pragma unroll
    for (int u = 0; u < 4; ++u) {
      float2 p = lxy[m0 + u];
      double dot = (double)p.x * xn + (double)p.y * yn;
      dd[u] = (sqn - 2.0 * dot) + lsq[m0 + u];
    }
#pragma unroll
    for (int u = 0; u < 4; ++u) {
      if (dd[u] < d16[15]) {
        double d = dd[u];
        int mi = m0 + u;
#pragma unroll
        for (int j = 15; j >= 1; --j) {
          bool shift = d < d16[j - 1];
          bool ins = d < d16[j];
          d16[j] = shift ? d16[j - 1] : (ins ? d : d16[j]);
          i16[j] = shift ? i16[j - 1] : (ins ? mi : i16[j]);
        }
        if (d < d16[0]) { d16[0] = d; i16[0] = mi; }
      }
    }
  }
  // 5 merge rounds across the 32-lane group (xor 1,2,4,8,16); lex (d, idx) order.
#pragma unroll
  for (int w = 1; w <= 16; w <<= 1) {
    double nd[16]; int ni[16];
#pragma unroll
    for (int i = 0; i < 16; ++i) {
      double rd = __shfl_xor(d16[15 - i], w, 64);
      int ri = __shfl_xor(i16[15 - i], w, 64);
      bool takeR = (rd < d16[i]) || (rd == d16[i] && ri < i16[i]);
      nd[i] = takeR ? rd : d16[i];
      ni[i] = takeR ? ri : i16[i];
    }
#pragma unroll
    for (int i = 0; i < 16; ++i) { d16[i] = nd[i]; i16[i] = ni[i]; }
    if (w < 16) {
#pragma unroll
      for (int dstg = 8; dstg >= 1; dstg >>= 1) {
#pragma unroll
        for (int i = 0; i < 16; ++i) {
          if ((i & dstg) == 0) {
            int a = i, c = i + dstg;
            bool sw = (d16[a] > d16[c]) || (d16[a] == d16[c] && i16[a] > i16[c]);
            double tlo = sw ? d16[c] : d16[a];
            double thi = sw ? d16[a] : d16[c];
            int ulo = sw ? i16[c] : i16[a];
            int uhi = sw ? i16[a] : i16[c];
            d16[a] = tlo; d16[c] = thi; i16[a] = ulo; i16[c] = uhi;
          }
        }
      }
    }
  }
  if (oct == 0) {
    int* dst = knn_sel + ((size_t)b * S_ + s) * K_;
#pragma unroll
    for (int j = 0; j < 16; ++j) dst[j] = i16[j];
  }
}

// ---------------- Y1[64][NF]: gather P + W1a*dxy + b1 ----------------
__global__ __launch_bounds__(256) void yk1_kernel(const float* __restrict__ xy,
                                                  const int* __restrict__ knn_sel,
                                                  const float* __restrict__ new_xyz,
                                                  const float* __restrict__ P,
                                                  const float* __restrict__ W1,
                                                  const float* __restrict__ b1,
                                                  float* __restrict__ Y1) {
  __shared__ float w0s[64], w1s[64], bbs[64];
  const int t = threadIdx.x;
  if (t < 64) { w0s[t] = W1[t * 66 + 0]; w1s[t] = W1[t * 66 + 1]; bbs[t] = b1[t]; }
  __syncthreads();
  const int n = blockIdx.x * 256 + t;
  const int bs = n >> 4;
  const int b = bs / S_;
  const int nbr = knn_sel[n];
  const float dx = xy[(size_t)b * 2 * N_ + nbr] - new_xyz[bs * 2 + 0];
  const float dy = xy[(size_t)b * 2 * N_ + N_ + nbr] - new_xyz[bs * 2 + 1];
  const float* prow = &P[((size_t)(b * N_ + nbr)) * 64];
  for (int c4 = 0; c4 < 64; c4 += 4) {
    float4 p4 = *reinterpret_cast<const float4*>(&prow[c4]);
    float v0 = p4.x + w0s[c4 + 0] * dx + w1s[c4 + 0] * dy + bbs[c4 + 0];
    float v1 = p4.y + w0s[c4 + 1] * dx + w1s[c4 + 1] * dy + bbs[c4 + 1];
    float v2 = p4.z + w0s[c4 + 2] * dx + w1s[c4 + 2] * dy + bbs[c4 + 2];
    float v3 = p4.w + w0s[c4 + 3] * dx + w1s[c4 + 3] * dy + bbs[c4 + 3];
    Y1[(size_t)(c4 + 0) * NF_ + n] = v0;
    Y1[(size_t)(c4 + 1) * NF_ + n] = v1;
    Y1[(size_t)(c4 + 2) * NF_ + n] = v2;
    Y1[(size_t)(c4 + 3) * NF_ + n] = v3;
  }
}

// ---------------- per-row sum + sumsq (fp64) ----------------
__global__ __launch_bounds__(1024) void rowstats_kernel(const float* __restrict__ Y,
                                                        double* __restrict__ sum_out,
                                                        double* __restrict__ sq_out) {
  const int r = blockIdx.x;
  const float* row = Y + (size_t)r * NF_;
  double s = 0.0, s2 = 0.0;
  for (int i = threadIdx.x * 4; i < NF_; i += 4096) {
    float4 v = *reinterpret_cast<const float4*>(&row[i]);
    double dx = v.x, dy = v.y, dz = v.z, dw = v.w;
    s += (dx + dy) + (dz + dw);
    s2 = fma(dx, dx, s2); s2 = fma(dy, dy, s2);
    s2 = fma(dz, dz, s2); s2 = fma(dw, dw, s2);
  }
  __shared__ double sh[1024], sh2[1024];
  sh[threadIdx.x] = s; sh2[threadIdx.x] = s2;
  __syncthreads();
  for (int o = 512; o > 0; o >>= 1) {
    if (threadIdx.x < o) {
      sh[threadIdx.x] += sh[threadIdx.x + o];
      sh2[threadIdx.x] += sh2[threadIdx.x + o];
    }
    __syncthreads();
  }
  if (threadIdx.x == 0) { sum_out[r] = sh[0]; sq_out[r] = sh2[0]; }
}

// ---------------- BN coeffs from sum/sumsq (validated) ----------------
__global__ void absch_kernel(const double* __restrict__ sumv, const double* __restrict__ sqv,
                             const float* __restrict__ g, const float* __restrict__ be,
                             float* __restrict__ A, float* __restrict__ D, int M) {
  int m = threadIdx.x;
  if (m >= M) return;
  double mu = sumv[m] * (1.0 / NF_);
  double var = sqv[m] * (1.0 / NF_) - mu * mu;
  double a = (double)g[m] / sqrt(var + 1e-5);
  A[m] = (float)a;
  D[m] = (float)((double)be[m] - a * mu);
}

// ---------------- reduce partials [P][2M] -> sum[M], sq[M] ----------------
__global__ void redab_kernel(const float* __restrict__ parts, double* __restrict__ sum_out,
                             double* __restrict__ sq_out, int P, int M) {
  int m = threadIdx.x;
  if (m >= M) return;
  double a = 0.0, b = 0.0;
  for (int p = 0; p < P; ++p) {
    a += (double)parts[(size_t)p * 2 * M + m];
    b += (double)parts[(size_t)p * 2 * M + M + m];
  }
  sum_out[m] = a;
  sq_out[m] = b;
}

// DPP prefix-add across each 16-lane row group; lane (L&15)==15 holds the group total.
__device__ __forceinline__ float rowsum16(float v) {
#define RADD(CTRL) { int tm_ = __builtin_amdgcn_update_dpp(0, __float_as_int(v), (CTRL), 0xF, 0xF, true); \
                     v += __int_as_float(tm_); }
  RADD(0x111) RADD(0x112) RADD(0x114) RADD(0x118)
#undef RADD
  return v;
}

// ============ passA (MFMA): y2 = W2b * x1b, accumulate sum(y2), sum(y2^2) ============
__global__ __launch_bounds__(256) void passA_mfma_kernel(
    const float* __restrict__ Y1, const unsigned short* __restrict__ W2b,
    const float* __restrict__ A1v, const float* __restrict__ Bc1v,
    float* __restrict__ parts) {
  __shared__ float ab1[128];
  __shared__ __align__(16) unsigned short x1b[64 * 64];    // 8 KB
  const int t = threadIdx.x;
  const int w = t >> 6, L = t & 63;
  if (t < 128) ab1[t] = (t < 64) ? A1v[t] : Bc1v[t - 64];
  bf16x8 w2f[2][2];
#pragma unroll
  for (int rb = 0; rb < 2; ++rb)
#pragma unroll
    for (int ks = 0; ks < 2; ++ks) {
      int row = (2 * w + rb) * 16 + (L & 15);
      int koff = ks * 32 + (L >> 4) * 8;
      w2f[rb][ks] = *reinterpret_cast<const bf16x8*>(&W2b[row * 64 + koff]);
    }
  float vs[2][4], vq[2][4];
#pragma unroll
  for (int rb = 0; rb < 2; ++rb)
#pragma unroll
    for (int r = 0; r < 4; ++r) { vs[rb][r] = 0.f; vq[rb][r] = 0.f; }
  char* x1c = reinterpret_cast<char*>(x1b);
  for (int ch = blockIdx.x; ch < NCH_; ch += 512) {
    const size_t n0 = (size_t)ch * 64;
    __syncthreads();
#pragma unroll
    for (int e = 0; e < 8; ++e) {
      int k0 = 2 * (w + 4 * e);
      float y0 = Y1[(size_t)k0 * NF_ + n0 + L];
      float y1 = Y1[(size_t)(k0 + 1) * NF_ + n0 + L];
      float v0 = fmaxf(fmaf(y0, ab1[k0], ab1[64 + k0]), 0.f);
      float v1 = fmaxf(fmaf(y1, ab1[k0 + 1], ab1[64 + k0 + 1]), 0.f);
      unsigned pk = (unsigned)f2bf(v0) | ((unsigned)f2bf(v1) << 16);
      *reinterpret_cast<unsigned*>(&x1c[L * 128 + ((2 * k0) ^ ((L & 7) << 4))]) = pk;
    }
    __syncthreads();
#pragma unroll
    for (int rb = 0; rb < 2; ++rb) {
      f32x4 acc2[4];
#pragma unroll
      for (int cb = 0; cb < 4; ++cb) acc2[cb][0] = acc2[cb][1] = acc2[cb][2] = acc2[cb][3] = 0.f;
#pragma unroll
      for (int ks = 0; ks < 2; ++ks)
#pragma unroll
        for (int cb = 0; cb < 4; ++cb) {
          int n = cb * 16 + (L & 15);
          int koff = ks * 32 + (L >> 4) * 8;
          bf16x8 bfr = *reinterpret_cast<const bf16x8*>(&x1c[n * 128 + ((2 * koff) ^ ((n & 7) << 4))]);
          acc2[cb] = __builtin_amdgcn_mfma_f32_16x16x32_bf16(w2f[rb][ks], bfr, acc2[cb], 0, 0, 0);
        }
#pragma unroll
      for (int cb = 0; cb < 4; ++cb)
#pragma unroll
        for (int r = 0; r < 4; ++r) {
          float y = acc2[cb][r];
          vs[rb][r] += y;
          vq[rb][r] = fmaf(y, y, vq[rb][r]);
        }
    }
  }
#pragma unroll
  for (int rb = 0; rb < 2; ++rb)
#pragma unroll
    for (int r = 0; r < 4; ++r) {
      float s = rowsum16(vs[rb][r]);
      float q = rowsum16(vq[rb][r]);
      if ((L & 15) == 15) {
        int row = (2 * w + rb) * 16 + (L >> 4) * 4 + r;
        parts[(size_t)blockIdx.x * 256 + row] = s;
        parts[(size_t)blockIdx.x * 256 + 128 + row] = q;
      }
    }
}

// ============ passB (MFMA): GEMM2 -> BN2/relu -> GEMM3, sum(y3), sum(y3^2) ============
__global__ __launch_bounds__(256) void passB_mfma_kernel(
    const float* __restrict__ Y1,
    const unsigned short* __restrict__ W2b, const unsigned short* __restrict__ W3b,
    const float* __restrict__ A1v, const float* __restrict__ Bc1v,
    const float* __restrict__ A2v, const float* __restrict__ D2v,
    float* __restrict__ parts) {
  __shared__ float ab1[128];
  __shared__ __align__(16) unsigned short x1b[64 * 64];    // 8 KB
  __shared__ __align__(16) unsigned short x2b[64 * 128];   // 16 KB
  const int t = threadIdx.x;
  const int w = t >> 6, L = t & 63;
  if (t < 128) ab1[t] = (t < 64) ? A1v[t] : Bc1v[t - 64];
  bf16x8 w3f[4][4];
#pragma unroll
  for (int rb = 0; rb < 4; ++rb)
#pragma unroll
    for (int ks = 0; ks < 4; ++ks) {
      int row = (4 * w + rb) * 16 + (L & 15);
      int koff = ks * 32 + (L >> 4) * 8;
      w3f[rb][ks] = *reinterpret_cast<const bf16x8*>(&W3b[row * 128 + koff]);
    }
  bf16x8 w2f[2][2];
#pragma unroll
  for (int rb = 0; rb < 2; ++rb)
#pragma unroll
    for (int ks = 0; ks < 2; ++ks) {
      int row = (2 * w + rb) * 16 + (L & 15);
      int koff = ks * 32 + (L >> 4) * 8;
      w2f[rb][ks] = *reinterpret_cast<const bf16x8*>(&W2b[row * 64 + koff]);
    }
  float vs[4][4], vq[4][4];
#pragma unroll
  for (int rb = 0; rb < 4; ++rb)
#pragma unroll
    for (int r = 0; r < 4; ++r) { vs[rb][r] = 0.f; vq[rb][r] = 0.f; }
  char* x1c = reinterpret_cast<char*>(x1b);
  char* x2c = reinterpret_cast<char*>(x2b);
  for (int ch = blockIdx.x; ch < NCH_; ch += 256) {
    const size_t n0 = (size_t)ch * 64;
    __syncthreads();
#pragma unroll
    for (int e = 0; e < 8; ++e) {
      int k0 = 2 * (w + 4 * e);
      float y0 = Y1[(size_t)k0 * NF_ + n0 + L];
      float y1 = Y1[(size_t)(k0 + 1) * NF_ + n0 + L];
      float v0 = fmaxf(fmaf(y0, ab1[k0], ab1[64 + k0]), 0.f);
      float v1 = fmaxf(fmaf(y1, ab1[k0 + 1], ab1[64 + k0 + 1]), 0.f);
      unsigned pk = (unsigned)f2bf(v0) | ((unsigned)f2bf(v1) << 16);
      *reinterpret_cast<unsigned*>(&x1c[L * 128 + ((2 * k0) ^ ((L & 7) << 4))]) = pk;
    }
    __syncthreads();
#pragma unroll
    for (int rb = 0; rb < 2; ++rb) {
      f32x4 acc2[4];
#pragma unroll
      for (int cb = 0; cb < 4; ++cb) acc2[cb][0] = acc2[cb][1] = acc2[cb][2] = acc2[cb][3] = 0.f;
#pragma unroll
      for (int ks = 0; ks < 2; ++ks)
#pragma unroll
        for (int cb = 0; cb < 4; ++cb) {
          int n = cb * 16 + (L & 15);
          int koff = ks * 32 + (L >> 4) * 8;
          bf16x8 bfr = *reinterpret_cast<const bf16x8*>(&x1c[n * 128 + ((2 * koff) ^ ((n & 7) << 4))]);
          acc2[cb] = __builtin_amdgcn_mfma_f32_16x16x32_bf16(w2f[rb][ks], bfr, acc2[cb], 0, 0, 0);
        }
#pragma unroll
      for (int cb = 0; cb < 4; ++cb) {
        int n = cb * 16 + (L & 15);
        int kbase = (2 * w + rb) * 16 + (L >> 4) * 4;
#pragma unroll
        for (int rp = 0; rp < 2; ++rp) {
          int r0 = 2 * rp;
          float a0 = A2v[kbase + r0], d0 = D2v[kbase + r0];
          float a1 = A2v[kbase + r0 + 1], d1 = D2v[kbase + r0 + 1];
          float v0 = fmaxf(fmaf(acc2[cb][r0], a0, d0), 0.f);
          float v1 = fmaxf(fmaf(acc2[cb][r0 + 1], a1, d1), 0.f);
          unsigned pk = (unsigned)f2bf(v0) | ((unsigned)f2bf(v1) << 16);
          int k0 = kbase + r0;
          *reinterpret_cast<unsigned*>(&x2c[n * 256 + ((2 * k0) ^ ((n & 7) << 4))]) = pk;
        }
      }
    }
    __syncthreads();
    bf16x8 b3[4][4];
#pragma unroll
    for (int cb = 0; cb < 4; ++cb)
#pragma unroll
      for (int ks = 0; ks < 4; ++ks) {
        int n = cb * 16 + (L & 15);
        int koff = ks * 32 + (L >> 4) * 8;
        b3[cb][ks] = *reinterpret_cast<const bf16x8*>(&x2c[n * 256 + ((2 * koff) ^ ((n & 7) << 4))]);
      }
#pragma unroll
    for (int rb = 0; rb < 4; ++rb) {
      f32x4 acc3[4];
#pragma unroll
      for (int cb = 0; cb < 4; ++cb) acc3[cb][0] = acc3[cb][1] = acc3[cb][2] = acc3[cb][3] = 0.f;
#pragma unroll
      for (int ks = 0; ks < 4; ++ks)
#pragma unroll
        for (int cb = 0; cb < 4; ++cb)
          acc3[cb] = __builtin_amdgcn_mfma_f32_16x16x32_bf16(w3f[rb][ks], b3[cb][ks], acc3[cb], 0, 0, 0);
#pragma unroll
      for (int cb = 0; cb < 4; ++cb)
#pragma unroll
        for (int r = 0; r < 4; ++r) {
          float y = acc3[cb][r];
          vs[rb][r] += y;
          vq[rb][r] = fmaf(y, y, vq[rb][r]);
        }
    }
  }
#pragma unroll
  for (int rb = 0; rb < 4; ++rb)
#pragma unroll
    for (int r = 0; r < 4; ++r) {
      float s = rowsum16(vs[rb][r]);
      float q = rowsum16(vq[rb][r]);
      if ((L & 15) == 15) {
        int row = (4 * w + rb) * 16 + (L >> 4) * 4 + r;
        parts[(size_t)blockIdx.x * 512 + row] = s;
        parts[(size_t)blockIdx.x * 512 + 256 + row] = q;
      }
    }
}

// ============ final (MFMA, validated): GEMM2 -> BN2 -> GEMM3 -> BN3 -> k-max ============
__global__ __launch_bounds__(256) void final_mfma_kernel(
    const float* __restrict__ Y1,
    const unsigned short* __restrict__ W2b,
    const unsigned short* __restrict__ W3b,
    const float* __restrict__ A1v, const float* __restrict__ Bc1v,
    const float* __restrict__ A2v, const float* __restrict__ D2v,
    const float* __restrict__ A3v, const float* __restrict__ D3v,
    float* __restrict__ out1) {
  __shared__ float ab1[128];
  __shared__ __align__(16) unsigned short x1b[64 * 64];
  __shared__ __align__(16) unsigned short x2b[64 * 128];
  const int t = threadIdx.x;
  const int w = t >> 6, L = t & 63;
  if (t < 128) ab1[t] = (t < 64) ? A1v[t] : Bc1v[t - 64];
  bf16x8 w3f[4][4];
#pragma unroll
  for (int rb = 0; rb < 4; ++rb)
#pragma unroll
    for (int ks = 0; ks < 4; ++ks) {
      int row = (4 * w + rb) * 16 + (L & 15);
      int koff = ks * 32 + (L >> 4) * 8;
      w3f[rb][ks] = *reinterpret_cast<const bf16x8*>(&W3b[row * 128 + koff]);
    }
  bf16x8 w2f[2][2];
#pragma unroll
  for (int rb = 0; rb < 2; ++rb)
#pragma unroll
    for (int ks = 0; ks < 2; ++ks) {
      int row = (2 * w + rb) * 16 + (L & 15);
      int koff = ks * 32 + (L >> 4) * 8;
      w2f[rb][ks] = *reinterpret_cast<const bf16x8*>(&W2b[row * 64 + koff]);
    }
  char* x1c = reinterpret_cast<char*>(x1b);
  char* x2c = reinterpret_cast<char*>(x2b);
  for (int ch = blockIdx.x; ch < NCH_; ch += 512) {
    const size_t n0 = (size_t)ch * 64;
    __syncthreads();
#pragma unroll
    for (int e = 0; e < 8; ++e) {
      int k0 = 2 * (w + 4 * e);
      float y0 = Y1[(size_t)k0 * NF_ + n0 + L];
      float y1 = Y1[(size_t)(k0 + 1) * NF_ + n0 + L];
      float v0 = fmaxf(fmaf(y0, ab1[k0], ab1[64 + k0]), 0.f);
      float v1 = fmaxf(fmaf(y1, ab1[k0 + 1], ab1[64 + k0 + 1]), 0.f);
      unsigned pk = (unsigned)f2bf(v0) | ((unsigned)f2bf(v1) << 16);
      *reinterpret_cast<unsigned*>(&x1c[L * 128 + ((2 * k0) ^ ((L & 7) << 4))]) = pk;
    }
    __syncthreads();
#pragma unroll
    for (int rb = 0; rb < 2; ++rb) {
      f32x4 acc2[4];
#pragma unroll
      for (int cb = 0; cb < 4; ++cb) acc2[cb][0] = acc2[cb][1] = acc2[cb][2] = acc2[cb][3] = 0.f;
#pragma unroll
      for (int ks = 0; ks < 2; ++ks)
#pragma unroll
        for (int cb = 0; cb < 4; ++cb) {
          int n = cb * 16 + (L & 15);
          int koff = ks * 32 + (L >> 4) * 8;
          bf16x8 bfr = *reinterpret_cast<const bf16x8*>(&x1c[n * 128 + ((2 * koff) ^ ((n & 7) << 4))]);
          acc2[cb] = __builtin_amdgcn_mfma_f32_16x16x32_bf16(w2f[rb][ks], bfr, acc2[cb], 0, 0, 0);
        }
#pragma unroll
      for (int cb = 0; cb < 4; ++cb) {
        int n = cb * 16 + (L & 15);
        int kbase = (2 * w + rb) * 16 + (L >> 4) * 4;
#pragma unroll
        for (int rp = 0; rp < 2; ++rp) {
          int r0 = 2 * rp;
          float a0 = A2v[kbase + r0], d0 = D2v[kbase + r0];
          float a1 = A2v[kbase + r0 + 1], d1 = D2v[kbase + r0 + 1];
          float v0 = fmaxf(fmaf(acc2[cb][r0], a0, d0), 0.f);
          float v1 = fmaxf(fmaf(acc2[cb][r0 + 1], a1, d1), 0.f);
          unsigned pk = (unsigned)f2bf(v0) | ((unsigned)f2bf(v1) << 16);
          int k0 = kbase + r0;
          *reinterpret_cast<unsigned*>(&x2c[n * 256 + ((2 * k0) ^ ((n & 7) << 4))]) = pk;
        }
      }
    }
    __syncthreads();
    bf16x8 b3[4][4];
#pragma unroll
    for (int cb = 0; cb < 4; ++cb)
#pragma unroll
      for (int ks = 0; ks < 4; ++ks) {
        int n = cb * 16 + (L & 15);
        int koff = ks * 32 + (L >> 4) * 8;
        b3[cb][ks] = *reinterpret_cast<const bf16x8*>(&x2c[n * 256 + ((2 * koff) ^ ((n & 7) << 4))]);
      }
#pragma unroll
    for (int rb = 0; rb < 4; ++rb) {
      f32x4 acc3[4];
#pragma unroll
      for (int cb = 0; cb < 4; ++cb) acc3[cb][0] = acc3[cb][1] = acc3[cb][2] = acc3[cb][3] = 0.f;
#pragma unroll
      for (int ks = 0; ks < 4; ++ks)
#pragma unroll
        for (int cb = 0; cb < 4; ++cb)
          acc3[cb] = __builtin_amdgcn_mfma_f32_16x16x32_bf16(w3f[rb][ks], b3[cb][ks], acc3[cb], 0, 0, 0);
      int rowbase = (4 * w + rb) * 16 + (L >> 4) * 4;
#pragma unroll
      for (int cb = 0; cb < 4; ++cb) {
#pragma unroll
        for (int r = 0; r < 4; ++r) {
          float v = fmaf(acc3[cb][r], A3v[rowbase + r], D3v[rowbase + r]);
          int xi = __float_as_int(v);
#define RMAX(CTRL) { int tm_ = __builtin_amdgcn_update_dpp(xi, xi, (CTRL), 0xF, 0xF, false); \
                     xi = __float_as_int(fmaxf(__int_as_float(xi), __int_as_float(tm_))); }
          RMAX(0x111) RMAX(0x112) RMAX(0x114) RMAX(0x118)
#undef RMAX
          if ((L & 15) == 15) {
            int row = rowbase + r;
            int bs = ch * 4 + cb;
            int b = bs / S_;
            int s = bs - b * S_;
            out1[((size_t)(b * 256 + row)) * S_ + s] = fmaxf(__int_as_float(xi), 0.f);
          }
        }
      }
    }
  }
}

__global__ void diag_kernel(float* out, float v) {
  if (threadIdx.x == 0 && blockIdx.x == 0) out[0] = v;
}

extern "C" void kernel_launch(void* const* d_in, const int* in_sizes, int n_in,
                              void* d_out, int out_size, void* d_ws, size_t ws_size,
                              hipStream_t stream) {
  const float* xy  = (const float*)d_in[0];
  const float* fea = (const float*)d_in[1];
  const float* W1  = (const float*)d_in[2];
  const float* b1  = (const float*)d_in[3];
  const float* g1  = (const float*)d_in[4];
  const float* be1 = (const float*)d_in[5];
  const float* W2  = (const float*)d_in[6];
  const float* g2  = (const float*)d_in[8];
  const float* be2 = (const float*)d_in[9];
  const float* W3  = (const float*)d_in[10];
  const float* g3  = (const float*)d_in[12];
  const float* be3 = (const float*)d_in[13];
  float* out = (float*)d_out;
  float* out1 = out + B_ * 2 * S_;

  char* w = (char*)d_ws;
  size_t off = 0;
  auto take = [&](size_t bytes) -> void* {
    void* p = w + off;
    off += (bytes + 255) & ~(size_t)255;
    return p;
  };
  int*    fps_idx = (int*)take((size_t)B_ * S_ * 4);
  float*  new_xyz = (float*)take((size_t)B_ * S_ * 2 * 4);
  int*    knn_sel = (int*)take((size_t)NF_ * 4);
  float*  P       = (float*)take((size_t)B_ * N_ * 64 * 4);   // 8.4 MB
  float*  Y1      = (float*)take((size_t)64 * NF_ * 4);       // 67.2 MB
  double* Sy1     = (double*)take(64 * 8);
  double* Sq1     = (double*)take(64 * 8);
  float*  A1      = (float*)take(64 * 4);
  float*  Bc1     = (float*)take(64 * 4);
  float*  partsA  = (float*)take((size_t)512 * 256 * 4);
  double* Sy2     = (double*)take(128 * 8);
  double* Sq2     = (double*)take(128 * 8);
  float*  A2      = (float*)take(128 * 4);
  float*  D2      = (float*)take(128 * 4);
  float*  partsB  = (float*)take((size_t)256 * 512 * 4);
  double* Sy3     = (double*)take(256 * 8);
  double* Sq3     = (double*)take(256 * 8);
  float*  A3      = (float*)take(256 * 4);
  float*  D3      = (float*)take(256 * 4);
  unsigned short* W2b = (unsigned short*)take((size_t)128 * 64 * 2);
  unsigned short* W3b = (unsigned short*)take((size_t)256 * 128 * 2);

  if (off > ws_size) {
    diag_kernel<<<1, 64, 0, stream>>>(out, (float)(ws_size >> 20));
    return;
  }

  fps_pk_kernel<<<16 + 512, 256, 0, stream>>>(xy, fea, W1, fps_idx, new_xyz, out, P);
  wconv_kernel<<<128, 256, 0, stream>>>(W2, W3, W2b, W3b);
  knn_kernel<<<dim3((S_ + 7) / 8, B_), 256, 0, stream>>>(xy, fps_idx, knn_sel);
  yk1_kernel<<<NF_ / 256, 256, 0, stream>>>(xy, knn_sel, new_xyz, P, W1, b1, Y1);

  rowstats_kernel<<<64, 1024, 0, stream>>>(Y1, Sy1, Sq1);
  absch_kernel<<<1, 64, 0, stream>>>(Sy1, Sq1, g1, be1, A1, Bc1, 64);

  passA_mfma_kernel<<<512, 256, 0, stream>>>(Y1, W2b, A1, Bc1, partsA);
  redab_kernel<<<1, 128, 0, stream>>>(partsA, Sy2, Sq2, 512, 128);
  absch_kernel<<<1, 128, 0, stream>>>(Sy2, Sq2, g2, be2, A2, D2, 128);

  passB_mfma_kernel<<<256, 256, 0, stream>>>(Y1, W2b, W3b, A1, Bc1, A2, D2, partsB);
  redab_kernel<<<1, 256, 0, stream>>>(partsB, Sy3, Sq3, 256, 256);
  absch_kernel<<<1, 256, 0, stream>>>(Sy3, Sq3, g3, be3, A3, D3, 256);

  final_mfma_kernel<<<512, 256, 0, stream>>>(Y1, W2b, W3b, A1, Bc1, A2, D2, A3, D3, out1);
}

// Round 15
// 1343.225 us; speedup vs baseline: 2.8984x; 1.0030x over previous
//
#include <hip/hip_runtime.h>
#include <math.h>

#define B_   16
#define N_   2048
#define S_   1025
#define K_   16
#define EMB_ 64
#define NF_  (B_ * S_ * K_)   // 262400
#define NCH_ (NF_ / 64)       // 4100 column-chunks of 64

typedef float v2f __attribute__((ext_vector_type(2)));
typedef short bf16x8 __attribute__((ext_vector_type(8)));
typedef float f32x4 __attribute__((ext_vector_type(4)));

__device__ __forceinline__ unsigned short f2bf(float f) {  // RNE fp32->bf16
  unsigned u = __float_as_uint(f);
  u += 0x7fffu + ((u >> 16) & 1u);
  return (unsigned short)(u >> 16);
}

// ======== FUSED: blocks 0-15 = FPS ; 16..527 = pk ; 528 = wconv ========
__global__ __launch_bounds__(256) __attribute__((amdgpu_waves_per_eu(1, 1)))
void fps_pk_kernel(const float* __restrict__ xy, const float* __restrict__ fea,
                   const float* __restrict__ W1,
                   const float* __restrict__ W2, const float* __restrict__ W3,
                   int* __restrict__ fps_idx, float* __restrict__ new_xyz,
                   float* __restrict__ out0, float* __restrict__ P,
                   unsigned short* __restrict__ W2b, unsigned short* __restrict__ W3b) {
  __shared__ float smem[8192];   // 32 KB union
  if (blockIdx.x < 16) {
    const int b = blockIdx.x;
    float2* lxy = reinterpret_cast<float2*>(smem);
    const int lane = threadIdx.x;
    const float* xb = xy + (size_t)b * 2 * N_;
    v2f pxp[16], pyp[16];
    float dist[32];
    if (lane < 64) {
      const float2* xb2 = (const float2*)xb;
      const float2* yb2 = (const float2*)(xb + N_);
#pragma unroll
      for (int q = 0; q < 16; ++q) {
        float2 x01 = xb2[lane * 16 + q];
        float2 y01 = yb2[lane * 16 + q];
        int p = lane * 32 + 2 * q;
        lxy[p] = make_float2(x01.x, y01.x);
        lxy[p + 1] = make_float2(x01.y, y01.y);
        pxp[q][0] = x01.x; pxp[q][1] = x01.y;
        pyp[q][0] = y01.x; pyp[q][1] = y01.y;
        dist[2 * q] = __builtin_inff();
        dist[2 * q + 1] = __builtin_inff();
      }
#pragma unroll
      for (int q = 0; q < 16; ++q) {
        asm volatile("" : "+v"(pxp[q]), "+v"(pyp[q]));
      }
    }
    __syncthreads();
    if (lane < 64) {
      int cur = 0;
      for (int t = 0; t < S_; ++t) {
        float2 c = lxy[cur];          // uniform-address broadcast read
        if (lane == 0) {
          fps_idx[b * S_ + t] = cur;
          new_xyz[(b * S_ + t) * 2 + 0] = c.x;
          new_xyz[(b * S_ + t) * 2 + 1] = c.y;
          out0[b * 2 * S_ + t] = c.x;
          out0[b * 2 * S_ + S_ + t] = c.y;
        }
        const float ncx = -c.x, ncy = -c.y;  // pk_add(x,-c) == rn(x-c)
        v2f ncx2; ncx2[0] = ncx; ncx2[1] = ncx;
        v2f ncy2; ncy2[0] = ncy; ncy2[1] = ncy;
#pragma unroll
        for (int q = 0; q < 16; ++q) {
          v2f dx, dy, sx, sy, dd;
          asm("v_pk_add_f32 %0, %1, %2" : "=v"(dx) : "v"(pxp[q]), "v"(ncx2));
          asm("v_pk_add_f32 %0, %1, %2" : "=v"(dy) : "v"(pyp[q]), "v"(ncy2));
          asm("v_pk_mul_f32 %0, %1, %1" : "=v"(sx) : "v"(dx));
          asm("v_pk_mul_f32 %0, %1, %1" : "=v"(sy) : "v"(dy));
          asm("v_pk_add_f32 %0, %1, %2" : "=v"(dd) : "v"(sx), "v"(sy));
          dist[2 * q] = fminf(dist[2 * q], dd[0]);
          dist[2 * q + 1] = fminf(dist[2 * q + 1], dd[1]);
        }
        // pairwise max tree (parallel, depth 5)
        float m1[16], m2[8], m3[4], m4[2];
#pragma unroll
        for (int j = 0; j < 16; ++j) m1[j] = fmaxf(dist[2 * j], dist[2 * j + 1]);
#pragma unroll
        for (int j = 0; j < 8; ++j) m2[j] = fmaxf(m1[2 * j], m1[2 * j + 1]);
#pragma unroll
        for (int j = 0; j < 4; ++j) m3[j] = fmaxf(m2[2 * j], m2[2 * j + 1]);
        m4[0] = fmaxf(m3[0], m3[1]);
        m4[1] = fmaxf(m3[2], m3[3]);
        const float lmax = fmaxf(m4[0], m4[1]);
        int xr = __float_as_int(lmax);
#define DPP_MAX_STEP(CTRL)                                                        \
        {                                                                         \
          int tmp_ = __builtin_amdgcn_update_dpp(xr, xr, (CTRL), 0xF, 0xF, false);\
          xr = __float_as_int(fmaxf(__int_as_float(xr), __int_as_float(tmp_)));   \
        }
        DPP_MAX_STEP(0x111)
        DPP_MAX_STEP(0x112)
        DPP_MAX_STEP(0x114)
        DPP_MAX_STEP(0x118)
        DPP_MAX_STEP(0x142)
        DPP_MAX_STEP(0x143)
#undef DPP_MAX_STEP
        const float g = __int_as_float(__builtin_amdgcn_readlane(xr, 63));
        // tree descent: left if left-subtree max == g (==exact) -> lowest j
        int n = (m4[0] == g) ? 0 : 1;
        float c3 = (n & 1) ? m3[2] : m3[0];
        n = 2 * n + ((c3 == g) ? 0 : 1);
        float lo2 = (n & 1) ? m2[2] : m2[0];
        float hi2 = (n & 1) ? m2[6] : m2[4];
        float c2 = (n & 2) ? hi2 : lo2;
        n = 2 * n + ((c2 == g) ? 0 : 1);
        float a0 = (n & 1) ? m1[2] : m1[0];
        float a1 = (n & 1) ? m1[6] : m1[4];
        float a2 = (n & 1) ? m1[10] : m1[8];
        float a3 = (n & 1) ? m1[14] : m1[12];
        float b0 = (n & 2) ? a1 : a0;
        float b1 = (n & 2) ? a3 : a2;
        float c1 = (n & 4) ? b1 : b0;
        n = 2 * n + ((c1 == g) ? 0 : 1);
        float e0 = (n & 1) ? dist[2] : dist[0];
        float e1 = (n & 1) ? dist[6] : dist[4];
        float e2 = (n & 1) ? dist[10] : dist[8];
        float e3 = (n & 1) ? dist[14] : dist[12];
        float e4 = (n & 1) ? dist[18] : dist[16];
        float e5 = (n & 1) ? dist[22] : dist[20];
        float e6 = (n & 1) ? dist[26] : dist[24];
        float e7 = (n & 1) ? dist[30] : dist[28];
        float f0 = (n & 2) ? e1 : e0;
        float f1 = (n & 2) ? e3 : e2;
        float f2 = (n & 2) ? e5 : e4;
        float f3 = (n & 2) ? e7 : e6;
        float g0 = (n & 4) ? f1 : f0;
        float g1 = (n & 4) ? f3 : f2;
        float c0 = (n & 8) ? g1 : g0;
        const int lf = 2 * n + ((c0 == g) ? 0 : 1);
        unsigned long long mask = __ballot(lmax == g);
        int first = __ffsll(mask) - 1;          // lowest lane with the max
        cur = __builtin_amdgcn_readlane(lane * 32 + lf, first);
      }
    }
  } else if (blockIdx.x < 528) {
    const int bid = blockIdx.x - 16;
    const int t = threadIdx.x;
    const int b = bid >> 5;
    const int pt0 = (bid & 31) << 6;
    float* W1L = smem;
    float* feaL = smem + 4096;
#pragma unroll
    for (int p = 0; p < 16; ++p) {
      int idx = t + 256 * p;
      int c = idx >> 6, e = idx & 63;
      W1L[e * 64 + c] = W1[c * 66 + 2 + e];
      int r = (t >> 6) + 4 * p, cc = t & 63;
      feaL[r * 64 + cc] = fea[((size_t)b * 64 + r) * N_ + pt0 + cc];
    }
    __syncthreads();
    const int tpt = t & 15, tcq = t >> 4;
    float acc[4][4];
#pragma unroll
    for (int i = 0; i < 4; ++i)
#pragma unroll
      for (int j = 0; j < 4; ++j) acc[i][j] = 0.f;
    for (int e = 0; e < 64; ++e) {
      float4 a4 = *reinterpret_cast<const float4*>(&W1L[e * 64 + tcq * 4]);
      float4 b4 = *reinterpret_cast<const float4*>(&feaL[e * 64 + tpt * 4]);
      const float av[4] = {a4.x, a4.y, a4.z, a4.w};
      const float bvv[4] = {b4.x, b4.y, b4.z, b4.w};
#pragma unroll
      for (int i = 0; i < 4; ++i)
#pragma unroll
        for (int j = 0; j < 4; ++j) acc[i][j] = fmaf(av[i], bvv[j], acc[i][j]);
    }
#pragma unroll
    for (int j = 0; j < 4; ++j) {
      int pt = tpt * 4 + j;
      float4 v = {acc[0][j], acc[1][j], acc[2][j], acc[3][j]};
      *reinterpret_cast<float4*>(&P[((size_t)(b * N_ + pt0 + pt)) * 64 + tcq * 4]) = v;
    }
  } else {
    // wconv: W2/W3 -> bf16 (RNE)
    const int t = threadIdx.x;
    for (int i = t; i < 128 * 64; i += 256) W2b[i] = f2bf(W2[i]);
    for (int i = t; i < 256 * 128; i += 256) W3b[i] = f2bf(W3[i]);
  }
}

// ---------------- KNN fp64-exact, 32 lanes per query point (validated) ----------------
__global__ __launch_bounds__(256) void knn_kernel(const float* __restrict__ xy,
                                                  const int* __restrict__ fps_idx,
                                                  int* __restrict__ knn_sel) {
  const int b = blockIdx.y;
  __shared__ float2 lxy[N_];
  __shared__ double lsq[N_];
  const float* xb = xy + (size_t)b * 2 * N_;
  for (int p = threadIdx.x; p < N_; p += 256) {
    float x = xb[p], y = xb[N_ + p];
    lxy[p] = make_float2(x, y);
    lsq[p] = (double)x * (double)x + (double)y * (double)y;
  }
  __syncthreads();
  const int t = threadIdx.x;
  const int s = blockIdx.x * 8 + (t >> 5);
  if (s >= S_) return;
  const int oct = t & 31;
  const int p0 = fps_idx[b * S_ + s];
  float2 q = lxy[p0];
  const double xn = (double)q.x, yn = (double)q.y;
  const double sqn = lsq[p0];
  double d16[16];
  int i16[16];
#pragma unroll
  for (int j = 0; j < 16; ++j) { d16[j] = __builtin_inf(); i16[j] = 0x7fffffff; }
  const int mlo = oct * 64;
  for (int m0 = mlo; m0 < mlo + 64; m0 += 4) {
    double dd[4];
#pragma unroll
    for (int u = 0; u < 4; ++u) {
      float2 p = lxy[m0 + u];
      double dot = (double)p.x * xn + (double)p.y * yn;
      dd[u] = (sqn - 2.0 * dot) + lsq[m0 + u];
    }
#pragma unroll
    for (int u = 0; u < 4; ++u) {
      if (dd[u] < d16[15]) {
        double d = dd[u];
        int mi = m0 + u;
#pragma unroll
        for (int j = 15; j >= 1; --j) {
          bool shift = d < d16[j - 1];
          bool ins = d < d16[j];
          d16[j] = shift ? d16[j - 1] : (ins ? d : d16[j]);
          i16[j] = shift ? i16[j - 1] : (ins ? mi : i16[j]);
        }
        if (d < d16[0]) { d16[0] = d; i16[0] = mi; }
      }
    }
  }
#pragma unroll
  for (int w = 1; w <= 16; w <<= 1) {
    double nd[16]; int ni[16];
#pragma unroll
    for (int i = 0; i < 16; ++i) {
      double rd = __shfl_xor(d16[15 - i], w, 64);
      int ri = __shfl_xor(i16[15 - i], w, 64);
      bool takeR = (rd < d16[i]) || (rd == d16[i] && ri < i16[i]);
      nd[i] = takeR ? rd : d16[i];
      ni[i] = takeR ? ri : i16[i];
    }
#pragma unroll
    for (int i = 0; i < 16; ++i) { d16[i] = nd[i]; i16[i] = ni[i]; }
    if (w < 16) {
#pragma unroll
      for (int dstg = 8; dstg >= 1; dstg >>= 1) {
#pragma unroll
        for (int i = 0; i < 16; ++i) {
          if ((i & dstg) == 0) {
            int a = i, c = i + dstg;
            bool sw = (d16[a] > d16[c]) || (d16[a] == d16[c] && i16[a] > i16[c]);
            double tlo = sw ? d16[c] : d16[a];
            double thi = sw ? d16[a] : d16[c];
            int ulo = sw ? i16[c] : i16[a];
            int uhi = sw ? i16[a] : i16[c];
            d16[a] = tlo; d16[c] = thi; i16[a] = ulo; i16[c] = uhi;
          }
        }
      }
    }
  }
  if (oct == 0) {
    int* dst = knn_sel + ((size_t)b * S_ + s) * K_;
#pragma unroll
    for (int j = 0; j < 16; ++j) dst[j] = i16[j];
  }
}

// ---------------- Y1[64][NF]: gather P + W1a*dxy + b1 ----------------
__global__ __launch_bounds__(256) void yk1_kernel(const float* __restrict__ xy,
                                                  const int* __restrict__ knn_sel,
                                                  const float* __restrict__ new_xyz,
                                                  const float* __restrict__ P,
                                                  const float* __restrict__ W1,
                                                  const float* __restrict__ b1,
                                                  float* __restrict__ Y1) {
  __shared__ float w0s[64], w1s[64], bbs[64];
  const int t = threadIdx.x;
  if (t < 64) { w0s[t] = W1[t * 66 + 0]; w1s[t] = W1[t * 66 + 1]; bbs[t] = b1[t]; }
  __syncthreads();
  const int n = blockIdx.x * 256 + t;
  const int bs = n >> 4;
  const int b = bs / S_;
  const int nbr = knn_sel[n];
  const float dx = xy[(size_t)b * 2 * N_ + nbr] - new_xyz[bs * 2 + 0];
  const float dy = xy[(size_t)b * 2 * N_ + N_ + nbr] - new_xyz[bs * 2 + 1];
  const float* prow = &P[((size_t)(b * N_ + nbr)) * 64];
  for (int c4 = 0; c4 < 64; c4 += 4) {
    float4 p4 = *reinterpret_cast<const float4*>(&prow[c4]);
    float v0 = p4.x + w0s[c4 + 0] * dx + w1s[c4 + 0] * dy + bbs[c4 + 0];
    float v1 = p4.y + w0s[c4 + 1] * dx + w1s[c4 + 1] * dy + bbs[c4 + 1];
    float v2 = p4.z + w0s[c4 + 2] * dx + w1s[c4 + 2] * dy + bbs[c4 + 2];
    float v3 = p4.w + w0s[c4 + 3] * dx + w1s[c4 + 3] * dy + bbs[c4 + 3];
    Y1[(size_t)(c4 + 0) * NF_ + n] = v0;
    Y1[(size_t)(c4 + 1) * NF_ + n] = v1;
    Y1[(size_t)(c4 + 2) * NF_ + n] = v2;
    Y1[(size_t)(c4 + 3) * NF_ + n] = v3;
  }
}

// ---------------- rowstats: 4 quarters x 64 rows, float partials ----------------
__global__ __launch_bounds__(256) void rowstats_kernel(const float* __restrict__ Y,
                                                       float* __restrict__ parts) {
  const int r = blockIdx.x & 63;
  const int qtr = blockIdx.x >> 6;   // 0..3
  const int QLEN = NF_ / 4;          // 65600
  const float* seg = Y + (size_t)r * NF_ + (size_t)qtr * QLEN;
  double s = 0.0, s2 = 0.0;
  for (int i = threadIdx.x * 4; i < QLEN; i += 1024) {
    float4 v = *reinterpret_cast<const float4*>(&seg[i]);
    double dx = v.x, dy = v.y, dz = v.z, dw = v.w;
    s += (dx + dy) + (dz + dw);
    s2 = fma(dx, dx, s2); s2 = fma(dy, dy, s2);
    s2 = fma(dz, dz, s2); s2 = fma(dw, dw, s2);
  }
  __shared__ double sh[256], sh2[256];
  sh[threadIdx.x] = s; sh2[threadIdx.x] = s2;
  __syncthreads();
  for (int o = 128; o > 0; o >>= 1) {
    if (threadIdx.x < o) {
      sh[threadIdx.x] += sh[threadIdx.x + o];
      sh2[threadIdx.x] += sh2[threadIdx.x + o];
    }
    __syncthreads();
  }
  if (threadIdx.x == 0) {
    parts[(size_t)qtr * 128 + r] = (float)sh[0];
    parts[(size_t)qtr * 128 + 64 + r] = (float)sh2[0];
  }
}

// ---------------- fused reduce + BN coeffs: parts[P][2M] -> A[M], D[M] ----------------
__global__ void redabsch_kernel(const float* __restrict__ parts, int P, int M,
                                const float* __restrict__ g, const float* __restrict__ be,
                                float* __restrict__ A, float* __restrict__ D) {
  int m = threadIdx.x;
  if (m >= M) return;
  double a = 0.0, b = 0.0;
  for (int p = 0; p < P; ++p) {
    a += (double)parts[(size_t)p * 2 * M + m];
    b += (double)parts[(size_t)p * 2 * M + M + m];
  }
  double mu = a * (1.0 / NF_);
  double var = b * (1.0 / NF_) - mu * mu;
  double aa = (double)g[m] / sqrt(var + 1e-5);
  A[m] = (float)aa;
  D[m] = (float)((double)be[m] - aa * mu);
}

// DPP prefix-add across each 16-lane row group; lane (L&15)==15 holds the group total.
__device__ __forceinline__ float rowsum16(float v) {
#define RADD(CTRL) { int tm_ = __builtin_amdgcn_update_dpp(0, __float_as_int(v), (CTRL), 0xF, 0xF, true); \
                     v += __int_as_float(tm_); }
  RADD(0x111) RADD(0x112) RADD(0x114) RADD(0x118)
#undef RADD
  return v;
}

// ============ passA (MFMA): y2 = W2b * x1b, accumulate sum(y2), sum(y2^2) ============
__global__ __launch_bounds__(256) void passA_mfma_kernel(
    const float* __restrict__ Y1, const unsigned short* __restrict__ W2b,
    const float* __restrict__ A1v, const float* __restrict__ Bc1v,
    float* __restrict__ parts) {
  __shared__ float ab1[128];
  __shared__ __align__(16) unsigned short x1b[64 * 64];    // 8 KB
  const int t = threadIdx.x;
  const int w = t >> 6, L = t & 63;
  if (t < 128) ab1[t] = (t < 64) ? A1v[t] : Bc1v[t - 64];
  bf16x8 w2f[2][2];
#pragma unroll
  for (int rb = 0; rb < 2; ++rb)
#pragma unroll
    for (int ks = 0; ks < 2; ++ks) {
      int row = (2 * w + rb) * 16 + (L & 15);
      int koff = ks * 32 + (L >> 4) * 8;
      w2f[rb][ks] = *reinterpret_cast<const bf16x8*>(&W2b[row * 64 + koff]);
    }
  float vs[2][4], vq[2][4];
#pragma unroll
  for (int rb = 0; rb < 2; ++rb)
#pragma unroll
    for (int r = 0; r < 4; ++r) { vs[rb][r] = 0.f; vq[rb][r] = 0.f; }
  char* x1c = reinterpret_cast<char*>(x1b);
  for (int ch = blockIdx.x; ch < NCH_; ch += 512) {
    const size_t n0 = (size_t)ch * 64;
    __syncthreads();
#pragma unroll
    for (int e = 0; e < 8; ++e) {
      int k0 = 2 * (w + 4 * e);
      float y0 = Y1[(size_t)k0 * NF_ + n0 + L];
      float y1 = Y1[(size_t)(k0 + 1) * NF_ + n0 + L];
      float v0 = fmaxf(fmaf(y0, ab1[k0], ab1[64 + k0]), 0.f);
      float v1 = fmaxf(fmaf(y1, ab1[k0 + 1], ab1[64 + k0 + 1]), 0.f);
      unsigned pk = (unsigned)f2bf(v0) | ((unsigned)f2bf(v1) << 16);
      *reinterpret_cast<unsigned*>(&x1c[L * 128 + ((2 * k0) ^ ((L & 7) << 4))]) = pk;
    }
    __syncthreads();
#pragma unroll
    for (int rb = 0; rb < 2; ++rb) {
      f32x4 acc2[4];
#pragma unroll
      for (int cb = 0; cb < 4; ++cb) acc2[cb][0] = acc2[cb][1] = acc2[cb][2] = acc2[cb][3] = 0.f;
#pragma unroll
      for (int ks = 0; ks < 2; ++ks)
#pragma unroll
        for (int cb = 0; cb < 4; ++cb) {
          int n = cb * 16 + (L & 15);
          int koff = ks * 32 + (L >> 4) * 8;
          bf16x8 bfr = *reinterpret_cast<const bf16x8*>(&x1c[n * 128 + ((2 * koff) ^ ((n & 7) << 4))]);
          acc2[cb] = __builtin_amdgcn_mfma_f32_16x16x32_bf16(w2f[rb][ks], bfr, acc2[cb], 0, 0, 0);
        }
#pragma unroll
      for (int cb = 0; cb < 4; ++cb)
#pragma unroll
        for (int r = 0; r < 4; ++r) {
          float y = acc2[cb][r];
          vs[rb][r] += y;
          vq[rb][r] = fmaf(y, y, vq[rb][r]);
        }
    }
  }
#pragma unroll
  for (int rb = 0; rb < 2; ++rb)
#pragma unroll
    for (int r = 0; r < 4; ++r) {
      float s = rowsum16(vs[rb][r]);
      float q = rowsum16(vq[rb][r]);
      if ((L & 15) == 15) {
        int row = (2 * w + rb) * 16 + (L >> 4) * 4 + r;
        parts[(size_t)blockIdx.x * 256 + row] = s;
        parts[(size_t)blockIdx.x * 256 + 128 + row] = q;
      }
    }
}

// ============ passB (MFMA): GEMM2 -> BN2/relu -> GEMM3, sum(y3), sum(y3^2) ============
__global__ __launch_bounds__(256) void passB_mfma_kernel(
    const float* __restrict__ Y1,
    const unsigned short* __restrict__ W2b, const unsigned short* __restrict__ W3b,
    const float* __restrict__ A1v, const float* __restrict__ Bc1v,
    const float* __restrict__ A2v, const float* __restrict__ D2v,
    float* __restrict__ parts) {
  __shared__ float ab1[128];
  __shared__ __align__(16) unsigned short x1b[64 * 64];    // 8 KB
  __shared__ __align__(16) unsigned short x2b[64 * 128];   // 16 KB
  const int t = threadIdx.x;
  const int w = t >> 6, L = t & 63;
  if (t < 128) ab1[t] = (t < 64) ? A1v[t] : Bc1v[t - 64];
  bf16x8 w3f[4][4];
#pragma unroll
  for (int rb = 0; rb < 4; ++rb)
#pragma unroll
    for (int ks = 0; ks < 4; ++ks) {
      int row = (4 * w + rb) * 16 + (L & 15);
      int koff = ks * 32 + (L >> 4) * 8;
      w3f[rb][ks] = *reinterpret_cast<const bf16x8*>(&W3b[row * 128 + koff]);
    }
  bf16x8 w2f[2][2];
#pragma unroll
  for (int rb = 0; rb < 2; ++rb)
#pragma unroll
    for (int ks = 0; ks < 2; ++ks) {
      int row = (2 * w + rb) * 16 + (L & 15);
      int koff = ks * 32 + (L >> 4) * 8;
      w2f[rb][ks] = *reinterpret_cast<const bf16x8*>(&W2b[row * 64 + koff]);
    }
  float vs[4][4], vq[4][4];
#pragma unroll
  for (int rb = 0; rb < 4; ++rb)
#pragma unroll
    for (int r = 0; r < 4; ++r) { vs[rb][r] = 0.f; vq[rb][r] = 0.f; }
  char* x1c = reinterpret_cast<char*>(x1b);
  char* x2c = reinterpret_cast<char*>(x2b);
  for (int ch = blockIdx.x; ch < NCH_; ch += 256) {
    const size_t n0 = (size_t)ch * 64;
    __syncthreads();
#pragma unroll
    for (int e = 0; e < 8; ++e) {
      int k0 = 2 * (w + 4 * e);
      float y0 = Y1[(size_t)k0 * NF_ + n0 + L];
      float y1 = Y1[(size_t)(k0 + 1) * NF_ + n0 + L];
      float v0 = fmaxf(fmaf(y0, ab1[k0], ab1[64 + k0]), 0.f);
      float v1 = fmaxf(fmaf(y1, ab1[k0 + 1], ab1[64 + k0 + 1]), 0.f);
      unsigned pk = (unsigned)f2bf(v0) | ((unsigned)f2bf(v1) << 16);
      *reinterpret_cast<unsigned*>(&x1c[L * 128 + ((2 * k0) ^ ((L & 7) << 4))]) = pk;
    }
    __syncthreads();
#pragma unroll
    for (int rb = 0; rb < 2; ++rb) {
      f32x4 acc2[4];
#pragma unroll
      for (int cb = 0; cb < 4; ++cb) acc2[cb][0] = acc2[cb][1] = acc2[cb][2] = acc2[cb][3] = 0.f;
#pragma unroll
      for (int ks = 0; ks < 2; ++ks)
#pragma unroll
        for (int cb = 0; cb < 4; ++cb) {
          int n = cb * 16 + (L & 15);
          int koff = ks * 32 + (L >> 4) * 8;
          bf16x8 bfr = *reinterpret_cast<const bf16x8*>(&x1c[n * 128 + ((2 * koff) ^ ((n & 7) << 4))]);
          acc2[cb] = __builtin_amdgcn_mfma_f32_16x16x32_bf16(w2f[rb][ks], bfr, acc2[cb], 0, 0, 0);
        }
#pragma unroll
      for (int cb = 0; cb < 4; ++cb) {
        int n = cb * 16 + (L & 15);
        int kbase = (2 * w + rb) * 16 + (L >> 4) * 4;
#pragma unroll
        for (int rp = 0; rp < 2; ++rp) {
          int r0 = 2 * rp;
          float a0 = A2v[kbase + r0], d0 = D2v[kbase + r0];
          float a1 = A2v[kbase + r0 + 1], d1 = D2v[kbase + r0 + 1];
          float v0 = fmaxf(fmaf(acc2[cb][r0], a0, d0), 0.f);
          float v1 = fmaxf(fmaf(acc2[cb][r0 + 1], a1, d1), 0.f);
          unsigned pk = (unsigned)f2bf(v0) | ((unsigned)f2bf(v1) << 16);
          int k0 = kbase + r0;
          *reinterpret_cast<unsigned*>(&x2c[n * 256 + ((2 * k0) ^ ((n & 7) << 4))]) = pk;
        }
      }
    }
    __syncthreads();
    bf16x8 b3[4][4];
#pragma unroll
    for (int cb = 0; cb < 4; ++cb)
#pragma unroll
      for (int ks = 0; ks < 4; ++ks) {
        int n = cb * 16 + (L & 15);
        int koff = ks * 32 + (L >> 4) * 8;
        b3[cb][ks] = *reinterpret_cast<const bf16x8*>(&x2c[n * 256 + ((2 * koff) ^ ((n & 7) << 4))]);
      }
#pragma unroll
    for (int rb = 0; rb < 4; ++rb) {
      f32x4 acc3[4];
#pragma unroll
      for (int cb = 0; cb < 4; ++cb) acc3[cb][0] = acc3[cb][1] = acc3[cb][2] = acc3[cb][3] = 0.f;
#pragma unroll
      for (int ks = 0; ks < 4; ++ks)
#pragma unroll
        for (int cb = 0; cb < 4; ++cb)
          acc3[cb] = __builtin_amdgcn_mfma_f32_16x16x32_bf16(w3f[rb][ks], b3[cb][ks], acc3[cb], 0, 0, 0);
#pragma unroll
      for (int cb = 0; cb < 4; ++cb)
#pragma unroll
        for (int r = 0; r < 4; ++r) {
          float y = acc3[cb][r];
          vs[rb][r] += y;
          vq[rb][r] = fmaf(y, y, vq[rb][r]);
        }
    }
  }
#pragma unroll
  for (int rb = 0; rb < 4; ++rb)
#pragma unroll
    for (int r = 0; r < 4; ++r) {
      float s = rowsum16(vs[rb][r]);
      float q = rowsum16(vq[rb][r]);
      if ((L & 15) == 15) {
        int row = (4 * w + rb) * 16 + (L >> 4) * 4 + r;
        parts[(size_t)blockIdx.x * 512 + row] = s;
        parts[(size_t)blockIdx.x * 512 + 256 + row] = q;
      }
    }
}

// ============ final (MFMA, validated): GEMM2 -> BN2 -> GEMM3 -> BN3 -> k-max ============
__global__ __launch_bounds__(256) void final_mfma_kernel(
    const float* __restrict__ Y1,
    const unsigned short* __restrict__ W2b,
    const unsigned short* __restrict__ W3b,
    const float* __restrict__ A1v, const float* __restrict__ Bc1v,
    const float* __restrict__ A2v, const float* __restrict__ D2v,
    const float* __restrict__ A3v, const float* __restrict__ D3v,
    float* __restrict__ out1) {
  __shared__ float ab1[128];
  __shared__ __align__(16) unsigned short x1b[64 * 64];
  __shared__ __align__(16) unsigned short x2b[64 * 128];
  const int t = threadIdx.x;
  const int w = t >> 6, L = t & 63;
  if (t < 128) ab1[t] = (t < 64) ? A1v[t] : Bc1v[t - 64];
  bf16x8 w3f[4][4];
#pragma unroll
  for (int rb = 0; rb < 4; ++rb)
#pragma unroll
    for (int ks = 0; ks < 4; ++ks) {
      int row = (4 * w + rb) * 16 + (L & 15);
      int koff = ks * 32 + (L >> 4) * 8;
      w3f[rb][ks] = *reinterpret_cast<const bf16x8*>(&W3b[row * 128 + koff]);
    }
  bf16x8 w2f[2][2];
#pragma unroll
  for (int rb = 0; rb < 2; ++rb)
#pragma unroll
    for (int ks = 0; ks < 2; ++ks) {
      int row = (2 * w + rb) * 16 + (L & 15);
      int koff = ks * 32 + (L >> 4) * 8;
      w2f[rb][ks] = *reinterpret_cast<const bf16x8*>(&W2b[row * 64 + koff]);
    }
  char* x1c = reinterpret_cast<char*>(x1b);
  char* x2c = reinterpret_cast<char*>(x2b);
  for (int ch = blockIdx.x; ch < NCH_; ch += 512) {
    const size_t n0 = (size_t)ch * 64;
    __syncthreads();
#pragma unroll
    for (int e = 0; e < 8; ++e) {
      int k0 = 2 * (w + 4 * e);
      float y0 = Y1[(size_t)k0 * NF_ + n0 + L];
      float y1 = Y1[(size_t)(k0 + 1) * NF_ + n0 + L];
      float v0 = fmaxf(fmaf(y0, ab1[k0], ab1[64 + k0]), 0.f);
      float v1 = fmaxf(fmaf(y1, ab1[k0 + 1], ab1[64 + k0 + 1]), 0.f);
      unsigned pk = (unsigned)f2bf(v0) | ((unsigned)f2bf(v1) << 16);
      *reinterpret_cast<unsigned*>(&x1c[L * 128 + ((2 * k0) ^ ((L & 7) << 4))]) = pk;
    }
    __syncthreads();
#pragma unroll
    for (int rb = 0; rb < 2; ++rb) {
      f32x4 acc2[4];
#pragma unroll
      for (int cb = 0; cb < 4; ++cb) acc2[cb][0] = acc2[cb][1] = acc2[cb][2] = acc2[cb][3] = 0.f;
#pragma unroll
      for (int ks = 0; ks < 2; ++ks)
#pragma unroll
        for (int cb = 0; cb < 4; ++cb) {
          int n = cb * 16 + (L & 15);
          int koff = ks * 32 + (L >> 4) * 8;
          bf16x8 bfr = *reinterpret_cast<const bf16x8*>(&x1c[n * 128 + ((2 * koff) ^ ((n & 7) << 4))]);
          acc2[cb] = __builtin_amdgcn_mfma_f32_16x16x32_bf16(w2f[rb][ks], bfr, acc2[cb], 0, 0, 0);
        }
#pragma unroll
      for (int cb = 0; cb < 4; ++cb) {
        int n = cb * 16 + (L & 15);
        int kbase = (2 * w + rb) * 16 + (L >> 4) * 4;
#pragma unroll
        for (int rp = 0; rp < 2; ++rp) {
          int r0 = 2 * rp;
          float a0 = A2v[kbase + r0], d0 = D2v[kbase + r0];
          float a1 = A2v[kbase + r0 + 1], d1 = D2v[kbase + r0 + 1];
          float v0 = fmaxf(fmaf(acc2[cb][r0], a0, d0), 0.f);
          float v1 = fmaxf(fmaf(acc2[cb][r0 + 1], a1, d1), 0.f);
          unsigned pk = (unsigned)f2bf(v0) | ((unsigned)f2bf(v1) << 16);
          int k0 = kbase + r0;
          *reinterpret_cast<unsigned*>(&x2c[n * 256 + ((2 * k0) ^ ((n & 7) << 4))]) = pk;
        }
      }
    }
    __syncthreads();
    bf16x8 b3[4][4];
#pragma unroll
    for (int cb = 0; cb < 4; ++cb)
#pragma unroll
      for (int ks = 0; ks < 4; ++ks) {
        int n = cb * 16 + (L & 15);
        int koff = ks * 32 + (L >> 4) * 8;
        b3[cb][ks] = *reinterpret_cast<const bf16x8*>(&x2c[n * 256 + ((2 * koff) ^ ((n & 7) << 4))]);
      }
#pragma unroll
    for (int rb = 0; rb < 4; ++rb) {
      f32x4 acc3[4];
#pragma unroll
      for (int cb = 0; cb < 4; ++cb) acc3[cb][0] = acc3[cb][1] = acc3[cb][2] = acc3[cb][3] = 0.f;
#pragma unroll
      for (int ks = 0; ks < 4; ++ks)
#pragma unroll
        for (int cb = 0; cb < 4; ++cb)
          acc3[cb] = __builtin_amdgcn_mfma_f32_16x16x32_bf16(w3f[rb][ks], b3[cb][ks], acc3[cb], 0, 0, 0);
      int rowbase = (4 * w + rb) * 16 + (L >> 4) * 4;
#pragma unroll
      for (int cb = 0; cb < 4; ++cb) {
#pragma unroll
        for (int r = 0; r < 4; ++r) {
          float v = fmaf(acc3[cb][r], A3v[rowbase + r], D3v[rowbase + r]);
          int xi = __float_as_int(v);
#define RMAX(CTRL) { int tm_ = __builtin_amdgcn_update_dpp(xi, xi, (CTRL), 0xF, 0xF, false); \
                     xi = __float_as_int(fmaxf(__int_as_float(xi), __int_as_float(tm_))); }
          RMAX(0x111) RMAX(0x112) RMAX(0x114) RMAX(0x118)
#undef RMAX
          if ((L & 15) == 15) {
            int row = rowbase + r;
            int bs = ch * 4 + cb;
            int b = bs / S_;
            int s = bs - b * S_;
            out1[((size_t)(b * 256 + row)) * S_ + s] = fmaxf(__int_as_float(xi), 0.f);
          }
        }
      }
    }
  }
}

__global__ void diag_kernel(float* out, float v) {
  if (threadIdx.x == 0 && blockIdx.x == 0) out[0] = v;
}

extern "C" void kernel_launch(void* const* d_in, const int* in_sizes, int n_in,
                              void* d_out, int out_size, void* d_ws, size_t ws_size,
                              hipStream_t stream) {
  const float* xy  = (const float*)d_in[0];
  const float* fea = (const float*)d_in[1];
  const float* W1  = (const float*)d_in[2];
  const float* b1  = (const float*)d_in[3];
  const float* g1  = (const float*)d_in[4];
  const float* be1 = (const float*)d_in[5];
  const float* W2  = (const float*)d_in[6];
  const float* g2  = (const float*)d_in[8];
  const float* be2 = (const float*)d_in[9];
  const float* W3  = (const float*)d_in[10];
  const float* g3  = (const float*)d_in[12];
  const float* be3 = (const float*)d_in[13];
  float* out = (float*)d_out;
  float* out1 = out + B_ * 2 * S_;

  char* w = (char*)d_ws;
  size_t off = 0;
  auto take = [&](size_t bytes) -> void* {
    void* p = w + off;
    off += (bytes + 255) & ~(size_t)255;
    return p;
  };
  int*    fps_idx = (int*)take((size_t)B_ * S_ * 4);
  float*  new_xyz = (float*)take((size_t)B_ * S_ * 2 * 4);
  int*    knn_sel = (int*)take((size_t)NF_ * 4);
  float*  P       = (float*)take((size_t)B_ * N_ * 64 * 4);   // 8.4 MB
  float*  Y1      = (float*)take((size_t)64 * NF_ * 4);       // 67.2 MB
  float*  parts1  = (float*)take((size_t)4 * 128 * 4);
  float*  A1      = (float*)take(64 * 4);
  float*  Bc1     = (float*)take(64 * 4);
  float*  partsA  = (float*)take((size_t)512 * 256 * 4);
  float*  A2      = (float*)take(128 * 4);
  float*  D2      = (float*)take(128 * 4);
  float*  partsB  = (float*)take((size_t)256 * 512 * 4);
  float*  A3      = (float*)take(256 * 4);
  float*  D3      = (float*)take(256 * 4);
  unsigned short* W2b = (unsigned short*)take((size_t)128 * 64 * 2);
  unsigned short* W3b = (unsigned short*)take((size_t)256 * 128 * 2);

  if (off > ws_size) {
    diag_kernel<<<1, 64, 0, stream>>>(out, (float)(ws_size >> 20));
    return;
  }

  fps_pk_kernel<<<16 + 512 + 1, 256, 0, stream>>>(xy, fea, W1, W2, W3,
                                                  fps_idx, new_xyz, out, P, W2b, W3b);
  knn_kernel<<<dim3((S_ + 7) / 8, B_), 256, 0, stream>>>(xy, fps_idx, knn_sel);
  yk1_kernel<<<NF_ / 256, 256, 0, stream>>>(xy, knn_sel, new_xyz, P, W1, b1, Y1);

  rowstats_kernel<<<256, 256, 0, stream>>>(Y1, parts1);
  redabsch_kernel<<<1, 64, 0, stream>>>(parts1, 4, 64, g1, be1, A1, Bc1);

  passA_mfma_kernel<<<512, 256, 0, stream>>>(Y1, W2b, A1, Bc1, partsA);
  redabsch_kernel<<<1, 128, 0, stream>>>(partsA, 512, 128, g2, be2, A2, D2);

  passB_mfma_kernel<<<256, 256, 0, stream>>>(Y1, W2b, W3b, A1, Bc1, A2, D2, partsB);
  redabsch_kernel<<<1, 256, 0, stream>>>(partsB, 256, 256, g3, be3, A3, D3);

  final_mfma_kernel<<<512, 256, 0, stream>>>(Y1, W2b, W3b, A1, Bc1, A2, D2, A3, D3, out1);
}